// Round 12
// baseline (322.671 us; speedup 1.0000x reference)
//
#include <hip/hip_runtime.h>
#include <cstddef>

// Problem constants (fixed by the reference)
#define EPQ_SHIFT 11       // EPQ = 2048
#define KSEL 256

typedef __attribute__((ext_vector_type(8))) short short8v;   // 8 bf16
typedef __attribute__((ext_vector_type(4))) float float4v;   // MFMA acc

__device__ __forceinline__ unsigned enc_f(float f) {
  unsigned u = __float_as_uint(f);
  return (u & 0x80000000u) ? ~u : (u | 0x80000000u);
}
__device__ __forceinline__ float dec_f(unsigned k) {
  unsigned u = (k & 0x80000000u) ? (k ^ 0x80000000u) : ~k;
  return __uint_as_float(u);
}
__device__ __forceinline__ unsigned short f2bf(float x) {  // RNE f32->bf16
  unsigned u = __float_as_uint(x);
  return (unsigned short)((u + 0x7FFFu + ((u >> 16) & 1u)) >> 16);
}

// ---------------- K1: init buffers + M = Wq^T Wk + Mt + bf16 splits -------
__global__ __launch_bounds__(256) void k1_gemmM(
    const float* __restrict__ Wq, const float* __restrict__ Wk,
    float* __restrict__ M, float* __restrict__ Mt,
    unsigned short* __restrict__ Mh, unsigned short* __restrict__ Ml,
    unsigned short* __restrict__ Mth, unsigned short* __restrict__ Mtl,
    float* __restrict__ outz, float* __restrict__ segsum,
    unsigned* __restrict__ segkey, int N) {
  int tid = threadIdx.x;
  {  // folded k0: zero out/segsum/segkey (grid-stride over 64x256 threads)
    int bid = blockIdx.y * gridDim.x + blockIdx.x;
    for (int idx = bid * 256 + tid; idx < N; idx += 16384) {
      outz[idx] = 0.f;
      segsum[idx] = 0.f;
      segkey[idx] = 0u;
    }
  }
  __shared__ float as[16][64];
  __shared__ float bs[16][64];
  int tx = tid & 15, ty = tid >> 4;
  int c1b = blockIdx.y * 64, c2b = blockIdx.x * 64;
  float acc[4][4] = {};
  for (int k0 = 0; k0 < 512; k0 += 16) {
#pragma unroll
    for (int l = 0; l < 4; ++l) {
      int lin = tid + l * 256;
      int kk = lin >> 6, c = lin & 63;
      as[kk][c] = Wq[(k0 + kk) * 512 + c1b + c];
      bs[kk][c] = Wk[(k0 + kk) * 512 + c2b + c];
    }
    __syncthreads();
#pragma unroll
    for (int kk = 0; kk < 16; ++kk) {
      float a[4], b[4];
#pragma unroll
      for (int m = 0; m < 4; ++m) a[m] = as[kk][ty * 4 + m];
#pragma unroll
      for (int n = 0; n < 4; ++n) b[n] = bs[kk][tx * 4 + n];
#pragma unroll
      for (int m = 0; m < 4; ++m)
#pragma unroll
        for (int n = 0; n < 4; ++n) acc[m][n] += a[m] * b[n];
    }
    __syncthreads();
  }
#pragma unroll
  for (int m = 0; m < 4; ++m)
#pragma unroll
    for (int n = 0; n < 4; ++n) {
      int c1 = c1b + ty * 4 + m, c2 = c2b + tx * 4 + n;
      float v = acc[m][n];
      M[c1 * 512 + c2] = v;
      Mt[c2 * 512 + c1] = v;
      unsigned short h = f2bf(v);
      unsigned short lo = f2bf(v - __uint_as_float((unsigned)h << 16));
      Mh[c1 * 512 + c2] = h;
      Ml[c1 * 512 + c2] = lo;
      Mth[c2 * 512 + c1] = h;
      Mtl[c2 * 512 + c1] = lo;
    }
}

// ===== MFMA micro-kernel (split-bf16, 3 products) =====
#define STAGE_A_F32(SRC_PTR)                                                 \
  {                                                                          \
    const float* s = (SRC_PTR);                                              \
    float4 v0 = *(const float4*)&s[0];                                       \
    float4 v1 = *(const float4*)&s[4];                                       \
    float4 v2 = *(const float4*)&s[8];                                       \
    float4 v3 = *(const float4*)&s[12];                                      \
    float vv[16] = {v0.x, v0.y, v0.z, v0.w, v1.x, v1.y, v1.z, v1.w,          \
                    v2.x, v2.y, v2.z, v2.w, v3.x, v3.y, v3.z, v3.w};         \
    unsigned hw[8], lw[8];                                                   \
    _Pragma("unroll") for (int j = 0; j < 8; ++j) {                          \
      unsigned short h0 = f2bf(vv[2 * j]);                                   \
      unsigned short h1 = f2bf(vv[2 * j + 1]);                               \
      unsigned short l0 =                                                    \
          f2bf(vv[2 * j] - __uint_as_float((unsigned)h0 << 16));             \
      unsigned short l1 =                                                    \
          f2bf(vv[2 * j + 1] - __uint_as_float((unsigned)h1 << 16));         \
      hw[j] = (unsigned)h0 | ((unsigned)h1 << 16);                           \
      lw[j] = (unsigned)l0 | ((unsigned)l1 << 16);                           \
    }                                                                        \
    int sw = (sn >> 1) & 3;                                                  \
    int g0 = (shalf * 2) ^ sw, g1 = (shalf * 2 + 1) ^ sw;                    \
    *(uint4*)&Ah[sn][g0 * 8] = make_uint4(hw[0], hw[1], hw[2], hw[3]);       \
    *(uint4*)&Ah[sn][g1 * 8] = make_uint4(hw[4], hw[5], hw[6], hw[7]);       \
    *(uint4*)&Al[sn][g0 * 8] = make_uint4(lw[0], lw[1], lw[2], lw[3]);       \
    *(uint4*)&Al[sn][g1 * 8] = make_uint4(lw[4], lw[5], lw[6], lw[7]);       \
  }

#define STAGE_B_BF16(HSRC, LSRC)                                             \
  {                                                                          \
    const unsigned short* sh_ = (HSRC);                                      \
    const unsigned short* sl_ = (LSRC);                                      \
    uint4 q0 = *(const uint4*)&sh_[0];                                       \
    uint4 q1 = *(const uint4*)&sh_[8];                                       \
    uint4 p0 = *(const uint4*)&sl_[0];                                       \
    uint4 p1 = *(const uint4*)&sl_[8];                                       \
    int sw = (sn >> 1) & 3;                                                  \
    int g0 = (shalf * 2) ^ sw, g1 = (shalf * 2 + 1) ^ sw;                    \
    *(uint4*)&Bh[sn][g0 * 8] = q0;                                           \
    *(uint4*)&Bh[sn][g1 * 8] = q1;                                           \
    *(uint4*)&Bl[sn][g0 * 8] = p0;                                           \
    *(uint4*)&Bl[sn][g1 * 8] = p1;                                           \
  }

#define MFMA_CHUNK()                                                         \
  {                                                                          \
    int ln = lane & 15, kq = lane >> 4;                                      \
    short8v ah[4], al[4];                                                    \
    _Pragma("unroll") for (int r = 0; r < 4; ++r) {                          \
      int row = wr2 * 64 + r * 16 + ln;                                      \
      int gg = kq ^ ((row >> 1) & 3);                                        \
      ah[r] = *(const short8v*)&Ah[row][gg * 8];                             \
      al[r] = *(const short8v*)&Al[row][gg * 8];                             \
    }                                                                        \
    _Pragma("unroll") for (int c = 0; c < 4; ++c) {                          \
      int col = wc2 * 64 + c * 16 + ln;                                      \
      int gg = kq ^ ((col >> 1) & 3);                                        \
      short8v bh = *(const short8v*)&Bh[col][gg * 8];                        \
      short8v bl = *(const short8v*)&Bl[col][gg * 8];                        \
      _Pragma("unroll") for (int r = 0; r < 4; ++r) {                        \
        acc[r][c] = __builtin_amdgcn_mfma_f32_16x16x32_bf16(                 \
            ah[r], bh, acc[r][c], 0, 0, 0);                                  \
        acc[r][c] = __builtin_amdgcn_mfma_f32_16x16x32_bf16(                 \
            ah[r], bl, acc[r][c], 0, 0, 0);                                  \
        acc[r][c] = __builtin_amdgcn_mfma_f32_16x16x32_bf16(                 \
            al[r], bh, acc[r][c], 0, 0, 0);                                  \
      }                                                                      \
    }                                                                        \
  }

// ---------------- K2m: projections; J0/J1 packed into Tj[n][256], I1 ------
__global__ __launch_bounds__(256) void k2m_mfma(
    const float* __restrict__ hv, const unsigned short* __restrict__ Mh,
    const unsigned short* __restrict__ Ml, const unsigned short* __restrict__ Mth,
    const unsigned short* __restrict__ Mtl, float* __restrict__ Tj,
    float* __restrict__ I1, int N) {
  __shared__ char pool[32768];
  unsigned short (*Ah)[32] = (unsigned short(*)[32])pool;
  unsigned short (*Al)[32] = (unsigned short(*)[32])(pool + 8192);
  unsigned short (*Bh)[32] = (unsigned short(*)[32])(pool + 16384);
  unsigned short (*Bl)[32] = (unsigned short(*)[32])(pool + 24576);
  float (*ep)[34] = (float(*)[34])pool;

  const int tid = threadIdx.x;
  const int lane = tid & 63;
  const int w = tid >> 6;
  const int wr2 = w >> 1, wc2 = w & 1;
  const int p = blockIdx.x;
  const int n0 = blockIdx.y * 128;
  const unsigned short* bhs = (p == 2) ? Mth : Mh;
  const unsigned short* bls = (p == 2) ? Mtl : Ml;
  const int rowoff = (p == 0) ? 0 : 128;
  float* outp = (p == 0) ? Tj : (p == 1) ? (Tj + 128) : I1;
  const size_t ostride = (p == 2) ? 128 : 256;

  float4v acc[4][4];
#pragma unroll
  for (int r = 0; r < 4; ++r)
#pragma unroll
    for (int c = 0; c < 4; ++c) acc[r][c] = (float4v){0.f, 0.f, 0.f, 0.f};

  const int sn = tid >> 1, shalf = tid & 1;
  for (int ch = 0; ch < 4; ++ch) {
    __syncthreads();
    {
      int gn = n0 + sn;
      gn = gn < N ? gn : N - 1;
      STAGE_A_F32(hv + (size_t)gn * 128 + ch * 32 + shalf * 16);
      size_t boff = (size_t)(rowoff + sn) * 512 + ch * 32 + shalf * 16;
      STAGE_B_BF16(bhs + boff, bls + boff);
    }
    __syncthreads();
    MFMA_CHUNK();
  }

  for (int g = 0; g < 4; ++g) {
    __syncthreads();
    if (wc2 == (g >> 1)) {
      int ln = lane & 15, kq = lane >> 4;
#pragma unroll
      for (int cc = 0; cc < 2; ++cc) {
        int c = (g & 1) * 2 + cc;
#pragma unroll
        for (int r = 0; r < 4; ++r)
#pragma unroll
          for (int reg = 0; reg < 4; ++reg)
            ep[wr2 * 64 + r * 16 + kq * 4 + reg][cc * 16 + ln] = acc[r][c][reg];
      }
    }
    __syncthreads();
    int row = tid >> 1, half = tid & 1;
    int gn = n0 + row;
    if (gn < N) {
#pragma unroll
      for (int j = 0; j < 4; ++j)
        *(float4*)&outp[(size_t)gn * ostride + 32 * g + 16 * half + 4 * j] =
            *(const float4*)&ep[row][16 * half + 4 * j];
    }
  }
}

// ---------------- K3: per-query vectors w,u,y,c_b (256 thr, c-split) ------
__global__ __launch_bounds__(256) void k3_query(const float* __restrict__ qsrc,
                                                const float* __restrict__ qrel,
                                                const float* __restrict__ M,
                                                const float* __restrict__ Mt,
                                                float* __restrict__ wv,
                                                float* __restrict__ uv,
                                                float* __restrict__ yv,
                                                float* __restrict__ cb) {
  __shared__ float qcat[256];
  __shared__ float prt[5][256];
  __shared__ float red[128];
  int b = blockIdx.x, tid = threadIdx.x;
  int d = tid & 127, hc = tid >> 7;
  qcat[tid] = (tid < 128) ? qsrc[b * 128 + tid] : qrel[b * 128 + (tid - 128)];
  __syncthreads();
  float w = 0.f, u = 0.f, y = 0.f, t1 = 0.f, t2 = 0.f;
  for (int c = hc * 128; c < hc * 128 + 128; ++c) {
    float q = qcat[c];
    size_t row = (size_t)(256 + c) * 512;
    w += Mt[row + d] * q;
    u += M[row + d] * q;
    y += (Mt[row + 128 + d] + M[row + 128 + d]) * q;
    t1 += M[row + 256 + d] * q;
    t2 += M[row + 384 + d] * q;
  }
  prt[0][tid] = w; prt[1][tid] = u; prt[2][tid] = y;
  prt[3][tid] = t1; prt[4][tid] = t2;
  __syncthreads();
  if (tid < 128) {
    float wc_ = prt[0][d] + prt[0][128 + d];
    float uc = prt[1][d] + prt[1][128 + d];
    float yc = prt[2][d] + prt[2][128 + d];
    float t1c = prt[3][d] + prt[3][128 + d];
    float t2c = prt[4][d] + prt[4][128 + d];
    wv[b * 128 + d] = wc_;
    uv[b * 128 + d] = uc;
    yv[b * 128 + d] = yc;
    red[d] = qcat[d] * t1c + qcat[128 + d] * t2c;
  }
  __syncthreads();
  for (int s = 64; s > 0; s >>= 1) {
    if (tid < s) red[tid] += red[tid + s];
    __syncthreads();
  }
  if (tid == 0) cb[b] = red[0];
}

// ---------------- K45: fused edge_const (MFMA) + logits + segment max -----
// Phase 1 = k4m (ec -> LDS). Phase 2 = per-edge dots: 2 lanes/edge, 64
// components each; rel re-read from global (L1/L2-hot from phase 1).
__global__ __launch_bounds__(256) void k45_fused(
    const float* __restrict__ rel, const unsigned short* __restrict__ Mth,
    const unsigned short* __restrict__ Mtl, const float* __restrict__ yv,
    const float* __restrict__ cbp, const float* __restrict__ hv,
    const float* __restrict__ Tj, const float* __restrict__ I1,
    const int* __restrict__ node_i, const int* __restrict__ node_j,
    const float* __restrict__ wvv, const float* __restrict__ uvv,
    float* __restrict__ logits, unsigned* __restrict__ segkey) {
  __shared__ char pool[32768];
  unsigned short (*Ah)[32] = (unsigned short(*)[32])pool;
  unsigned short (*Al)[32] = (unsigned short(*)[32])(pool + 8192);
  unsigned short (*Bh)[32] = (unsigned short(*)[32])(pool + 16384);
  unsigned short (*Bl)[32] = (unsigned short(*)[32])(pool + 24576);
  float (*ep)[34] = (float(*)[34])pool;
  __shared__ float ecl[128];
  __shared__ float wl[128];
  __shared__ float ul[128];

  const int tid = threadIdx.x;
  const int lane = tid & 63;
  const int w = tid >> 6;
  const int wr2 = w >> 1, wc2 = w & 1;
  const int e0 = blockIdx.x * 128;
  const int b = e0 >> EPQ_SHIFT;

  if (tid < 128) wl[tid] = wvv[b * 128 + tid];
  else ul[tid - 128] = uvv[b * 128 + (tid - 128)];

  // ---- phase 1: GEMM q[e][d] = sum_c rel[e][c] * M11[c][d] ----
  float4v acc[4][4];
#pragma unroll
  for (int r = 0; r < 4; ++r)
#pragma unroll
    for (int c = 0; c < 4; ++c) acc[r][c] = (float4v){0.f, 0.f, 0.f, 0.f};

  const int sn = tid >> 1, shalf = tid & 1;
  for (int ch = 0; ch < 4; ++ch) {
    __syncthreads();
    {
      STAGE_A_F32(rel + (size_t)(e0 + sn) * 128 + ch * 32 + shalf * 16);
      size_t boff = (size_t)(128 + sn) * 512 + 128 + ch * 32 + shalf * 16;
      STAGE_B_BF16(Mth + boff, Mtl + boff);
    }
    __syncthreads();
    MFMA_CHUNK();
  }

  float part = 0.f;
  const int e_loc1 = tid >> 1, half1 = tid & 1;
  for (int g = 0; g < 4; ++g) {
    __syncthreads();
    if (wc2 == (g >> 1)) {
      int ln = lane & 15, kq = lane >> 4;
#pragma unroll
      for (int cc = 0; cc < 2; ++cc) {
        int c = (g & 1) * 2 + cc;
#pragma unroll
        for (int r = 0; r < 4; ++r)
#pragma unroll
          for (int reg = 0; reg < 4; ++reg)
            ep[wr2 * 64 + r * 16 + kq * 4 + reg][cc * 16 + ln] = acc[r][c][reg];
      }
    }
    __syncthreads();
    const float* rsrc = rel + (size_t)(e0 + e_loc1) * 128 + 32 * g + 16 * half1;
    const float* ysrc = yv + b * 128 + 32 * g + 16 * half1;
#pragma unroll
    for (int j = 0; j < 4; ++j) {
      float4 q = *(const float4*)&ep[e_loc1][16 * half1 + 4 * j];
      float4 rr = *(const float4*)&rsrc[4 * j];
      float4 yy = *(const float4*)&ysrc[4 * j];
      part += (q.x + yy.x) * rr.x + (q.y + yy.y) * rr.y +
              (q.z + yy.z) * rr.z + (q.w + yy.w) * rr.w;
    }
  }
  part += __shfl_xor(part, 1, 64);
  if ((tid & 1) == 0) ecl[e_loc1] = part + cbp[b];
  __syncthreads();

  // ---- phase 2: logits. 2 lanes/edge, 64 comps/lane, single pass ----
  {
    const int eslot = lane >> 1, half = lane & 1;
    const int e_loc = w * 32 + eslot;
    const int e = e0 + e_loc;
    const int i = node_i[e], j = node_j[e];
    const int c0 = half * 64;
    const float* relp = rel + (size_t)e * 128 + c0;
    const float* hvi = hv + (size_t)i * 128 + c0;
    const float* hvj = hv + (size_t)j * 128 + c0;
    const float* tjp = Tj + (size_t)j * 256 + c0;   // J0; J1 at +128
    const float* iip = I1 + (size_t)i * 128 + c0;

    float p = 0.f;
#pragma unroll
    for (int k = 0; k < 16; ++k) {
      float4 rr = *(const float4*)&relp[4 * k];
      float4 h_i = *(const float4*)&hvi[4 * k];
      float4 h_j = *(const float4*)&hvj[4 * k];
      float4 a0 = *(const float4*)&tjp[4 * k];
      float4 a1 = *(const float4*)&tjp[128 + 4 * k];
      float4 ii = *(const float4*)&iip[4 * k];
      float4 w4 = *(const float4*)&wl[c0 + 4 * k];
      float4 u4 = *(const float4*)&ul[c0 + 4 * k];
      p += h_i.x * a0.x + h_i.y * a0.y + h_i.z * a0.z + h_i.w * a0.w;
      p += rr.x * (a1.x + ii.x) + rr.y * (a1.y + ii.y) +
           rr.z * (a1.z + ii.z) + rr.w * (a1.w + ii.w);
      p += h_i.x * w4.x + h_i.y * w4.y + h_i.z * w4.z + h_i.w * w4.w;
      p += h_j.x * u4.x + h_j.y * u4.y + h_j.z * u4.z + h_j.w * u4.w;
    }
    p += __shfl_xor(p, 1, 64);
    if (half == 0) {
      float lg = p + ecl[e_loc];
      logits[e] = lg;
      atomicMax(&segkey[i], enc_f(lg));
    }
  }
}

// ---------------- K6: ex = exp(logit - segmax), segment sum ----------------
__global__ void k6_exp(float* __restrict__ exb, const int* __restrict__ node_i,
                       const unsigned* __restrict__ segkey,
                       float* __restrict__ segsum, int E) {
  int e = blockIdx.x * 256 + threadIdx.x;
  if (e >= E) return;
  int i = node_i[e];
  float m = dec_f(segkey[i]);
  float ex = expf(exb[e] - m);
  exb[e] = ex;
  atomicAdd(&segsum[i], ex);
}

// ---------------- K7: per-query exact top-256 radix select + scatter-add ----
__global__ __launch_bounds__(256) void k7_topk(const float* __restrict__ exb,
                                               const int* __restrict__ node_i,
                                               const int* __restrict__ node_j,
                                               const float* __restrict__ segsum,
                                               const float* __restrict__ score,
                                               float* __restrict__ out) {
  __shared__ unsigned vals[2048];
  __shared__ unsigned hist[256];
  __shared__ unsigned sc[256];
  __shared__ unsigned tie_scan[256];
  __shared__ unsigned sel_info[2];
  int q = blockIdx.x, t = threadIdx.x;
  size_t base = (size_t)q * 2048;
#pragma unroll
  for (int l = 0; l < 8; ++l) {
    int el = t * 8 + l;
    int i = node_i[base + el];
    float tgt = exb[base + el] / segsum[i] * score[i];  // attn * src_score >= 0
    vals[el] = __float_as_uint(tgt);
  }
  __syncthreads();
  unsigned prefix = 0, need = KSEL;
  for (int pass = 3; pass >= 0; --pass) {
    hist[t] = 0;
    __syncthreads();
    int sh = pass * 8;
#pragma unroll
    for (int l = 0; l < 8; ++l) {
      unsigned v = vals[t * 8 + l];
      bool match = (pass == 3) || ((v >> (sh + 8)) == (prefix >> (sh + 8)));
      if (match) atomicAdd(&hist[(v >> sh) & 255u], 1u);
    }
    __syncthreads();
    sc[t] = hist[t];
    __syncthreads();
    for (int off = 1; off < 256; off <<= 1) {  // suffix-inclusive sum
      unsigned add = (t + off < 256) ? sc[t + off] : 0u;
      __syncthreads();
      sc[t] += add;
      __syncthreads();
    }
    unsigned above = sc[t] - hist[t];
    if (above < need && need <= sc[t]) {
      sel_info[0] = (unsigned)t;
      sel_info[1] = need - above;
    }
    __syncthreads();
    prefix |= sel_info[0] << sh;
    need = sel_info[1];
    __syncthreads();
  }
  unsigned T = prefix, r = need;
  unsigned lc = 0;
#pragma unroll
  for (int l = 0; l < 8; ++l)
    if (vals[t * 8 + l] == T) lc++;
  tie_scan[t] = lc;
  __syncthreads();
  unsigned own = lc;
  for (int off = 1; off < 256; off <<= 1) {
    unsigned add = (t >= off) ? tie_scan[t - off] : 0u;
    __syncthreads();
    tie_scan[t] += add;
    __syncthreads();
  }
  unsigned excl = tie_scan[t] - own;
  unsigned cnt = 0;
#pragma unroll
  for (int l = 0; l < 8; ++l) {
    int el = t * 8 + l;
    unsigned v = vals[el];
    bool take = false;
    if (v > T) take = true;
    else if (v == T) { if (excl + cnt < r) take = true; cnt++; }
    if (take) {
      int j = node_j[base + el];
      atomicAdd(&out[j], __uint_as_float(v));
    }
  }
}

// ---------------- host ----------------
extern "C" void kernel_launch(void* const* d_in, const int* in_sizes, int n_in,
                              void* d_out, int out_size, void* d_ws, size_t ws_size,
                              hipStream_t stream) {
  const float* score = (const float*)d_in[0];
  const float* hv    = (const float*)d_in[1];
  const float* rel   = (const float*)d_in[2];
  const float* qsrc  = (const float*)d_in[3];
  const float* qrel  = (const float*)d_in[4];
  const float* Wq    = (const float*)d_in[5];
  const float* Wk    = (const float*)d_in[6];
  const int* node_i  = (const int*)d_in[8];
  const int* node_j  = (const int*)d_in[9];

  const int N = in_sizes[0];            // 50000
  const int B = in_sizes[3] / 128;      // 64
  const int E = in_sizes[2] / 128;      // 131072

  float* ws = (float*)d_ws;
  float* M  = ws;
  float* Mt = M + 262144;
  float* Tj = Mt + 262144;              // [N][256] = J0|J1 packed
  float* I1 = Tj + (size_t)N * 256;
  float* wv = I1 + (size_t)N * 128;
  float* uv = wv + (size_t)B * 128;
  float* yv = uv + (size_t)B * 128;
  float* cb = yv + (size_t)B * 128;
  float* exb = cb + B;
  unsigned* segkey = (unsigned*)(exb + E);
  float* segsum = (float*)(segkey + N);
  unsigned short* Mh  = (unsigned short*)(segsum + N);
  unsigned short* Ml  = Mh + 262144;
  unsigned short* Mth = Ml + 262144;
  unsigned short* Mtl = Mth + 262144;
  float* out = (float*)d_out;

  k1_gemmM<<<dim3(8, 8), 256, 0, stream>>>(Wq, Wk, M, Mt, Mh, Ml, Mth, Mtl,
                                           out, segsum, segkey, N);
  k2m_mfma<<<dim3(3, (N + 127) / 128), 256, 0, stream>>>(hv, Mh, Ml, Mth, Mtl,
                                                         Tj, I1, N);
  k3_query<<<B, 256, 0, stream>>>(qsrc, qrel, M, Mt, wv, uv, yv, cb);
  k45_fused<<<E / 128, 256, 0, stream>>>(rel, Mth, Mtl, yv, cb, hv, Tj, I1,
                                         node_i, node_j, wv, uv, exb, segkey);
  k6_exp<<<(E + 255) / 256, 256, 0, stream>>>(exb, node_i, segkey, segsum, E);
  k7_topk<<<B, 256, 0, stream>>>(exb, node_i, node_j, segsum, score, out);
}

// Round 13
// 237.306 us; speedup vs baseline: 1.3597x; 1.3597x over previous
//
#include <hip/hip_runtime.h>
#include <cstddef>

// Problem constants (fixed by the reference)
#define EPQ_SHIFT 11       // EPQ = 2048
#define KSEL 256

typedef __attribute__((ext_vector_type(8))) short short8v;   // 8 bf16
typedef __attribute__((ext_vector_type(4))) float float4v;   // MFMA acc

__device__ __forceinline__ unsigned enc_f(float f) {
  unsigned u = __float_as_uint(f);
  return (u & 0x80000000u) ? ~u : (u | 0x80000000u);
}
__device__ __forceinline__ float dec_f(unsigned k) {
  unsigned u = (k & 0x80000000u) ? (k ^ 0x80000000u) : ~k;
  return __uint_as_float(u);
}
__device__ __forceinline__ unsigned short f2bf(float x) {  // RNE f32->bf16
  unsigned u = __float_as_uint(x);
  return (unsigned short)((u + 0x7FFFu + ((u >> 16) & 1u)) >> 16);
}

// ---------------- K1: init buffers + M = Wq^T Wk + Mt + bf16 splits -------
__global__ __launch_bounds__(256) void k1_gemmM(
    const float* __restrict__ Wq, const float* __restrict__ Wk,
    float* __restrict__ M, float* __restrict__ Mt,
    unsigned short* __restrict__ Mh, unsigned short* __restrict__ Ml,
    unsigned short* __restrict__ Mth, unsigned short* __restrict__ Mtl,
    float* __restrict__ outz, float* __restrict__ segsum,
    unsigned* __restrict__ segkey, int N) {
  int tid = threadIdx.x;
  {  // folded k0: zero out/segsum/segkey (grid-stride over 64x256 threads)
    int bid = blockIdx.y * gridDim.x + blockIdx.x;
    for (int idx = bid * 256 + tid; idx < N; idx += 16384) {
      outz[idx] = 0.f;
      segsum[idx] = 0.f;
      segkey[idx] = 0u;
    }
  }
  __shared__ float as[16][64];
  __shared__ float bs[16][64];
  int tx = tid & 15, ty = tid >> 4;
  int c1b = blockIdx.y * 64, c2b = blockIdx.x * 64;
  float acc[4][4] = {};
  for (int k0 = 0; k0 < 512; k0 += 16) {
#pragma unroll
    for (int l = 0; l < 4; ++l) {
      int lin = tid + l * 256;
      int kk = lin >> 6, c = lin & 63;
      as[kk][c] = Wq[(k0 + kk) * 512 + c1b + c];
      bs[kk][c] = Wk[(k0 + kk) * 512 + c2b + c];
    }
    __syncthreads();
#pragma unroll
    for (int kk = 0; kk < 16; ++kk) {
      float a[4], b[4];
#pragma unroll
      for (int m = 0; m < 4; ++m) a[m] = as[kk][ty * 4 + m];
#pragma unroll
      for (int n = 0; n < 4; ++n) b[n] = bs[kk][tx * 4 + n];
#pragma unroll
      for (int m = 0; m < 4; ++m)
#pragma unroll
        for (int n = 0; n < 4; ++n) acc[m][n] += a[m] * b[n];
    }
    __syncthreads();
  }
#pragma unroll
  for (int m = 0; m < 4; ++m)
#pragma unroll
    for (int n = 0; n < 4; ++n) {
      int c1 = c1b + ty * 4 + m, c2 = c2b + tx * 4 + n;
      float v = acc[m][n];
      M[c1 * 512 + c2] = v;
      Mt[c2 * 512 + c1] = v;
      unsigned short h = f2bf(v);
      unsigned short lo = f2bf(v - __uint_as_float((unsigned)h << 16));
      Mh[c1 * 512 + c2] = h;
      Ml[c1 * 512 + c2] = lo;
      Mth[c2 * 512 + c1] = h;
      Mtl[c2 * 512 + c1] = lo;
    }
}

// ===== MFMA micro-kernel (split-bf16, 3 products) =====
#define STAGE_A_F32(SRC_PTR)                                                 \
  {                                                                          \
    const float* s = (SRC_PTR);                                              \
    float4 v0 = *(const float4*)&s[0];                                       \
    float4 v1 = *(const float4*)&s[4];                                       \
    float4 v2 = *(const float4*)&s[8];                                       \
    float4 v3 = *(const float4*)&s[12];                                      \
    float vv[16] = {v0.x, v0.y, v0.z, v0.w, v1.x, v1.y, v1.z, v1.w,          \
                    v2.x, v2.y, v2.z, v2.w, v3.x, v3.y, v3.z, v3.w};         \
    unsigned hw[8], lw[8];                                                   \
    _Pragma("unroll") for (int j = 0; j < 8; ++j) {                          \
      unsigned short h0 = f2bf(vv[2 * j]);                                   \
      unsigned short h1 = f2bf(vv[2 * j + 1]);                               \
      unsigned short l0 =                                                    \
          f2bf(vv[2 * j] - __uint_as_float((unsigned)h0 << 16));             \
      unsigned short l1 =                                                    \
          f2bf(vv[2 * j + 1] - __uint_as_float((unsigned)h1 << 16));         \
      hw[j] = (unsigned)h0 | ((unsigned)h1 << 16);                           \
      lw[j] = (unsigned)l0 | ((unsigned)l1 << 16);                           \
    }                                                                        \
    int sw = (sn >> 1) & 3;                                                  \
    int g0 = (shalf * 2) ^ sw, g1 = (shalf * 2 + 1) ^ sw;                    \
    *(uint4*)&Ah[sn][g0 * 8] = make_uint4(hw[0], hw[1], hw[2], hw[3]);       \
    *(uint4*)&Ah[sn][g1 * 8] = make_uint4(hw[4], hw[5], hw[6], hw[7]);       \
    *(uint4*)&Al[sn][g0 * 8] = make_uint4(lw[0], lw[1], lw[2], lw[3]);       \
    *(uint4*)&Al[sn][g1 * 8] = make_uint4(lw[4], lw[5], lw[6], lw[7]);       \
  }

#define STAGE_B_BF16(HSRC, LSRC)                                             \
  {                                                                          \
    const unsigned short* sh_ = (HSRC);                                      \
    const unsigned short* sl_ = (LSRC);                                      \
    uint4 q0 = *(const uint4*)&sh_[0];                                       \
    uint4 q1 = *(const uint4*)&sh_[8];                                       \
    uint4 p0 = *(const uint4*)&sl_[0];                                       \
    uint4 p1 = *(const uint4*)&sl_[8];                                       \
    int sw = (sn >> 1) & 3;                                                  \
    int g0 = (shalf * 2) ^ sw, g1 = (shalf * 2 + 1) ^ sw;                    \
    *(uint4*)&Bh[sn][g0 * 8] = q0;                                           \
    *(uint4*)&Bh[sn][g1 * 8] = q1;                                           \
    *(uint4*)&Bl[sn][g0 * 8] = p0;                                           \
    *(uint4*)&Bl[sn][g1 * 8] = p1;                                           \
  }

#define MFMA_CHUNK()                                                         \
  {                                                                          \
    int ln = lane & 15, kq = lane >> 4;                                      \
    short8v ah[4], al[4];                                                    \
    _Pragma("unroll") for (int r = 0; r < 4; ++r) {                          \
      int row = wr2 * 64 + r * 16 + ln;                                      \
      int gg = kq ^ ((row >> 1) & 3);                                        \
      ah[r] = *(const short8v*)&Ah[row][gg * 8];                             \
      al[r] = *(const short8v*)&Al[row][gg * 8];                             \
    }                                                                        \
    _Pragma("unroll") for (int c = 0; c < 4; ++c) {                          \
      int col = wc2 * 64 + c * 16 + ln;                                      \
      int gg = kq ^ ((col >> 1) & 3);                                        \
      short8v bh = *(const short8v*)&Bh[col][gg * 8];                        \
      short8v bl = *(const short8v*)&Bl[col][gg * 8];                        \
      _Pragma("unroll") for (int r = 0; r < 4; ++r) {                        \
        acc[r][c] = __builtin_amdgcn_mfma_f32_16x16x32_bf16(                 \
            ah[r], bh, acc[r][c], 0, 0, 0);                                  \
        acc[r][c] = __builtin_amdgcn_mfma_f32_16x16x32_bf16(                 \
            ah[r], bl, acc[r][c], 0, 0, 0);                                  \
        acc[r][c] = __builtin_amdgcn_mfma_f32_16x16x32_bf16(                 \
            al[r], bh, acc[r][c], 0, 0, 0);                                  \
      }                                                                      \
    }                                                                        \
  }

// ---------------- K2m: projections; J0/J1 packed into Tj[n][256], I1 ------
__global__ __launch_bounds__(256) void k2m_mfma(
    const float* __restrict__ hv, const unsigned short* __restrict__ Mh,
    const unsigned short* __restrict__ Ml, const unsigned short* __restrict__ Mth,
    const unsigned short* __restrict__ Mtl, float* __restrict__ Tj,
    float* __restrict__ I1, int N) {
  __shared__ char pool[32768];
  unsigned short (*Ah)[32] = (unsigned short(*)[32])pool;
  unsigned short (*Al)[32] = (unsigned short(*)[32])(pool + 8192);
  unsigned short (*Bh)[32] = (unsigned short(*)[32])(pool + 16384);
  unsigned short (*Bl)[32] = (unsigned short(*)[32])(pool + 24576);
  float (*ep)[34] = (float(*)[34])pool;

  const int tid = threadIdx.x;
  const int lane = tid & 63;
  const int w = tid >> 6;
  const int wr2 = w >> 1, wc2 = w & 1;
  const int p = blockIdx.x;
  const int n0 = blockIdx.y * 128;
  const unsigned short* bhs = (p == 2) ? Mth : Mh;
  const unsigned short* bls = (p == 2) ? Mtl : Ml;
  const int rowoff = (p == 0) ? 0 : 128;
  float* outp = (p == 0) ? Tj : (p == 1) ? (Tj + 128) : I1;
  const size_t ostride = (p == 2) ? 128 : 256;

  float4v acc[4][4];
#pragma unroll
  for (int r = 0; r < 4; ++r)
#pragma unroll
    for (int c = 0; c < 4; ++c) acc[r][c] = (float4v){0.f, 0.f, 0.f, 0.f};

  const int sn = tid >> 1, shalf = tid & 1;
  for (int ch = 0; ch < 4; ++ch) {
    __syncthreads();
    {
      int gn = n0 + sn;
      gn = gn < N ? gn : N - 1;
      STAGE_A_F32(hv + (size_t)gn * 128 + ch * 32 + shalf * 16);
      size_t boff = (size_t)(rowoff + sn) * 512 + ch * 32 + shalf * 16;
      STAGE_B_BF16(bhs + boff, bls + boff);
    }
    __syncthreads();
    MFMA_CHUNK();
  }

  for (int g = 0; g < 4; ++g) {
    __syncthreads();
    if (wc2 == (g >> 1)) {
      int ln = lane & 15, kq = lane >> 4;
#pragma unroll
      for (int cc = 0; cc < 2; ++cc) {
        int c = (g & 1) * 2 + cc;
#pragma unroll
        for (int r = 0; r < 4; ++r)
#pragma unroll
          for (int reg = 0; reg < 4; ++reg)
            ep[wr2 * 64 + r * 16 + kq * 4 + reg][cc * 16 + ln] = acc[r][c][reg];
      }
    }
    __syncthreads();
    int row = tid >> 1, half = tid & 1;
    int gn = n0 + row;
    if (gn < N) {
#pragma unroll
      for (int j = 0; j < 4; ++j)
        *(float4*)&outp[(size_t)gn * ostride + 32 * g + 16 * half + 4 * j] =
            *(const float4*)&ep[row][16 * half + 4 * j];
    }
  }
}

// ---------------- K3: per-query vectors w,u,y,c_b (256 thr, c-split) ------
__global__ __launch_bounds__(256) void k3_query(const float* __restrict__ qsrc,
                                                const float* __restrict__ qrel,
                                                const float* __restrict__ M,
                                                const float* __restrict__ Mt,
                                                float* __restrict__ wv,
                                                float* __restrict__ uv,
                                                float* __restrict__ yv,
                                                float* __restrict__ cb) {
  __shared__ float qcat[256];
  __shared__ float prt[5][256];
  __shared__ float red[128];
  int b = blockIdx.x, tid = threadIdx.x;
  int d = tid & 127, hc = tid >> 7;
  qcat[tid] = (tid < 128) ? qsrc[b * 128 + tid] : qrel[b * 128 + (tid - 128)];
  __syncthreads();
  float w = 0.f, u = 0.f, y = 0.f, t1 = 0.f, t2 = 0.f;
  for (int c = hc * 128; c < hc * 128 + 128; ++c) {
    float q = qcat[c];
    size_t row = (size_t)(256 + c) * 512;
    w += Mt[row + d] * q;
    u += M[row + d] * q;
    y += (Mt[row + 128 + d] + M[row + 128 + d]) * q;
    t1 += M[row + 256 + d] * q;
    t2 += M[row + 384 + d] * q;
  }
  prt[0][tid] = w; prt[1][tid] = u; prt[2][tid] = y;
  prt[3][tid] = t1; prt[4][tid] = t2;
  __syncthreads();
  if (tid < 128) {
    float wc_ = prt[0][d] + prt[0][128 + d];
    float uc = prt[1][d] + prt[1][128 + d];
    float yc = prt[2][d] + prt[2][128 + d];
    float t1c = prt[3][d] + prt[3][128 + d];
    float t2c = prt[4][d] + prt[4][128 + d];
    wv[b * 128 + d] = wc_;
    uv[b * 128 + d] = uc;
    yv[b * 128 + d] = yc;
    red[d] = qcat[d] * t1c + qcat[128 + d] * t2c;
  }
  __syncthreads();
  for (int s = 64; s > 0; s >>= 1) {
    if (tid < s) red[tid] += red[tid + s];
    __syncthreads();
  }
  if (tid == 0) cb[b] = red[0];
}

// ---------------- K4m: edge_const via MFMA (separate dispatch) ------------
__global__ __launch_bounds__(256) void k4m_mfma(
    const float* __restrict__ rel, const unsigned short* __restrict__ Mth,
    const unsigned short* __restrict__ Mtl, const float* __restrict__ yv,
    const float* __restrict__ cbp, float* __restrict__ ec) {
  __shared__ char pool[32768];
  unsigned short (*Ah)[32] = (unsigned short(*)[32])pool;
  unsigned short (*Al)[32] = (unsigned short(*)[32])(pool + 8192);
  unsigned short (*Bh)[32] = (unsigned short(*)[32])(pool + 16384);
  unsigned short (*Bl)[32] = (unsigned short(*)[32])(pool + 24576);
  float (*ep)[34] = (float(*)[34])pool;

  const int tid = threadIdx.x;
  const int lane = tid & 63;
  const int w = tid >> 6;
  const int wr2 = w >> 1, wc2 = w & 1;
  const int e0 = blockIdx.x * 128;
  const int b = e0 >> EPQ_SHIFT;

  float4v acc[4][4];
#pragma unroll
  for (int r = 0; r < 4; ++r)
#pragma unroll
    for (int c = 0; c < 4; ++c) acc[r][c] = (float4v){0.f, 0.f, 0.f, 0.f};

  const int sn = tid >> 1, shalf = tid & 1;
  for (int ch = 0; ch < 4; ++ch) {
    __syncthreads();
    {
      STAGE_A_F32(rel + (size_t)(e0 + sn) * 128 + ch * 32 + shalf * 16);
      size_t boff = (size_t)(128 + sn) * 512 + 128 + ch * 32 + shalf * 16;
      STAGE_B_BF16(Mth + boff, Mtl + boff);
    }
    __syncthreads();
    MFMA_CHUNK();
  }

  float part = 0.f;
  const int e_loc = tid >> 1, half = tid & 1;
  for (int g = 0; g < 4; ++g) {
    __syncthreads();
    if (wc2 == (g >> 1)) {
      int ln = lane & 15, kq = lane >> 4;
#pragma unroll
      for (int cc = 0; cc < 2; ++cc) {
        int c = (g & 1) * 2 + cc;
#pragma unroll
        for (int r = 0; r < 4; ++r)
#pragma unroll
          for (int reg = 0; reg < 4; ++reg)
            ep[wr2 * 64 + r * 16 + kq * 4 + reg][cc * 16 + ln] = acc[r][c][reg];
      }
    }
    __syncthreads();
    const float* rsrc = rel + (size_t)(e0 + e_loc) * 128 + 32 * g + 16 * half;
    const float* ysrc = yv + b * 128 + 32 * g + 16 * half;
#pragma unroll
    for (int j = 0; j < 4; ++j) {
      float4 q = *(const float4*)&ep[e_loc][16 * half + 4 * j];
      float4 rr = *(const float4*)&rsrc[4 * j];
      float4 yy = *(const float4*)&ysrc[4 * j];
      part += (q.x + yy.x) * rr.x + (q.y + yy.y) * rr.y +
              (q.z + yy.z) * rr.z + (q.w + yy.w) * rr.w;
    }
  }
  part += __shfl_xor(part, 1, 64);
  if ((tid & 1) == 0) ec[e0 + e_loc] = part + cbp[b];
}

// ---------------- K5: per-edge logits + segment max (16 edges/block) ------
__global__ __launch_bounds__(256) void k5_logits(const float* __restrict__ rel,
                                                 const float* __restrict__ hv,
                                                 const float* __restrict__ Tj,
                                                 const float* __restrict__ I1,
                                                 const float* __restrict__ wv,
                                                 const float* __restrict__ uv,
                                                 const float* __restrict__ ec,
                                                 const int* __restrict__ node_i,
                                                 const int* __restrict__ node_j,
                                                 float* __restrict__ logits,
                                                 unsigned* __restrict__ segkey) {
  __shared__ float wl[128];
  __shared__ float ul[128];
  int tid = threadIdx.x;
  int e0 = blockIdx.x * 16;
  int b = e0 >> EPQ_SHIFT;
  if (tid < 128) wl[tid] = wv[b * 128 + tid];
  else ul[tid - 128] = uv[b * 128 + (tid - 128)];
  __syncthreads();
  int lane = tid & 15, eg = tid >> 4;
  int e = e0 + eg;
  int i = node_i[e], j = node_j[e];
  int c0 = lane * 8;

  float rr[8], hi[8], hj[8], a0[8], a1[8], ii[8];
  *(float4*)&rr[0] = *(const float4*)&rel[(size_t)e * 128 + c0];
  *(float4*)&rr[4] = *(const float4*)&rel[(size_t)e * 128 + c0 + 4];
  *(float4*)&hi[0] = *(const float4*)&hv[(size_t)i * 128 + c0];
  *(float4*)&hi[4] = *(const float4*)&hv[(size_t)i * 128 + c0 + 4];
  *(float4*)&hj[0] = *(const float4*)&hv[(size_t)j * 128 + c0];
  *(float4*)&hj[4] = *(const float4*)&hv[(size_t)j * 128 + c0 + 4];
  *(float4*)&a0[0] = *(const float4*)&Tj[(size_t)j * 256 + c0];
  *(float4*)&a0[4] = *(const float4*)&Tj[(size_t)j * 256 + c0 + 4];
  *(float4*)&a1[0] = *(const float4*)&Tj[(size_t)j * 256 + 128 + c0];
  *(float4*)&a1[4] = *(const float4*)&Tj[(size_t)j * 256 + 128 + c0 + 4];
  *(float4*)&ii[0] = *(const float4*)&I1[(size_t)i * 128 + c0];
  *(float4*)&ii[4] = *(const float4*)&I1[(size_t)i * 128 + c0 + 4];

  float p = 0.f;
#pragma unroll
  for (int k = 0; k < 8; ++k) {
    p += hi[k] * a0[k];               // hvi . J0[j]
    p += rr[k] * (a1[k] + ii[k]);     // rel . (J1[j] + I1[i])
    p += hi[k] * wl[c0 + k];          // hvi . w_b
    p += hj[k] * ul[c0 + k];          // hvj . u_b
  }
#pragma unroll
  for (int m = 8; m >= 1; m >>= 1) p += __shfl_xor(p, m, 64);
  if (lane == 0) {
    float lg = p + ec[e];
    logits[e] = lg;
    atomicMax(&segkey[i], enc_f(lg));
  }
}

// ---------------- K6: ex = exp(logit - segmax), segment sum ----------------
__global__ void k6_exp(float* __restrict__ exb, const int* __restrict__ node_i,
                       const unsigned* __restrict__ segkey,
                       float* __restrict__ segsum, int E) {
  int e = blockIdx.x * 256 + threadIdx.x;
  if (e >= E) return;
  int i = node_i[e];
  float m = dec_f(segkey[i]);
  float ex = expf(exb[e] - m);
  exb[e] = ex;
  atomicAdd(&segsum[i], ex);
}

// ---------------- K7: per-query exact top-256 radix select + scatter-add ----
__global__ __launch_bounds__(256) void k7_topk(const float* __restrict__ exb,
                                               const int* __restrict__ node_i,
                                               const int* __restrict__ node_j,
                                               const float* __restrict__ segsum,
                                               const float* __restrict__ score,
                                               float* __restrict__ out) {
  __shared__ unsigned vals[2048];
  __shared__ unsigned hist[256];
  __shared__ unsigned sc[256];
  __shared__ unsigned tie_scan[256];
  __shared__ unsigned sel_info[2];
  int q = blockIdx.x, t = threadIdx.x;
  size_t base = (size_t)q * 2048;
#pragma unroll
  for (int l = 0; l < 8; ++l) {
    int el = t * 8 + l;
    int i = node_i[base + el];
    float tgt = exb[base + el] / segsum[i] * score[i];  // attn * src_score >= 0
    vals[el] = __float_as_uint(tgt);
  }
  __syncthreads();
  unsigned prefix = 0, need = KSEL;
  for (int pass = 3; pass >= 0; --pass) {
    hist[t] = 0;
    __syncthreads();
    int sh = pass * 8;
#pragma unroll
    for (int l = 0; l < 8; ++l) {
      unsigned v = vals[t * 8 + l];
      bool match = (pass == 3) || ((v >> (sh + 8)) == (prefix >> (sh + 8)));
      if (match) atomicAdd(&hist[(v >> sh) & 255u], 1u);
    }
    __syncthreads();
    sc[t] = hist[t];
    __syncthreads();
    for (int off = 1; off < 256; off <<= 1) {  // suffix-inclusive sum
      unsigned add = (t + off < 256) ? sc[t + off] : 0u;
      __syncthreads();
      sc[t] += add;
      __syncthreads();
    }
    unsigned above = sc[t] - hist[t];
    if (above < need && need <= sc[t]) {
      sel_info[0] = (unsigned)t;
      sel_info[1] = need - above;
    }
    __syncthreads();
    prefix |= sel_info[0] << sh;
    need = sel_info[1];
    __syncthreads();
  }
  unsigned T = prefix, r = need;
  unsigned lc = 0;
#pragma unroll
  for (int l = 0; l < 8; ++l)
    if (vals[t * 8 + l] == T) lc++;
  tie_scan[t] = lc;
  __syncthreads();
  unsigned own = lc;
  for (int off = 1; off < 256; off <<= 1) {
    unsigned add = (t >= off) ? tie_scan[t - off] : 0u;
    __syncthreads();
    tie_scan[t] += add;
    __syncthreads();
  }
  unsigned excl = tie_scan[t] - own;
  unsigned cnt = 0;
#pragma unroll
  for (int l = 0; l < 8; ++l) {
    int el = t * 8 + l;
    unsigned v = vals[el];
    bool take = false;
    if (v > T) take = true;
    else if (v == T) { if (excl + cnt < r) take = true; cnt++; }
    if (take) {
      int j = node_j[base + el];
      atomicAdd(&out[j], __uint_as_float(v));
    }
  }
}

// ---------------- host ----------------
extern "C" void kernel_launch(void* const* d_in, const int* in_sizes, int n_in,
                              void* d_out, int out_size, void* d_ws, size_t ws_size,
                              hipStream_t stream) {
  const float* score = (const float*)d_in[0];
  const float* hv    = (const float*)d_in[1];
  const float* rel   = (const float*)d_in[2];
  const float* qsrc  = (const float*)d_in[3];
  const float* qrel  = (const float*)d_in[4];
  const float* Wq    = (const float*)d_in[5];
  const float* Wk    = (const float*)d_in[6];
  const int* node_i  = (const int*)d_in[8];
  const int* node_j  = (const int*)d_in[9];

  const int N = in_sizes[0];            // 50000
  const int B = in_sizes[3] / 128;      // 64
  const int E = in_sizes[2] / 128;      // 131072

  float* ws = (float*)d_ws;
  float* M  = ws;
  float* Mt = M + 262144;
  float* Tj = Mt + 262144;              // [N][256] = J0|J1 packed
  float* I1 = Tj + (size_t)N * 256;
  float* wv = I1 + (size_t)N * 128;
  float* uv = wv + (size_t)B * 128;
  float* yv = uv + (size_t)B * 128;
  float* cb = yv + (size_t)B * 128;
  float* ec = cb + B;
  float* exb = ec + E;
  unsigned* segkey = (unsigned*)(exb + E);
  float* segsum = (float*)(segkey + N);
  unsigned short* Mh  = (unsigned short*)(segsum + N);
  unsigned short* Ml  = Mh + 262144;
  unsigned short* Mth = Ml + 262144;
  unsigned short* Mtl = Mth + 262144;
  float* out = (float*)d_out;

  k1_gemmM<<<dim3(8, 8), 256, 0, stream>>>(Wq, Wk, M, Mt, Mh, Ml, Mth, Mtl,
                                           out, segsum, segkey, N);
  k2m_mfma<<<dim3(3, (N + 127) / 128), 256, 0, stream>>>(hv, Mh, Ml, Mth, Mtl,
                                                         Tj, I1, N);
  k3_query<<<B, 256, 0, stream>>>(qsrc, qrel, M, Mt, wv, uv, yv, cb);
  k4m_mfma<<<E / 128, 256, 0, stream>>>(rel, Mth, Mtl, yv, cb, ec);
  k5_logits<<<E / 16, 256, 0, stream>>>(rel, hv, Tj, I1, wv, uv, ec,
                                        node_i, node_j, exb, segkey);
  k6_exp<<<(E + 255) / 256, 256, 0, stream>>>(exb, node_i, segkey, segsum, E);
  k7_topk<<<B, 256, 0, stream>>>(exb, node_i, node_j, segsum, score, out);
}

// Round 14
// 236.248 us; speedup vs baseline: 1.3658x; 1.0045x over previous
//
#include <hip/hip_runtime.h>
#include <cstddef>

// Problem constants (fixed by the reference)
#define EPQ_SHIFT 11       // EPQ = 2048
#define KSEL 256

typedef __attribute__((ext_vector_type(8))) short short8v;   // 8 bf16
typedef __attribute__((ext_vector_type(4))) float float4v;   // MFMA acc

__device__ __forceinline__ unsigned enc_f(float f) {
  unsigned u = __float_as_uint(f);
  return (u & 0x80000000u) ? ~u : (u | 0x80000000u);
}
__device__ __forceinline__ float dec_f(unsigned k) {
  unsigned u = (k & 0x80000000u) ? (k ^ 0x80000000u) : ~k;
  return __uint_as_float(u);
}
__device__ __forceinline__ unsigned short f2bf(float x) {  // RNE f32->bf16
  unsigned u = __float_as_uint(x);
  return (unsigned short)((u + 0x7FFFu + ((u >> 16) & 1u)) >> 16);
}

// ---------------- K1: init buffers + M = Wq^T Wk + Mt + bf16 splits -------
__global__ __launch_bounds__(256) void k1_gemmM(
    const float* __restrict__ Wq, const float* __restrict__ Wk,
    float* __restrict__ M, float* __restrict__ Mt,
    unsigned short* __restrict__ Mh, unsigned short* __restrict__ Ml,
    unsigned short* __restrict__ Mth, unsigned short* __restrict__ Mtl,
    float* __restrict__ outz, float* __restrict__ segsum,
    unsigned* __restrict__ segkey, int N) {
  int tid = threadIdx.x;
  {  // folded k0: zero out/segsum/segkey
    int bid = blockIdx.y * gridDim.x + blockIdx.x;
    for (int idx = bid * 256 + tid; idx < N; idx += 16384) {
      outz[idx] = 0.f;
      segsum[idx] = 0.f;
      segkey[idx] = 0u;
    }
  }
  __shared__ float as[16][64];
  __shared__ float bs[16][64];
  int tx = tid & 15, ty = tid >> 4;
  int c1b = blockIdx.y * 64, c2b = blockIdx.x * 64;
  float acc[4][4] = {};
  for (int k0 = 0; k0 < 512; k0 += 16) {
#pragma unroll
    for (int l = 0; l < 4; ++l) {
      int lin = tid + l * 256;
      int kk = lin >> 6, c = lin & 63;
      as[kk][c] = Wq[(k0 + kk) * 512 + c1b + c];
      bs[kk][c] = Wk[(k0 + kk) * 512 + c2b + c];
    }
    __syncthreads();
#pragma unroll
    for (int kk = 0; kk < 16; ++kk) {
      float a[4], b[4];
#pragma unroll
      for (int m = 0; m < 4; ++m) a[m] = as[kk][ty * 4 + m];
#pragma unroll
      for (int n = 0; n < 4; ++n) b[n] = bs[kk][tx * 4 + n];
#pragma unroll
      for (int m = 0; m < 4; ++m)
#pragma unroll
        for (int n = 0; n < 4; ++n) acc[m][n] += a[m] * b[n];
    }
    __syncthreads();
  }
#pragma unroll
  for (int m = 0; m < 4; ++m)
#pragma unroll
    for (int n = 0; n < 4; ++n) {
      int c1 = c1b + ty * 4 + m, c2 = c2b + tx * 4 + n;
      float v = acc[m][n];
      M[c1 * 512 + c2] = v;
      Mt[c2 * 512 + c1] = v;
      unsigned short h = f2bf(v);
      unsigned short lo = f2bf(v - __uint_as_float((unsigned)h << 16));
      Mh[c1 * 512 + c2] = h;
      Ml[c1 * 512 + c2] = lo;
      Mth[c2 * 512 + c1] = h;
      Mtl[c2 * 512 + c1] = lo;
    }
}

// ===== MFMA staging/compute macros (128-row variant, used by k4m) =====
#define STAGE_A_F32(SRC_PTR)                                                 \
  {                                                                          \
    const float* s = (SRC_PTR);                                              \
    float4 v0 = *(const float4*)&s[0];                                       \
    float4 v1 = *(const float4*)&s[4];                                       \
    float4 v2 = *(const float4*)&s[8];                                       \
    float4 v3 = *(const float4*)&s[12];                                      \
    float vv[16] = {v0.x, v0.y, v0.z, v0.w, v1.x, v1.y, v1.z, v1.w,          \
                    v2.x, v2.y, v2.z, v2.w, v3.x, v3.y, v3.z, v3.w};         \
    unsigned hw[8], lw[8];                                                   \
    _Pragma("unroll") for (int j = 0; j < 8; ++j) {                          \
      unsigned short h0 = f2bf(vv[2 * j]);                                   \
      unsigned short h1 = f2bf(vv[2 * j + 1]);                               \
      unsigned short l0 =                                                    \
          f2bf(vv[2 * j] - __uint_as_float((unsigned)h0 << 16));             \
      unsigned short l1 =                                                    \
          f2bf(vv[2 * j + 1] - __uint_as_float((unsigned)h1 << 16));         \
      hw[j] = (unsigned)h0 | ((unsigned)h1 << 16);                           \
      lw[j] = (unsigned)l0 | ((unsigned)l1 << 16);                           \
    }                                                                        \
    int sw = (sn >> 1) & 3;                                                  \
    int g0 = (shalf * 2) ^ sw, g1 = (shalf * 2 + 1) ^ sw;                    \
    *(uint4*)&Ah[sn][g0 * 8] = make_uint4(hw[0], hw[1], hw[2], hw[3]);       \
    *(uint4*)&Ah[sn][g1 * 8] = make_uint4(hw[4], hw[5], hw[6], hw[7]);       \
    *(uint4*)&Al[sn][g0 * 8] = make_uint4(lw[0], lw[1], lw[2], lw[3]);       \
    *(uint4*)&Al[sn][g1 * 8] = make_uint4(lw[4], lw[5], lw[6], lw[7]);       \
  }

#define STAGE_B_BF16(HSRC, LSRC)                                             \
  {                                                                          \
    const unsigned short* sh_ = (HSRC);                                      \
    const unsigned short* sl_ = (LSRC);                                      \
    uint4 q0 = *(const uint4*)&sh_[0];                                       \
    uint4 q1 = *(const uint4*)&sh_[8];                                       \
    uint4 p0 = *(const uint4*)&sl_[0];                                       \
    uint4 p1 = *(const uint4*)&sl_[8];                                       \
    int sw = (sn >> 1) & 3;                                                  \
    int g0 = (shalf * 2) ^ sw, g1 = (shalf * 2 + 1) ^ sw;                    \
    *(uint4*)&Bh[sn][g0 * 8] = q0;                                           \
    *(uint4*)&Bh[sn][g1 * 8] = q1;                                           \
    *(uint4*)&Bl[sn][g0 * 8] = p0;                                           \
    *(uint4*)&Bl[sn][g1 * 8] = p1;                                           \
  }

#define MFMA_CHUNK()                                                         \
  {                                                                          \
    int ln = lane & 15, kq = lane >> 4;                                      \
    short8v ah[4], al[4];                                                    \
    _Pragma("unroll") for (int r = 0; r < 4; ++r) {                          \
      int row = wr2 * 64 + r * 16 + ln;                                      \
      int gg = kq ^ ((row >> 1) & 3);                                        \
      ah[r] = *(const short8v*)&Ah[row][gg * 8];                             \
      al[r] = *(const short8v*)&Al[row][gg * 8];                             \
    }                                                                        \
    _Pragma("unroll") for (int c = 0; c < 4; ++c) {                          \
      int col = wc2 * 64 + c * 16 + ln;                                      \
      int gg = kq ^ ((col >> 1) & 3);                                        \
      short8v bh = *(const short8v*)&Bh[col][gg * 8];                        \
      short8v bl = *(const short8v*)&Bl[col][gg * 8];                        \
      _Pragma("unroll") for (int r = 0; r < 4; ++r) {                        \
        acc[r][c] = __builtin_amdgcn_mfma_f32_16x16x32_bf16(                 \
            ah[r], bh, acc[r][c], 0, 0, 0);                                  \
        acc[r][c] = __builtin_amdgcn_mfma_f32_16x16x32_bf16(                 \
            ah[r], bl, acc[r][c], 0, 0, 0);                                  \
        acc[r][c] = __builtin_amdgcn_mfma_f32_16x16x32_bf16(                 \
            al[r], bh, acc[r][c], 0, 0, 0);                                  \
      }                                                                      \
    }                                                                        \
  }

// ---------------- K2m3: ALL THREE projections in one pass (64-node tile) --
// A (hv) staged once in LDS bf16 hi/lo for all 4 K-chunks; per projection p
// the B tile is restaged from L2-resident M tables. Outputs Tj=[J0|J1], I1.
__global__ __launch_bounds__(256) void k2m3_mfma(
    const float* __restrict__ hv, const unsigned short* __restrict__ Mh,
    const unsigned short* __restrict__ Ml, const unsigned short* __restrict__ Mth,
    const unsigned short* __restrict__ Mtl, float* __restrict__ Tj,
    float* __restrict__ I1, int N) {
  __shared__ char pool[49152];
  unsigned short (*Ah4)[64][32] = (unsigned short(*)[64][32])pool;           // 16KB
  unsigned short (*Al4)[64][32] = (unsigned short(*)[64][32])(pool + 16384); // 16KB
  unsigned short (*Bh)[32] = (unsigned short(*)[32])(pool + 32768);          // 8KB
  unsigned short (*Bl)[32] = (unsigned short(*)[32])(pool + 40960);          // 8KB
  float (*ep)[34] = (float(*)[34])(pool + 32768);  // overlays B (8.5KB)

  const int tid = threadIdx.x;
  const int lane = tid & 63;
  const int w = tid >> 6;
  const int wr2 = w >> 1, wc2 = w & 1;   // wave tile: 32 nodes x 64 cols
  const int n0 = blockIdx.x * 64;

  // ---- stage A: hv[n0..n0+64][0..128] -> bf16 hi/lo, all 4 chunks ----
  {
    const int n = tid >> 2, q = tid & 3;
    int gn = n0 + n;
    gn = gn < N ? gn : N - 1;
    const int g = q ^ ((n >> 1) & 3);
#pragma unroll
    for (int ch = 0; ch < 4; ++ch) {
      float4 v0 = *(const float4*)&hv[(size_t)gn * 128 + ch * 32 + q * 8];
      float4 v1 = *(const float4*)&hv[(size_t)gn * 128 + ch * 32 + q * 8 + 4];
      float vv[8] = {v0.x, v0.y, v0.z, v0.w, v1.x, v1.y, v1.z, v1.w};
      unsigned hw[4], lw[4];
#pragma unroll
      for (int j = 0; j < 4; ++j) {
        unsigned short h0 = f2bf(vv[2 * j]);
        unsigned short h1 = f2bf(vv[2 * j + 1]);
        unsigned short l0 = f2bf(vv[2 * j] - __uint_as_float((unsigned)h0 << 16));
        unsigned short l1 = f2bf(vv[2 * j + 1] - __uint_as_float((unsigned)h1 << 16));
        hw[j] = (unsigned)h0 | ((unsigned)h1 << 16);
        lw[j] = (unsigned)l0 | ((unsigned)l1 << 16);
      }
      *(uint4*)&Ah4[ch][n][g * 8] = make_uint4(hw[0], hw[1], hw[2], hw[3]);
      *(uint4*)&Al4[ch][n][g * 8] = make_uint4(lw[0], lw[1], lw[2], lw[3]);
    }
  }

  for (int p = 0; p < 3; ++p) {
    const unsigned short* bhs = (p == 2) ? Mth : Mh;
    const unsigned short* bls = (p == 2) ? Mtl : Ml;
    const int borow = (p == 0) ? 0 : 128;
    float* outp = (p == 0) ? Tj : (p == 1) ? (Tj + 128) : I1;
    const size_t ostride = (p == 2) ? 128 : 256;

    float4v acc[2][4];
#pragma unroll
    for (int r = 0; r < 2; ++r)
#pragma unroll
      for (int c = 0; c < 4; ++c) acc[r][c] = (float4v){0.f, 0.f, 0.f, 0.f};

    for (int ch = 0; ch < 4; ++ch) {
      __syncthreads();  // prev MFMA / epilogue readers done with B/ep region
      {                 // stage B[d][c] = M[borow+d][ch*32+c] (hi/lo)
        const int d = tid >> 1, half = tid & 1;
        size_t boff = (size_t)(borow + d) * 512 + ch * 32 + half * 16;
        uint4 q0 = *(const uint4*)&bhs[boff];
        uint4 q1 = *(const uint4*)&bhs[boff + 8];
        uint4 p0 = *(const uint4*)&bls[boff];
        uint4 p1 = *(const uint4*)&bls[boff + 8];
        int sw = (d >> 1) & 3;
        int g0 = (half * 2) ^ sw, g1 = (half * 2 + 1) ^ sw;
        *(uint4*)&Bh[d][g0 * 8] = q0;
        *(uint4*)&Bh[d][g1 * 8] = q1;
        *(uint4*)&Bl[d][g0 * 8] = p0;
        *(uint4*)&Bl[d][g1 * 8] = p1;
      }
      __syncthreads();
      {
        int ln = lane & 15, kq = lane >> 4;
        short8v ah[2], al[2];
#pragma unroll
        for (int r = 0; r < 2; ++r) {
          int row = wr2 * 32 + r * 16 + ln;
          int gg = kq ^ ((row >> 1) & 3);
          ah[r] = *(const short8v*)&Ah4[ch][row][gg * 8];
          al[r] = *(const short8v*)&Al4[ch][row][gg * 8];
        }
#pragma unroll
        for (int c = 0; c < 4; ++c) {
          int col = wc2 * 64 + c * 16 + ln;
          int gg = kq ^ ((col >> 1) & 3);
          short8v bh = *(const short8v*)&Bh[col][gg * 8];
          short8v bl = *(const short8v*)&Bl[col][gg * 8];
#pragma unroll
          for (int r = 0; r < 2; ++r) {
            acc[r][c] = __builtin_amdgcn_mfma_f32_16x16x32_bf16(ah[r], bh,
                                                                acc[r][c], 0, 0, 0);
            acc[r][c] = __builtin_amdgcn_mfma_f32_16x16x32_bf16(ah[r], bl,
                                                                acc[r][c], 0, 0, 0);
            acc[r][c] = __builtin_amdgcn_mfma_f32_16x16x32_bf16(al[r], bh,
                                                                acc[r][c], 0, 0, 0);
          }
        }
      }
    }

    // epilogue: 4 col-groups of 32, transpose via ep (overlays B region)
    for (int g = 0; g < 4; ++g) {
      __syncthreads();
      if (wc2 == (g >> 1)) {
        int ln = lane & 15, kq = lane >> 4;
#pragma unroll
        for (int cc = 0; cc < 2; ++cc) {
          int c = (g & 1) * 2 + cc;
#pragma unroll
          for (int r = 0; r < 2; ++r)
#pragma unroll
            for (int reg = 0; reg < 4; ++reg)
              ep[wr2 * 32 + r * 16 + kq * 4 + reg][cc * 16 + ln] = acc[r][c][reg];
        }
      }
      __syncthreads();
      int row = tid >> 2, part = tid & 3;
      int gn = n0 + row;
      if (gn < N) {
        *(float4*)&outp[(size_t)gn * ostride + g * 32 + part * 8] =
            *(const float4*)&ep[row][part * 8];
        *(float4*)&outp[(size_t)gn * ostride + g * 32 + part * 8 + 4] =
            *(const float4*)&ep[row][part * 8 + 4];
      }
    }
  }
}

// ---------------- K3: per-query vectors w,u,y,c_b (256 thr, c-split) ------
__global__ __launch_bounds__(256) void k3_query(const float* __restrict__ qsrc,
                                                const float* __restrict__ qrel,
                                                const float* __restrict__ M,
                                                const float* __restrict__ Mt,
                                                float* __restrict__ wv,
                                                float* __restrict__ uv,
                                                float* __restrict__ yv,
                                                float* __restrict__ cb) {
  __shared__ float qcat[256];
  __shared__ float prt[5][256];
  __shared__ float red[128];
  int b = blockIdx.x, tid = threadIdx.x;
  int d = tid & 127, hc = tid >> 7;
  qcat[tid] = (tid < 128) ? qsrc[b * 128 + tid] : qrel[b * 128 + (tid - 128)];
  __syncthreads();
  float w = 0.f, u = 0.f, y = 0.f, t1 = 0.f, t2 = 0.f;
  for (int c = hc * 128; c < hc * 128 + 128; ++c) {
    float q = qcat[c];
    size_t row = (size_t)(256 + c) * 512;
    w += Mt[row + d] * q;
    u += M[row + d] * q;
    y += (Mt[row + 128 + d] + M[row + 128 + d]) * q;
    t1 += M[row + 256 + d] * q;
    t2 += M[row + 384 + d] * q;
  }
  prt[0][tid] = w; prt[1][tid] = u; prt[2][tid] = y;
  prt[3][tid] = t1; prt[4][tid] = t2;
  __syncthreads();
  if (tid < 128) {
    float wc_ = prt[0][d] + prt[0][128 + d];
    float uc = prt[1][d] + prt[1][128 + d];
    float yc = prt[2][d] + prt[2][128 + d];
    float t1c = prt[3][d] + prt[3][128 + d];
    float t2c = prt[4][d] + prt[4][128 + d];
    wv[b * 128 + d] = wc_;
    uv[b * 128 + d] = uc;
    yv[b * 128 + d] = yc;
    red[d] = qcat[d] * t1c + qcat[128 + d] * t2c;
  }
  __syncthreads();
  for (int s = 64; s > 0; s >>= 1) {
    if (tid < s) red[tid] += red[tid + s];
    __syncthreads();
  }
  if (tid == 0) cb[b] = red[0];
}

// ---------------- K4m: edge_const via MFMA (separate dispatch) ------------
__global__ __launch_bounds__(256) void k4m_mfma(
    const float* __restrict__ rel, const unsigned short* __restrict__ Mth,
    const unsigned short* __restrict__ Mtl, const float* __restrict__ yv,
    const float* __restrict__ cbp, float* __restrict__ ec) {
  __shared__ char pool[32768];
  unsigned short (*Ah)[32] = (unsigned short(*)[32])pool;
  unsigned short (*Al)[32] = (unsigned short(*)[32])(pool + 8192);
  unsigned short (*Bh)[32] = (unsigned short(*)[32])(pool + 16384);
  unsigned short (*Bl)[32] = (unsigned short(*)[32])(pool + 24576);
  float (*ep)[34] = (float(*)[34])pool;

  const int tid = threadIdx.x;
  const int lane = tid & 63;
  const int w = tid >> 6;
  const int wr2 = w >> 1, wc2 = w & 1;
  const int e0 = blockIdx.x * 128;
  const int b = e0 >> EPQ_SHIFT;

  float4v acc[4][4];
#pragma unroll
  for (int r = 0; r < 4; ++r)
#pragma unroll
    for (int c = 0; c < 4; ++c) acc[r][c] = (float4v){0.f, 0.f, 0.f, 0.f};

  const int sn = tid >> 1, shalf = tid & 1;
  for (int ch = 0; ch < 4; ++ch) {
    __syncthreads();
    {
      STAGE_A_F32(rel + (size_t)(e0 + sn) * 128 + ch * 32 + shalf * 16);
      size_t boff = (size_t)(128 + sn) * 512 + 128 + ch * 32 + shalf * 16;
      STAGE_B_BF16(Mth + boff, Mtl + boff);
    }
    __syncthreads();
    MFMA_CHUNK();
  }

  float part = 0.f;
  const int e_loc = tid >> 1, half = tid & 1;
  for (int g = 0; g < 4; ++g) {
    __syncthreads();
    if (wc2 == (g >> 1)) {
      int ln = lane & 15, kq = lane >> 4;
#pragma unroll
      for (int cc = 0; cc < 2; ++cc) {
        int c = (g & 1) * 2 + cc;
#pragma unroll
        for (int r = 0; r < 4; ++r)
#pragma unroll
          for (int reg = 0; reg < 4; ++reg)
            ep[wr2 * 64 + r * 16 + kq * 4 + reg][cc * 16 + ln] = acc[r][c][reg];
      }
    }
    __syncthreads();
    const float* rsrc = rel + (size_t)(e0 + e_loc) * 128 + 32 * g + 16 * half;
    const float* ysrc = yv + b * 128 + 32 * g + 16 * half;
#pragma unroll
    for (int j = 0; j < 4; ++j) {
      float4 q = *(const float4*)&ep[e_loc][16 * half + 4 * j];
      float4 rr = *(const float4*)&rsrc[4 * j];
      float4 yy = *(const float4*)&ysrc[4 * j];
      part += (q.x + yy.x) * rr.x + (q.y + yy.y) * rr.y +
              (q.z + yy.z) * rr.z + (q.w + yy.w) * rr.w;
    }
  }
  part += __shfl_xor(part, 1, 64);
  if ((tid & 1) == 0) ec[e0 + e_loc] = part + cbp[b];
}

// ---------------- K5: per-edge logits + segment max (16 edges/block) ------
__global__ __launch_bounds__(256) void k5_logits(const float* __restrict__ rel,
                                                 const float* __restrict__ hv,
                                                 const float* __restrict__ Tj,
                                                 const float* __restrict__ I1,
                                                 const float* __restrict__ wv,
                                                 const float* __restrict__ uv,
                                                 const float* __restrict__ ec,
                                                 const int* __restrict__ node_i,
                                                 const int* __restrict__ node_j,
                                                 float* __restrict__ logits,
                                                 unsigned* __restrict__ segkey,
                                                 int e_base) {
  __shared__ float wl[128];
  __shared__ float ul[128];
  int tid = threadIdx.x;
  int e0 = e_base + blockIdx.x * 16;
  int b = e0 >> EPQ_SHIFT;
  if (tid < 128) wl[tid] = wv[b * 128 + tid];
  else ul[tid - 128] = uv[b * 128 + (tid - 128)];
  __syncthreads();
  int lane = tid & 15, eg = tid >> 4;
  int e = e0 + eg;
  int i = node_i[e], j = node_j[e];
  int c0 = lane * 8;

  float rr[8], hi[8], hj[8], a0[8], a1[8], ii[8];
  *(float4*)&rr[0] = *(const float4*)&rel[(size_t)e * 128 + c0];
  *(float4*)&rr[4] = *(const float4*)&rel[(size_t)e * 128 + c0 + 4];
  *(float4*)&hi[0] = *(const float4*)&hv[(size_t)i * 128 + c0];
  *(float4*)&hi[4] = *(const float4*)&hv[(size_t)i * 128 + c0 + 4];
  *(float4*)&hj[0] = *(const float4*)&hv[(size_t)j * 128 + c0];
  *(float4*)&hj[4] = *(const float4*)&hv[(size_t)j * 128 + c0 + 4];
  *(float4*)&a0[0] = *(const float4*)&Tj[(size_t)j * 256 + c0];
  *(float4*)&a0[4] = *(const float4*)&Tj[(size_t)j * 256 + c0 + 4];
  *(float4*)&a1[0] = *(const float4*)&Tj[(size_t)j * 256 + 128 + c0];
  *(float4*)&a1[4] = *(const float4*)&Tj[(size_t)j * 256 + 128 + c0 + 4];
  *(float4*)&ii[0] = *(const float4*)&I1[(size_t)i * 128 + c0];
  *(float4*)&ii[4] = *(const float4*)&I1[(size_t)i * 128 + c0 + 4];

  float p = 0.f;
#pragma unroll
  for (int k = 0; k < 8; ++k) {
    p += hi[k] * a0[k];               // hvi . J0[j]
    p += rr[k] * (a1[k] + ii[k]);     // rel . (J1[j] + I1[i])
    p += hi[k] * wl[c0 + k];          // hvi . w_b
    p += hj[k] * ul[c0 + k];          // hvj . u_b
  }
#pragma unroll
  for (int m = 8; m >= 1; m >>= 1) p += __shfl_xor(p, m, 64);
  if (lane == 0) {
    float lg = p + ec[e];
    logits[e] = lg;
    atomicMax(&segkey[i], enc_f(lg));
  }
}

// ---------------- K6: ex = exp(logit - segmax), segment sum ----------------
__global__ void k6_exp(float* __restrict__ exb, const int* __restrict__ node_i,
                       const unsigned* __restrict__ segkey,
                       float* __restrict__ segsum, int E) {
  int e = blockIdx.x * 256 + threadIdx.x;
  if (e >= E) return;
  int i = node_i[e];
  float m = dec_f(segkey[i]);
  float ex = expf(exb[e] - m);
  exb[e] = ex;
  atomicAdd(&segsum[i], ex);
}

// ---------------- K7: per-query exact top-256 radix select + scatter-add ----
__global__ __launch_bounds__(256) void k7_topk(const float* __restrict__ exb,
                                               const int* __restrict__ node_i,
                                               const int* __restrict__ node_j,
                                               const float* __restrict__ segsum,
                                               const float* __restrict__ score,
                                               float* __restrict__ out) {
  __shared__ unsigned vals[2048];
  __shared__ unsigned hist[256];
  __shared__ unsigned sc[256];
  __shared__ unsigned tie_scan[256];
  __shared__ unsigned sel_info[2];
  int q = blockIdx.x, t = threadIdx.x;
  size_t base = (size_t)q * 2048;
#pragma unroll
  for (int l = 0; l < 8; ++l) {
    int el = t * 8 + l;
    int i = node_i[base + el];
    float tgt = exb[base + el] / segsum[i] * score[i];  // attn * src_score >= 0
    vals[el] = __float_as_uint(tgt);
  }
  __syncthreads();
  unsigned prefix = 0, need = KSEL;
  for (int pass = 3; pass >= 0; --pass) {
    hist[t] = 0;
    __syncthreads();
    int sh = pass * 8;
#pragma unroll
    for (int l = 0; l < 8; ++l) {
      unsigned v = vals[t * 8 + l];
      bool match = (pass == 3) || ((v >> (sh + 8)) == (prefix >> (sh + 8)));
      if (match) atomicAdd(&hist[(v >> sh) & 255u], 1u);
    }
    __syncthreads();
    sc[t] = hist[t];
    __syncthreads();
    for (int off = 1; off < 256; off <<= 1) {  // suffix-inclusive sum
      unsigned add = (t + off < 256) ? sc[t + off] : 0u;
      __syncthreads();
      sc[t] += add;
      __syncthreads();
    }
    unsigned above = sc[t] - hist[t];
    if (above < need && need <= sc[t]) {
      sel_info[0] = (unsigned)t;
      sel_info[1] = need - above;
    }
    __syncthreads();
    prefix |= sel_info[0] << sh;
    need = sel_info[1];
    __syncthreads();
  }
  unsigned T = prefix, r = need;
  unsigned lc = 0;
#pragma unroll
  for (int l = 0; l < 8; ++l)
    if (vals[t * 8 + l] == T) lc++;
  tie_scan[t] = lc;
  __syncthreads();
  unsigned own = lc;
  for (int off = 1; off < 256; off <<= 1) {
    unsigned add = (t >= off) ? tie_scan[t - off] : 0u;
    __syncthreads();
    tie_scan[t] += add;
    __syncthreads();
  }
  unsigned excl = tie_scan[t] - own;
  unsigned cnt = 0;
#pragma unroll
  for (int l = 0; l < 8; ++l) {
    int el = t * 8 + l;
    unsigned v = vals[el];
    bool take = false;
    if (v > T) take = true;
    else if (v == T) { if (excl + cnt < r) take = true; cnt++; }
    if (take) {
      int j = node_j[base + el];
      atomicAdd(&out[j], __uint_as_float(v));
    }
  }
}

// ---------------- host ----------------
extern "C" void kernel_launch(void* const* d_in, const int* in_sizes, int n_in,
                              void* d_out, int out_size, void* d_ws, size_t ws_size,
                              hipStream_t stream) {
  const float* score = (const float*)d_in[0];
  const float* hv    = (const float*)d_in[1];
  const float* rel   = (const float*)d_in[2];
  const float* qsrc  = (const float*)d_in[3];
  const float* qrel  = (const float*)d_in[4];
  const float* Wq    = (const float*)d_in[5];
  const float* Wk    = (const float*)d_in[6];
  const int* node_i  = (const int*)d_in[8];
  const int* node_j  = (const int*)d_in[9];

  const int N = in_sizes[0];            // 50000
  const int B = in_sizes[3] / 128;      // 64
  const int E = in_sizes[2] / 128;      // 131072

  float* ws = (float*)d_ws;
  float* M  = ws;
  float* Mt = M + 262144;
  float* Tj = Mt + 262144;              // [N][256] = J0|J1 packed
  float* I1 = Tj + (size_t)N * 256;
  float* wv = I1 + (size_t)N * 128;
  float* uv = wv + (size_t)B * 128;
  float* yv = uv + (size_t)B * 128;
  float* cb = yv + (size_t)B * 128;
  float* ec = cb + B;
  float* exb = ec + E;
  unsigned* segkey = (unsigned*)(exb + E);
  float* segsum = (float*)(segkey + N);
  unsigned short* Mh  = (unsigned short*)(segsum + N);
  unsigned short* Ml  = Mh + 262144;
  unsigned short* Mth = Ml + 262144;
  unsigned short* Mtl = Mth + 262144;
  float* out = (float*)d_out;

  k1_gemmM<<<dim3(8, 8), 256, 0, stream>>>(Wq, Wk, M, Mt, Mh, Ml, Mth, Mtl,
                                           out, segsum, segkey, N);
  k2m3_mfma<<<(N + 63) / 64, 256, 0, stream>>>(hv, Mh, Ml, Mth, Mtl, Tj, I1, N);
  k3_query<<<B, 256, 0, stream>>>(qsrc, qrel, M, Mt, wv, uv, yv, cb);
  k4m_mfma<<<E / 128, 256, 0, stream>>>(rel, Mth, Mtl, yv, cb, ec);
  k5_logits<<<E / 32, 256, 0, stream>>>(rel, hv, Tj, I1, wv, uv, ec,
                                        node_i, node_j, exb, segkey, 0);
  k5_logits<<<E / 32, 256, 0, stream>>>(rel, hv, Tj, I1, wv, uv, ec,
                                        node_i, node_j, exb, segkey, E / 2);
  k6_exp<<<(E + 255) / 256, 256, 0, stream>>>(exb, node_i, segkey, segsum, E);
  k7_topk<<<B, 256, 0, stream>>>(exb, node_i, node_j, segsum, score, out);
}

// Round 15
// 216.226 us; speedup vs baseline: 1.4923x; 1.0926x over previous
//
#include <hip/hip_runtime.h>
#include <cstddef>

// Problem constants (fixed by the reference)
#define EPQ_SHIFT 11       // EPQ = 2048
#define KSEL 256

typedef __attribute__((ext_vector_type(8))) short short8v;   // 8 bf16
typedef __attribute__((ext_vector_type(4))) float float4v;   // MFMA acc

__device__ __forceinline__ unsigned enc_f(float f) {
  unsigned u = __float_as_uint(f);
  return (u & 0x80000000u) ? ~u : (u | 0x80000000u);
}
__device__ __forceinline__ float dec_f(unsigned k) {
  unsigned u = (k & 0x80000000u) ? (k ^ 0x80000000u) : ~k;
  return __uint_as_float(u);
}
__device__ __forceinline__ unsigned short f2bf(float x) {  // RNE f32->bf16
  unsigned u = __float_as_uint(x);
  return (unsigned short)((u + 0x7FFFu + ((u >> 16) & 1u)) >> 16);
}

// ---------------- K1: init buffers + M = Wq^T Wk + Mt + bf16 splits -------
__global__ __launch_bounds__(256) void k1_gemmM(
    const float* __restrict__ Wq, const float* __restrict__ Wk,
    float* __restrict__ M, float* __restrict__ Mt,
    unsigned short* __restrict__ Mh, unsigned short* __restrict__ Ml,
    unsigned short* __restrict__ Mth, unsigned short* __restrict__ Mtl,
    float* __restrict__ outz, float* __restrict__ segsum,
    unsigned* __restrict__ segkey, int N) {
  int tid = threadIdx.x;
  {  // folded k0: zero out/segsum/segkey
    int bid = blockIdx.y * gridDim.x + blockIdx.x;
    for (int idx = bid * 256 + tid; idx < N; idx += 16384) {
      outz[idx] = 0.f;
      segsum[idx] = 0.f;
      segkey[idx] = 0u;
    }
  }
  __shared__ float as[16][64];
  __shared__ float bs[16][64];
  int tx = tid & 15, ty = tid >> 4;
  int c1b = blockIdx.y * 64, c2b = blockIdx.x * 64;
  float acc[4][4] = {};
  for (int k0 = 0; k0 < 512; k0 += 16) {
#pragma unroll
    for (int l = 0; l < 4; ++l) {
      int lin = tid + l * 256;
      int kk = lin >> 6, c = lin & 63;
      as[kk][c] = Wq[(k0 + kk) * 512 + c1b + c];
      bs[kk][c] = Wk[(k0 + kk) * 512 + c2b + c];
    }
    __syncthreads();
#pragma unroll
    for (int kk = 0; kk < 16; ++kk) {
      float a[4], b[4];
#pragma unroll
      for (int m = 0; m < 4; ++m) a[m] = as[kk][ty * 4 + m];
#pragma unroll
      for (int n = 0; n < 4; ++n) b[n] = bs[kk][tx * 4 + n];
#pragma unroll
      for (int m = 0; m < 4; ++m)
#pragma unroll
        for (int n = 0; n < 4; ++n) acc[m][n] += a[m] * b[n];
    }
    __syncthreads();
  }
#pragma unroll
  for (int m = 0; m < 4; ++m)
#pragma unroll
    for (int n = 0; n < 4; ++n) {
      int c1 = c1b + ty * 4 + m, c2 = c2b + tx * 4 + n;
      float v = acc[m][n];
      M[c1 * 512 + c2] = v;
      Mt[c2 * 512 + c1] = v;
      unsigned short h = f2bf(v);
      unsigned short lo = f2bf(v - __uint_as_float((unsigned)h << 16));
      Mh[c1 * 512 + c2] = h;
      Ml[c1 * 512 + c2] = lo;
      Mth[c2 * 512 + c1] = h;
      Mtl[c2 * 512 + c1] = lo;
    }
}

// ===== 64-row-tile MFMA skeleton (shared by k2m / k4m) =====
// Block 256 thr = 4 waves; tile 64 rows x 128 cols; wave w: wr2=w>>1 owns
// 32-row half, wc2=w&1 owns 64-col half; acc[2][4] of 16x16 frags.
// Per K-chunk(32): fused staging phase — every thread stages its A part
// (8 f32 -> bf16 hi/lo, 16B-group swizzle g=q^((row>>1)&3)) AND its B part
// (16 bf16 hi+lo, groups g=(half*2+{0,1})^((d>>1)&3)) behind ONE barrier
// pair. LDS 24KB: Ah[64][32]|Al|Bh[128][32]|Bl; ep[64][34] overlays B.

#define STAGE_AB(ASRC, BH, BL, BOFF)                                         \
  {                                                                          \
    const int an = tid >> 2, aq = tid & 3;                                   \
    const float* s = (ASRC); /* 8 floats for row an, cols aq*8.. */          \
    float4 v0 = *(const float4*)&s[0];                                       \
    float4 v1 = *(const float4*)&s[4];                                       \
    float vv[8] = {v0.x, v0.y, v0.z, v0.w, v1.x, v1.y, v1.z, v1.w};          \
    unsigned hw[4], lw[4];                                                   \
    _Pragma("unroll") for (int j = 0; j < 4; ++j) {                          \
      unsigned short h0 = f2bf(vv[2 * j]);                                   \
      unsigned short h1 = f2bf(vv[2 * j + 1]);                               \
      unsigned short l0 =                                                    \
          f2bf(vv[2 * j] - __uint_as_float((unsigned)h0 << 16));             \
      unsigned short l1 =                                                    \
          f2bf(vv[2 * j + 1] - __uint_as_float((unsigned)h1 << 16));         \
      hw[j] = (unsigned)h0 | ((unsigned)h1 << 16);                           \
      lw[j] = (unsigned)l0 | ((unsigned)l1 << 16);                           \
    }                                                                        \
    int ag = aq ^ ((an >> 1) & 3);                                           \
    *(uint4*)&Ah[an][ag * 8] = make_uint4(hw[0], hw[1], hw[2], hw[3]);       \
    *(uint4*)&Al[an][ag * 8] = make_uint4(lw[0], lw[1], lw[2], lw[3]);       \
    const int bd = tid >> 1, bhalf = tid & 1;                                \
    size_t boff_ = (BOFF);                                                   \
    uint4 q0 = *(const uint4*)&(BH)[boff_];                                  \
    uint4 q1 = *(const uint4*)&(BH)[boff_ + 8];                              \
    uint4 p0 = *(const uint4*)&(BL)[boff_];                                  \
    uint4 p1 = *(const uint4*)&(BL)[boff_ + 8];                              \
    int sw = (bd >> 1) & 3;                                                  \
    int g0 = (bhalf * 2) ^ sw, g1 = (bhalf * 2 + 1) ^ sw;                    \
    *(uint4*)&Bh[bd][g0 * 8] = q0;                                           \
    *(uint4*)&Bh[bd][g1 * 8] = q1;                                           \
    *(uint4*)&Bl[bd][g0 * 8] = p0;                                           \
    *(uint4*)&Bl[bd][g1 * 8] = p1;                                           \
  }

#define MFMA_CHUNK64()                                                       \
  {                                                                          \
    int ln = lane & 15, kq = lane >> 4;                                      \
    short8v ah[2], al[2];                                                    \
    _Pragma("unroll") for (int r = 0; r < 2; ++r) {                          \
      int row = wr2 * 32 + r * 16 + ln;                                      \
      int gg = kq ^ ((row >> 1) & 3);                                        \
      ah[r] = *(const short8v*)&Ah[row][gg * 8];                             \
      al[r] = *(const short8v*)&Al[row][gg * 8];                             \
    }                                                                        \
    _Pragma("unroll") for (int c = 0; c < 4; ++c) {                          \
      int col = wc2 * 64 + c * 16 + ln;                                      \
      int gg = kq ^ ((col >> 1) & 3);                                        \
      short8v bh = *(const short8v*)&Bh[col][gg * 8];                        \
      short8v bl = *(const short8v*)&Bl[col][gg * 8];                        \
      _Pragma("unroll") for (int r = 0; r < 2; ++r) {                        \
        acc[r][c] = __builtin_amdgcn_mfma_f32_16x16x32_bf16(                 \
            ah[r], bh, acc[r][c], 0, 0, 0);                                  \
        acc[r][c] = __builtin_amdgcn_mfma_f32_16x16x32_bf16(                 \
            ah[r], bl, acc[r][c], 0, 0, 0);                                  \
        acc[r][c] = __builtin_amdgcn_mfma_f32_16x16x32_bf16(                 \
            al[r], bh, acc[r][c], 0, 0, 0);                                  \
      }                                                                      \
    }                                                                        \
  }

#define EP_WRITE(GRP)                                                        \
  if (wc2 == ((GRP) >> 1)) {                                                 \
    int ln = lane & 15, kq = lane >> 4;                                      \
    _Pragma("unroll") for (int cc = 0; cc < 2; ++cc) {                       \
      int c = ((GRP) & 1) * 2 + cc;                                          \
      _Pragma("unroll") for (int r = 0; r < 2; ++r)                          \
        _Pragma("unroll") for (int reg = 0; reg < 4; ++reg)                  \
          ep[wr2 * 32 + r * 16 + kq * 4 + reg][cc * 16 + ln] =               \
              acc[r][c][reg];                                                \
  }                                                                          \
  }

// ---------------- K2m: projection (one of 3) for 64-node tile -------------
// blockIdx.x = p, blockIdx.y = node tile. Outputs Tj=[J0|J1] (p<2) or I1.
__global__ __launch_bounds__(256) void k2m_mfma(
    const float* __restrict__ hv, const unsigned short* __restrict__ Mh,
    const unsigned short* __restrict__ Ml, const unsigned short* __restrict__ Mth,
    const unsigned short* __restrict__ Mtl, float* __restrict__ Tj,
    float* __restrict__ I1, int N) {
  __shared__ char pool[24576];
  unsigned short (*Ah)[32] = (unsigned short(*)[32])pool;
  unsigned short (*Al)[32] = (unsigned short(*)[32])(pool + 4096);
  unsigned short (*Bh)[32] = (unsigned short(*)[32])(pool + 8192);
  unsigned short (*Bl)[32] = (unsigned short(*)[32])(pool + 16384);
  float (*ep)[34] = (float(*)[34])(pool + 8192);

  const int tid = threadIdx.x;
  const int lane = tid & 63;
  const int w = tid >> 6;
  const int wr2 = w >> 1, wc2 = w & 1;
  const int p = blockIdx.x;
  const int n0 = blockIdx.y * 64;
  const unsigned short* bhs = (p == 2) ? Mth : Mh;
  const unsigned short* bls = (p == 2) ? Mtl : Ml;
  const int borow = (p == 0) ? 0 : 128;
  float* outp = (p == 0) ? Tj : (p == 1) ? (Tj + 128) : I1;
  const size_t ostride = (p == 2) ? 128 : 256;

  float4v acc[2][4];
#pragma unroll
  for (int r = 0; r < 2; ++r)
#pragma unroll
    for (int c = 0; c < 4; ++c) acc[r][c] = (float4v){0.f, 0.f, 0.f, 0.f};

  for (int ch = 0; ch < 4; ++ch) {
    __syncthreads();
    {
      int gn = n0 + (tid >> 2);
      gn = gn < N ? gn : N - 1;
      STAGE_AB(hv + (size_t)gn * 128 + ch * 32 + (tid & 3) * 8, bhs, bls,
               (size_t)(borow + (tid >> 1)) * 512 + ch * 32 + (tid & 1) * 16);
    }
    __syncthreads();
    MFMA_CHUNK64();
  }

  for (int g = 0; g < 4; ++g) {
    __syncthreads();
    EP_WRITE(g);
    __syncthreads();
    int row = tid >> 2, part = tid & 3;
    int gn = n0 + row;
    if (gn < N) {
      *(float4*)&outp[(size_t)gn * ostride + g * 32 + part * 8] =
          *(const float4*)&ep[row][part * 8];
      *(float4*)&outp[(size_t)gn * ostride + g * 32 + part * 8 + 4] =
          *(const float4*)&ep[row][part * 8 + 4];
    }
  }
}

// ---------------- K3: per-query vectors w,u,y,c_b (256 thr, c-split) ------
__global__ __launch_bounds__(256) void k3_query(const float* __restrict__ qsrc,
                                                const float* __restrict__ qrel,
                                                const float* __restrict__ M,
                                                const float* __restrict__ Mt,
                                                float* __restrict__ wv,
                                                float* __restrict__ uv,
                                                float* __restrict__ yv,
                                                float* __restrict__ cb) {
  __shared__ float qcat[256];
  __shared__ float prt[5][256];
  __shared__ float red[128];
  int b = blockIdx.x, tid = threadIdx.x;
  int d = tid & 127, hc = tid >> 7;
  qcat[tid] = (tid < 128) ? qsrc[b * 128 + tid] : qrel[b * 128 + (tid - 128)];
  __syncthreads();
  float w = 0.f, u = 0.f, y = 0.f, t1 = 0.f, t2 = 0.f;
  for (int c = hc * 128; c < hc * 128 + 128; ++c) {
    float q = qcat[c];
    size_t row = (size_t)(256 + c) * 512;
    w += Mt[row + d] * q;
    u += M[row + d] * q;
    y += (Mt[row + 128 + d] + M[row + 128 + d]) * q;
    t1 += M[row + 256 + d] * q;
    t2 += M[row + 384 + d] * q;
  }
  prt[0][tid] = w; prt[1][tid] = u; prt[2][tid] = y;
  prt[3][tid] = t1; prt[4][tid] = t2;
  __syncthreads();
  if (tid < 128) {
    float wc_ = prt[0][d] + prt[0][128 + d];
    float uc = prt[1][d] + prt[1][128 + d];
    float yc = prt[2][d] + prt[2][128 + d];
    float t1c = prt[3][d] + prt[3][128 + d];
    float t2c = prt[4][d] + prt[4][128 + d];
    wv[b * 128 + d] = wc_;
    uv[b * 128 + d] = uc;
    yv[b * 128 + d] = yc;
    red[d] = qcat[d] * t1c + qcat[128 + d] * t2c;
  }
  __syncthreads();
  for (int s = 64; s > 0; s >>= 1) {
    if (tid < s) red[tid] += red[tid + s];
    __syncthreads();
  }
  if (tid == 0) cb[b] = red[0];
}

// ---------------- K4m: edge_const, 64-edge tile ---------------------------
// q[e][d] = sum_c rel[e][c]*M11[c][d]; ec[e] = sum_d (q+y_b)[d]*rel[e][d]+c_b
__global__ __launch_bounds__(256) void k4m_mfma(
    const float* __restrict__ rel, const unsigned short* __restrict__ Mth,
    const unsigned short* __restrict__ Mtl, const float* __restrict__ yv,
    const float* __restrict__ cbp, float* __restrict__ ec) {
  __shared__ char pool[24576];
  unsigned short (*Ah)[32] = (unsigned short(*)[32])pool;
  unsigned short (*Al)[32] = (unsigned short(*)[32])(pool + 4096);
  unsigned short (*Bh)[32] = (unsigned short(*)[32])(pool + 8192);
  unsigned short (*Bl)[32] = (unsigned short(*)[32])(pool + 16384);
  float (*ep)[34] = (float(*)[34])(pool + 8192);

  const int tid = threadIdx.x;
  const int lane = tid & 63;
  const int w = tid >> 6;
  const int wr2 = w >> 1, wc2 = w & 1;
  const int e0 = blockIdx.x * 64;
  const int b = e0 >> EPQ_SHIFT;

  float4v acc[2][4];
#pragma unroll
  for (int r = 0; r < 2; ++r)
#pragma unroll
    for (int c = 0; c < 4; ++c) acc[r][c] = (float4v){0.f, 0.f, 0.f, 0.f};

  for (int ch = 0; ch < 4; ++ch) {
    __syncthreads();
    STAGE_AB(rel + (size_t)(e0 + (tid >> 2)) * 128 + ch * 32 + (tid & 3) * 8,
             Mth, Mtl,
             (size_t)(128 + (tid >> 1)) * 512 + 128 + ch * 32 + (tid & 1) * 16);
    __syncthreads();
    MFMA_CHUNK64();
  }

  float part = 0.f;
  const int e_loc = tid >> 2, quarter = tid & 3;
  for (int g = 0; g < 4; ++g) {
    __syncthreads();
    EP_WRITE(g);
    __syncthreads();
    const float* rsrc = rel + (size_t)(e0 + e_loc) * 128 + g * 32 + quarter * 8;
    const float* ysrc = yv + b * 128 + g * 32 + quarter * 8;
#pragma unroll
    for (int j = 0; j < 2; ++j) {
      float4 qv = *(const float4*)&ep[e_loc][quarter * 8 + 4 * j];
      float4 rr = *(const float4*)&rsrc[4 * j];
      float4 yy = *(const float4*)&ysrc[4 * j];
      part += (qv.x + yy.x) * rr.x + (qv.y + yy.y) * rr.y +
              (qv.z + yy.z) * rr.z + (qv.w + yy.w) * rr.w;
    }
  }
  part += __shfl_xor(part, 1, 64);
  part += __shfl_xor(part, 2, 64);
  if ((tid & 3) == 0) ec[e0 + e_loc] = part + cbp[b];
}

// ---------------- K5: per-edge logits + segment max (16 edges/block) ------
__global__ __launch_bounds__(256) void k5_logits(const float* __restrict__ rel,
                                                 const float* __restrict__ hv,
                                                 const float* __restrict__ Tj,
                                                 const float* __restrict__ I1,
                                                 const float* __restrict__ wv,
                                                 const float* __restrict__ uv,
                                                 const float* __restrict__ ec,
                                                 const int* __restrict__ node_i,
                                                 const int* __restrict__ node_j,
                                                 float* __restrict__ logits,
                                                 unsigned* __restrict__ segkey) {
  __shared__ float wl[128];
  __shared__ float ul[128];
  int tid = threadIdx.x;
  int e0 = blockIdx.x * 16;
  int b = e0 >> EPQ_SHIFT;
  if (tid < 128) wl[tid] = wv[b * 128 + tid];
  else ul[tid - 128] = uv[b * 128 + (tid - 128)];
  __syncthreads();
  int lane = tid & 15, eg = tid >> 4;
  int e = e0 + eg;
  int i = node_i[e], j = node_j[e];
  int c0 = lane * 8;

  float rr[8], hi[8], hj[8], a0[8], a1[8], ii[8];
  *(float4*)&rr[0] = *(const float4*)&rel[(size_t)e * 128 + c0];
  *(float4*)&rr[4] = *(const float4*)&rel[(size_t)e * 128 + c0 + 4];
  *(float4*)&hi[0] = *(const float4*)&hv[(size_t)i * 128 + c0];
  *(float4*)&hi[4] = *(const float4*)&hv[(size_t)i * 128 + c0 + 4];
  *(float4*)&hj[0] = *(const float4*)&hv[(size_t)j * 128 + c0];
  *(float4*)&hj[4] = *(const float4*)&hv[(size_t)j * 128 + c0 + 4];
  *(float4*)&a0[0] = *(const float4*)&Tj[(size_t)j * 256 + c0];
  *(float4*)&a0[4] = *(const float4*)&Tj[(size_t)j * 256 + c0 + 4];
  *(float4*)&a1[0] = *(const float4*)&Tj[(size_t)j * 256 + 128 + c0];
  *(float4*)&a1[4] = *(const float4*)&Tj[(size_t)j * 256 + 128 + c0 + 4];
  *(float4*)&ii[0] = *(const float4*)&I1[(size_t)i * 128 + c0];
  *(float4*)&ii[4] = *(const float4*)&I1[(size_t)i * 128 + c0 + 4];

  float p = 0.f;
#pragma unroll
  for (int k = 0; k < 8; ++k) {
    p += hi[k] * a0[k];               // hvi . J0[j]
    p += rr[k] * (a1[k] + ii[k]);     // rel . (J1[j] + I1[i])
    p += hi[k] * wl[c0 + k];          // hvi . w_b
    p += hj[k] * ul[c0 + k];          // hvj . u_b
  }
#pragma unroll
  for (int m = 8; m >= 1; m >>= 1) p += __shfl_xor(p, m, 64);
  if (lane == 0) {
    float lg = p + ec[e];
    logits[e] = lg;
    atomicMax(&segkey[i], enc_f(lg));
  }
}

// ---------------- K6: ex = exp(logit - segmax), segment sum ----------------
__global__ void k6_exp(float* __restrict__ exb, const int* __restrict__ node_i,
                       const unsigned* __restrict__ segkey,
                       float* __restrict__ segsum, int E) {
  int e = blockIdx.x * 256 + threadIdx.x;
  if (e >= E) return;
  int i = node_i[e];
  float m = dec_f(segkey[i]);
  float ex = expf(exb[e] - m);
  exb[e] = ex;
  atomicAdd(&segsum[i], ex);
}

// ---------------- K7: per-query exact top-256 radix select + scatter-add ----
__global__ __launch_bounds__(256) void k7_topk(const float* __restrict__ exb,
                                               const int* __restrict__ node_i,
                                               const int* __restrict__ node_j,
                                               const float* __restrict__ segsum,
                                               const float* __restrict__ score,
                                               float* __restrict__ out) {
  __shared__ unsigned vals[2048];
  __shared__ unsigned hist[256];
  __shared__ unsigned sc[256];
  __shared__ unsigned tie_scan[256];
  __shared__ unsigned sel_info[2];
  int q = blockIdx.x, t = threadIdx.x;
  size_t base = (size_t)q * 2048;
#pragma unroll
  for (int l = 0; l < 8; ++l) {
    int el = t * 8 + l;
    int i = node_i[base + el];
    float tgt = exb[base + el] / segsum[i] * score[i];  // attn * src_score >= 0
    vals[el] = __float_as_uint(tgt);
  }
  __syncthreads();
  unsigned prefix = 0, need = KSEL;
  for (int pass = 3; pass >= 0; --pass) {
    hist[t] = 0;
    __syncthreads();
    int sh = pass * 8;
#pragma unroll
    for (int l = 0; l < 8; ++l) {
      unsigned v = vals[t * 8 + l];
      bool match = (pass == 3) || ((v >> (sh + 8)) == (prefix >> (sh + 8)));
      if (match) atomicAdd(&hist[(v >> sh) & 255u], 1u);
    }
    __syncthreads();
    sc[t] = hist[t];
    __syncthreads();
    for (int off = 1; off < 256; off <<= 1) {  // suffix-inclusive sum
      unsigned add = (t + off < 256) ? sc[t + off] : 0u;
      __syncthreads();
      sc[t] += add;
      __syncthreads();
    }
    unsigned above = sc[t] - hist[t];
    if (above < need && need <= sc[t]) {
      sel_info[0] = (unsigned)t;
      sel_info[1] = need - above;
    }
    __syncthreads();
    prefix |= sel_info[0] << sh;
    need = sel_info[1];
    __syncthreads();
  }
  unsigned T = prefix, r = need;
  unsigned lc = 0;
#pragma unroll
  for (int l = 0; l < 8; ++l)
    if (vals[t * 8 + l] == T) lc++;
  tie_scan[t] = lc;
  __syncthreads();
  unsigned own = lc;
  for (int off = 1; off < 256; off <<= 1) {
    unsigned add = (t >= off) ? tie_scan[t - off] : 0u;
    __syncthreads();
    tie_scan[t] += add;
    __syncthreads();
  }
  unsigned excl = tie_scan[t] - own;
  unsigned cnt = 0;
#pragma unroll
  for (int l = 0; l < 8; ++l) {
    int el = t * 8 + l;
    unsigned v = vals[el];
    bool take = false;
    if (v > T) take = true;
    else if (v == T) { if (excl + cnt < r) take = true; cnt++; }
    if (take) {
      int j = node_j[base + el];
      atomicAdd(&out[j], __uint_as_float(v));
    }
  }
}

// ---------------- host ----------------
extern "C" void kernel_launch(void* const* d_in, const int* in_sizes, int n_in,
                              void* d_out, int out_size, void* d_ws, size_t ws_size,
                              hipStream_t stream) {
  const float* score = (const float*)d_in[0];
  const float* hv    = (const float*)d_in[1];
  const float* rel   = (const float*)d_in[2];
  const float* qsrc  = (const float*)d_in[3];
  const float* qrel  = (const float*)d_in[4];
  const float* Wq    = (const float*)d_in[5];
  const float* Wk    = (const float*)d_in[6];
  const int* node_i  = (const int*)d_in[8];
  const int* node_j  = (const int*)d_in[9];

  const int N = in_sizes[0];            // 50000
  const int B = in_sizes[3] / 128;      // 64
  const int E = in_sizes[2] / 128;      // 131072

  float* ws = (float*)d_ws;
  float* M  = ws;
  float* Mt = M + 262144;
  float* Tj = Mt + 262144;              // [N][256] = J0|J1 packed
  float* I1 = Tj + (size_t)N * 256;
  float* wv = I1 + (size_t)N * 128;
  float* uv = wv + (size_t)B * 128;
  float* yv = uv + (size_t)B * 128;
  float* cb = yv + (size_t)B * 128;
  float* ec = cb + B;
  float* exb = ec + E;
  unsigned* segkey = (unsigned*)(exb + E);
  float* segsum = (float*)(segkey + N);
  unsigned short* Mh  = (unsigned short*)(segsum + N);
  unsigned short* Ml  = Mh + 262144;
  unsigned short* Mth = Ml + 262144;
  unsigned short* Mtl = Mth + 262144;
  float* out = (float*)d_out;

  k1_gemmM<<<dim3(8, 8), 256, 0, stream>>>(Wq, Wk, M, Mt, Mh, Ml, Mth, Mtl,
                                           out, segsum, segkey, N);
  k2m_mfma<<<dim3(3, (N + 63) / 64), 256, 0, stream>>>(hv, Mh, Ml, Mth, Mtl,
                                                       Tj, I1, N);
  k3_query<<<B, 256, 0, stream>>>(qsrc, qrel, M, Mt, wv, uv, yv, cb);
  k4m_mfma<<<E / 64, 256, 0, stream>>>(rel, Mth, Mtl, yv, cb, ec);
  k5_logits<<<E / 16, 256, 0, stream>>>(rel, hv, Tj, I1, wv, uv, ec,
                                        node_i, node_j, exb, segkey);
  k6_exp<<<(E + 255) / 256, 256, 0, stream>>>(exb, node_i, segkey, segsum, E);
  k7_topk<<<B, 256, 0, stream>>>(exb, node_i, node_j, segsum, score, out);
}

// Round 16
// 214.432 us; speedup vs baseline: 1.5048x; 1.0084x over previous
//
#include <hip/hip_runtime.h>
#include <cstddef>

// Problem constants (fixed by the reference)
#define EPQ_SHIFT 11       // EPQ = 2048
#define KSEL 256

typedef __attribute__((ext_vector_type(8))) short short8v;   // 8 bf16
typedef __attribute__((ext_vector_type(4))) float float4v;   // MFMA acc

__device__ __forceinline__ unsigned enc_f(float f) {
  unsigned u = __float_as_uint(f);
  return (u & 0x80000000u) ? ~u : (u | 0x80000000u);
}
__device__ __forceinline__ float dec_f(unsigned k) {
  unsigned u = (k & 0x80000000u) ? (k ^ 0x80000000u) : ~k;
  return __uint_as_float(u);
}
__device__ __forceinline__ unsigned short f2bf(float x) {  // RNE f32->bf16
  unsigned u = __float_as_uint(x);
  return (unsigned short)((u + 0x7FFFu + ((u >> 16) & 1u)) >> 16);
}

// ---------------- K1: init buffers + M = Wq^T Wk + Mt + bf16 splits -------
__global__ __launch_bounds__(256) void k1_gemmM(
    const float* __restrict__ Wq, const float* __restrict__ Wk,
    float* __restrict__ M, float* __restrict__ Mt,
    unsigned short* __restrict__ Mh, unsigned short* __restrict__ Ml,
    unsigned short* __restrict__ Mth, unsigned short* __restrict__ Mtl,
    float* __restrict__ outz, float* __restrict__ segsum,
    unsigned* __restrict__ segkey, int N) {
  int tid = threadIdx.x;
  {  // folded k0: zero out/segsum/segkey
    int bid = blockIdx.y * gridDim.x + blockIdx.x;
    for (int idx = bid * 256 + tid; idx < N; idx += 16384) {
      outz[idx] = 0.f;
      segsum[idx] = 0.f;
      segkey[idx] = 0u;
    }
  }
  __shared__ float as[16][64];
  __shared__ float bs[16][64];
  int tx = tid & 15, ty = tid >> 4;
  int c1b = blockIdx.y * 64, c2b = blockIdx.x * 64;
  float acc[4][4] = {};
  for (int k0 = 0; k0 < 512; k0 += 16) {
#pragma unroll
    for (int l = 0; l < 4; ++l) {
      int lin = tid + l * 256;
      int kk = lin >> 6, c = lin & 63;
      as[kk][c] = Wq[(k0 + kk) * 512 + c1b + c];
      bs[kk][c] = Wk[(k0 + kk) * 512 + c2b + c];
    }
    __syncthreads();
#pragma unroll
    for (int kk = 0; kk < 16; ++kk) {
      float a[4], b[4];
#pragma unroll
      for (int m = 0; m < 4; ++m) a[m] = as[kk][ty * 4 + m];
#pragma unroll
      for (int n = 0; n < 4; ++n) b[n] = bs[kk][tx * 4 + n];
#pragma unroll
      for (int m = 0; m < 4; ++m)
#pragma unroll
        for (int n = 0; n < 4; ++n) acc[m][n] += a[m] * b[n];
    }
    __syncthreads();
  }
#pragma unroll
  for (int m = 0; m < 4; ++m)
#pragma unroll
    for (int n = 0; n < 4; ++n) {
      int c1 = c1b + ty * 4 + m, c2 = c2b + tx * 4 + n;
      float v = acc[m][n];
      M[c1 * 512 + c2] = v;
      Mt[c2 * 512 + c1] = v;
      unsigned short h = f2bf(v);
      unsigned short lo = f2bf(v - __uint_as_float((unsigned)h << 16));
      Mh[c1 * 512 + c2] = h;
      Ml[c1 * 512 + c2] = lo;
      Mth[c2 * 512 + c1] = h;
      Mtl[c2 * 512 + c1] = lo;
    }
}

// ===== 64-row-tile MFMA skeleton, register-double-buffered staging =====
// Block 256 thr = 4 waves; tile 64 rows x 128 cols; wave w: wr2=w>>1 owns
// 32-row half, wc2=w&1 owns 64-col half; acc[2][4] of 16x16 frags.
// Per K-chunk(32): LDS writes come from REGISTERS prefetched during the
// previous chunk's MFMA (load latency off the critical path).
// LDS 24KB: Ah[64][32]|Al|Bh[128][32]|Bl; ep[64][34] overlays B.

// registers declared by K_DECL; loads via K_LOAD(ch); LDS write via K_WRITE.
#define K_DECL()                                                             \
  float4 ra0, ra1;                                                           \
  uint4 rbh0, rbh1, rbl0, rbl1;                                              \
  const int an = tid >> 2, aq = tid & 3;                                     \
  const int ag = aq ^ ((an >> 1) & 3);                                       \
  const int bd = tid >> 1, bhalf = tid & 1;                                  \
  const int bsw = (bd >> 1) & 3;                                             \
  const int bg0 = (bhalf * 2) ^ bsw, bg1 = (bhalf * 2 + 1) ^ bsw;

#define K_LOAD(CH)                                                           \
  ra0 = *(const float4*)&asrc[(CH) * 32];                                    \
  ra1 = *(const float4*)&asrc[(CH) * 32 + 4];                                \
  rbh0 = *(const uint4*)&bhsrc[(CH) * 32];                                   \
  rbh1 = *(const uint4*)&bhsrc[(CH) * 32 + 8];                               \
  rbl0 = *(const uint4*)&blsrc[(CH) * 32];                                   \
  rbl1 = *(const uint4*)&blsrc[(CH) * 32 + 8];

#define K_WRITE()                                                            \
  {                                                                          \
    float vv[8] = {ra0.x, ra0.y, ra0.z, ra0.w, ra1.x, ra1.y, ra1.z, ra1.w};  \
    unsigned hw[4], lw[4];                                                   \
    _Pragma("unroll") for (int j = 0; j < 4; ++j) {                          \
      unsigned short h0 = f2bf(vv[2 * j]);                                   \
      unsigned short h1 = f2bf(vv[2 * j + 1]);                               \
      unsigned short l0 =                                                    \
          f2bf(vv[2 * j] - __uint_as_float((unsigned)h0 << 16));             \
      unsigned short l1 =                                                    \
          f2bf(vv[2 * j + 1] - __uint_as_float((unsigned)h1 << 16));         \
      hw[j] = (unsigned)h0 | ((unsigned)h1 << 16);                           \
      lw[j] = (unsigned)l0 | ((unsigned)l1 << 16);                           \
    }                                                                        \
    *(uint4*)&Ah[an][ag * 8] = make_uint4(hw[0], hw[1], hw[2], hw[3]);       \
    *(uint4*)&Al[an][ag * 8] = make_uint4(lw[0], lw[1], lw[2], lw[3]);       \
    *(uint4*)&Bh[bd][bg0 * 8] = rbh0;                                        \
    *(uint4*)&Bh[bd][bg1 * 8] = rbh1;                                        \
    *(uint4*)&Bl[bd][bg0 * 8] = rbl0;                                        \
    *(uint4*)&Bl[bd][bg1 * 8] = rbl1;                                        \
  }

#define MFMA_CHUNK64()                                                       \
  {                                                                          \
    int ln = lane & 15, kq = lane >> 4;                                      \
    short8v ah[2], al[2];                                                    \
    _Pragma("unroll") for (int r = 0; r < 2; ++r) {                          \
      int row = wr2 * 32 + r * 16 + ln;                                      \
      int gg = kq ^ ((row >> 1) & 3);                                        \
      ah[r] = *(const short8v*)&Ah[row][gg * 8];                             \
      al[r] = *(const short8v*)&Al[row][gg * 8];                             \
    }                                                                        \
    _Pragma("unroll") for (int c = 0; c < 4; ++c) {                          \
      int col = wc2 * 64 + c * 16 + ln;                                      \
      int gg = kq ^ ((col >> 1) & 3);                                        \
      short8v bh = *(const short8v*)&Bh[col][gg * 8];                        \
      short8v bl = *(const short8v*)&Bl[col][gg * 8];                        \
      _Pragma("unroll") for (int r = 0; r < 2; ++r) {                        \
        acc[r][c] = __builtin_amdgcn_mfma_f32_16x16x32_bf16(                 \
            ah[r], bh, acc[r][c], 0, 0, 0);                                  \
        acc[r][c] = __builtin_amdgcn_mfma_f32_16x16x32_bf16(                 \
            ah[r], bl, acc[r][c], 0, 0, 0);                                  \
        acc[r][c] = __builtin_amdgcn_mfma_f32_16x16x32_bf16(                 \
            al[r], bh, acc[r][c], 0, 0, 0);                                  \
      }                                                                      \
    }                                                                        \
  }

#define K_MAIN_LOOP()                                                        \
  K_LOAD(0);                                                                 \
  _Pragma("unroll") for (int ch = 0; ch < 4; ++ch) {                         \
    __syncthreads();                                                         \
    K_WRITE();                                                               \
    float4 na0, na1;                                                         \
    uint4 nbh0, nbh1, nbl0, nbl1;                                            \
    if (ch < 3) {  /* prefetch next chunk; drains under barrier+MFMA */      \
      na0 = *(const float4*)&asrc[(ch + 1) * 32];                            \
      na1 = *(const float4*)&asrc[(ch + 1) * 32 + 4];                        \
      nbh0 = *(const uint4*)&bhsrc[(ch + 1) * 32];                           \
      nbh1 = *(const uint4*)&bhsrc[(ch + 1) * 32 + 8];                       \
      nbl0 = *(const uint4*)&blsrc[(ch + 1) * 32];                           \
      nbl1 = *(const uint4*)&blsrc[(ch + 1) * 32 + 8];                       \
    }                                                                        \
    __syncthreads();                                                         \
    MFMA_CHUNK64();                                                          \
    ra0 = na0; ra1 = na1;                                                    \
    rbh0 = nbh0; rbh1 = nbh1; rbl0 = nbl0; rbl1 = nbl1;                      \
  }

#define EP_WRITE(GRP)                                                        \
  if (wc2 == ((GRP) >> 1)) {                                                 \
    int ln = lane & 15, kq = lane >> 4;                                      \
    _Pragma("unroll") for (int cc = 0; cc < 2; ++cc) {                       \
      int c = ((GRP) & 1) * 2 + cc;                                          \
      _Pragma("unroll") for (int r = 0; r < 2; ++r)                          \
        _Pragma("unroll") for (int reg = 0; reg < 4; ++reg)                  \
          ep[wr2 * 32 + r * 16 + kq * 4 + reg][cc * 16 + ln] =               \
              acc[r][c][reg];                                                \
  }                                                                          \
  }

// ---------------- K2m: projection (one of 3) for 64-node tile -------------
__global__ __launch_bounds__(256) void k2m_mfma(
    const float* __restrict__ hv, const unsigned short* __restrict__ Mh,
    const unsigned short* __restrict__ Ml, const unsigned short* __restrict__ Mth,
    const unsigned short* __restrict__ Mtl, float* __restrict__ Tj,
    float* __restrict__ I1, int N) {
  __shared__ char pool[24576];
  unsigned short (*Ah)[32] = (unsigned short(*)[32])pool;
  unsigned short (*Al)[32] = (unsigned short(*)[32])(pool + 4096);
  unsigned short (*Bh)[32] = (unsigned short(*)[32])(pool + 8192);
  unsigned short (*Bl)[32] = (unsigned short(*)[32])(pool + 16384);
  float (*ep)[34] = (float(*)[34])(pool + 8192);

  const int tid = threadIdx.x;
  const int lane = tid & 63;
  const int w = tid >> 6;
  const int wr2 = w >> 1, wc2 = w & 1;
  const int p = blockIdx.x;
  const int n0 = blockIdx.y * 64;
  const unsigned short* bhs = (p == 2) ? Mth : Mh;
  const unsigned short* bls = (p == 2) ? Mtl : Ml;
  const int borow = (p == 0) ? 0 : 128;
  float* outp = (p == 0) ? Tj : (p == 1) ? (Tj + 128) : I1;
  const size_t ostride = (p == 2) ? 128 : 256;

  float4v acc[2][4];
#pragma unroll
  for (int r = 0; r < 2; ++r)
#pragma unroll
    for (int c = 0; c < 4; ++c) acc[r][c] = (float4v){0.f, 0.f, 0.f, 0.f};

  K_DECL();
  int gn = n0 + an;
  gn = gn < N ? gn : N - 1;
  const float* asrc = hv + (size_t)gn * 128 + aq * 8;
  const unsigned short* bhsrc = bhs + (size_t)(borow + bd) * 512 + bhalf * 16;
  const unsigned short* blsrc = bls + (size_t)(borow + bd) * 512 + bhalf * 16;

  K_MAIN_LOOP();

  for (int g = 0; g < 4; ++g) {
    __syncthreads();
    EP_WRITE(g);
    __syncthreads();
    int row = tid >> 2, part = tid & 3;
    int on = n0 + row;
    if (on < N) {
      *(float4*)&outp[(size_t)on * ostride + g * 32 + part * 8] =
          *(const float4*)&ep[row][part * 8];
      *(float4*)&outp[(size_t)on * ostride + g * 32 + part * 8 + 4] =
          *(const float4*)&ep[row][part * 8 + 4];
    }
  }
}

// ---------------- K3: per-query vectors w,u,y,c_b (256 thr, c-split) ------
__global__ __launch_bounds__(256) void k3_query(const float* __restrict__ qsrc,
                                                const float* __restrict__ qrel,
                                                const float* __restrict__ M,
                                                const float* __restrict__ Mt,
                                                float* __restrict__ wv,
                                                float* __restrict__ uv,
                                                float* __restrict__ yv,
                                                float* __restrict__ cb) {
  __shared__ float qcat[256];
  __shared__ float prt[5][256];
  __shared__ float red[128];
  int b = blockIdx.x, tid = threadIdx.x;
  int d = tid & 127, hc = tid >> 7;
  qcat[tid] = (tid < 128) ? qsrc[b * 128 + tid] : qrel[b * 128 + (tid - 128)];
  __syncthreads();
  float w = 0.f, u = 0.f, y = 0.f, t1 = 0.f, t2 = 0.f;
  for (int c = hc * 128; c < hc * 128 + 128; ++c) {
    float q = qcat[c];
    size_t row = (size_t)(256 + c) * 512;
    w += Mt[row + d] * q;
    u += M[row + d] * q;
    y += (Mt[row + 128 + d] + M[row + 128 + d]) * q;
    t1 += M[row + 256 + d] * q;
    t2 += M[row + 384 + d] * q;
  }
  prt[0][tid] = w; prt[1][tid] = u; prt[2][tid] = y;
  prt[3][tid] = t1; prt[4][tid] = t2;
  __syncthreads();
  if (tid < 128) {
    float wc_ = prt[0][d] + prt[0][128 + d];
    float uc = prt[1][d] + prt[1][128 + d];
    float yc = prt[2][d] + prt[2][128 + d];
    float t1c = prt[3][d] + prt[3][128 + d];
    float t2c = prt[4][d] + prt[4][128 + d];
    wv[b * 128 + d] = wc_;
    uv[b * 128 + d] = uc;
    yv[b * 128 + d] = yc;
    red[d] = qcat[d] * t1c + qcat[128 + d] * t2c;
  }
  __syncthreads();
  for (int s = 64; s > 0; s >>= 1) {
    if (tid < s) red[tid] += red[tid + s];
    __syncthreads();
  }
  if (tid == 0) cb[b] = red[0];
}

// ---------------- K4m: edge_const, 64-edge tile, pipelined ---------------
__global__ __launch_bounds__(256) void k4m_mfma(
    const float* __restrict__ rel, const unsigned short* __restrict__ Mth,
    const unsigned short* __restrict__ Mtl, const float* __restrict__ yv,
    const float* __restrict__ cbp, float* __restrict__ ec) {
  __shared__ char pool[24576];
  unsigned short (*Ah)[32] = (unsigned short(*)[32])pool;
  unsigned short (*Al)[32] = (unsigned short(*)[32])(pool + 4096);
  unsigned short (*Bh)[32] = (unsigned short(*)[32])(pool + 8192);
  unsigned short (*Bl)[32] = (unsigned short(*)[32])(pool + 16384);
  float (*ep)[34] = (float(*)[34])(pool + 8192);

  const int tid = threadIdx.x;
  const int lane = tid & 63;
  const int w = tid >> 6;
  const int wr2 = w >> 1, wc2 = w & 1;
  const int e0 = blockIdx.x * 64;
  const int b = e0 >> EPQ_SHIFT;

  float4v acc[2][4];
#pragma unroll
  for (int r = 0; r < 2; ++r)
#pragma unroll
    for (int c = 0; c < 4; ++c) acc[r][c] = (float4v){0.f, 0.f, 0.f, 0.f};

  K_DECL();
  const float* asrc = rel + (size_t)(e0 + an) * 128 + aq * 8;
  const unsigned short* bhsrc = Mth + (size_t)(128 + bd) * 512 + 128 + bhalf * 16;
  const unsigned short* blsrc = Mtl + (size_t)(128 + bd) * 512 + 128 + bhalf * 16;

  K_MAIN_LOOP();

  float part = 0.f;
  const int e_loc = tid >> 2, quarter = tid & 3;
  for (int g = 0; g < 4; ++g) {
    __syncthreads();
    EP_WRITE(g);
    __syncthreads();
    const float* rsrc = rel + (size_t)(e0 + e_loc) * 128 + g * 32 + quarter * 8;
    const float* ysrc = yv + b * 128 + g * 32 + quarter * 8;
#pragma unroll
    for (int j = 0; j < 2; ++j) {
      float4 qv = *(const float4*)&ep[e_loc][quarter * 8 + 4 * j];
      float4 rr = *(const float4*)&rsrc[4 * j];
      float4 yy = *(const float4*)&ysrc[4 * j];
      part += (qv.x + yy.x) * rr.x + (qv.y + yy.y) * rr.y +
              (qv.z + yy.z) * rr.z + (qv.w + yy.w) * rr.w;
    }
  }
  part += __shfl_xor(part, 1, 64);
  part += __shfl_xor(part, 2, 64);
  if ((tid & 3) == 0) ec[e0 + e_loc] = part + cbp[b];
}

// ---------------- K5: per-edge logits + segment max (16 edges/block) ------
__global__ __launch_bounds__(256) void k5_logits(const float* __restrict__ rel,
                                                 const float* __restrict__ hv,
                                                 const float* __restrict__ Tj,
                                                 const float* __restrict__ I1,
                                                 const float* __restrict__ wv,
                                                 const float* __restrict__ uv,
                                                 const float* __restrict__ ec,
                                                 const int* __restrict__ node_i,
                                                 const int* __restrict__ node_j,
                                                 float* __restrict__ logits,
                                                 unsigned* __restrict__ segkey,
                                                 int e_base) {
  __shared__ float wl[128];
  __shared__ float ul[128];
  int tid = threadIdx.x;
  int e0 = e_base + blockIdx.x * 16;
  int b = e0 >> EPQ_SHIFT;
  if (tid < 128) wl[tid] = wv[b * 128 + tid];
  else ul[tid - 128] = uv[b * 128 + (tid - 128)];
  __syncthreads();
  int lane = tid & 15, eg = tid >> 4;
  int e = e0 + eg;
  int i = node_i[e], j = node_j[e];
  int c0 = lane * 8;

  float rr[8], hi[8], hj[8], a0[8], a1[8], ii[8];
  *(float4*)&rr[0] = *(const float4*)&rel[(size_t)e * 128 + c0];
  *(float4*)&rr[4] = *(const float4*)&rel[(size_t)e * 128 + c0 + 4];
  *(float4*)&hi[0] = *(const float4*)&hv[(size_t)i * 128 + c0];
  *(float4*)&hi[4] = *(const float4*)&hv[(size_t)i * 128 + c0 + 4];
  *(float4*)&hj[0] = *(const float4*)&hv[(size_t)j * 128 + c0];
  *(float4*)&hj[4] = *(const float4*)&hv[(size_t)j * 128 + c0 + 4];
  *(float4*)&a0[0] = *(const float4*)&Tj[(size_t)j * 256 + c0];
  *(float4*)&a0[4] = *(const float4*)&Tj[(size_t)j * 256 + c0 + 4];
  *(float4*)&a1[0] = *(const float4*)&Tj[(size_t)j * 256 + 128 + c0];
  *(float4*)&a1[4] = *(const float4*)&Tj[(size_t)j * 256 + 128 + c0 + 4];
  *(float4*)&ii[0] = *(const float4*)&I1[(size_t)i * 128 + c0];
  *(float4*)&ii[4] = *(const float4*)&I1[(size_t)i * 128 + c0 + 4];

  float p = 0.f;
#pragma unroll
  for (int k = 0; k < 8; ++k) {
    p += hi[k] * a0[k];               // hvi . J0[j]
    p += rr[k] * (a1[k] + ii[k]);     // rel . (J1[j] + I1[i])
    p += hi[k] * wl[c0 + k];          // hvi . w_b
    p += hj[k] * ul[c0 + k];          // hvj . u_b
  }
#pragma unroll
  for (int m = 8; m >= 1; m >>= 1) p += __shfl_xor(p, m, 64);
  if (lane == 0) {
    float lg = p + ec[e];
    logits[e] = lg;
    atomicMax(&segkey[i], enc_f(lg));
  }
}

// ---------------- K6: ex = exp(logit - segmax), segment sum ----------------
__global__ void k6_exp(float* __restrict__ exb, const int* __restrict__ node_i,
                       const unsigned* __restrict__ segkey,
                       float* __restrict__ segsum, int E) {
  int e = blockIdx.x * 256 + threadIdx.x;
  if (e >= E) return;
  int i = node_i[e];
  float m = dec_f(segkey[i]);
  float ex = expf(exb[e] - m);
  exb[e] = ex;
  atomicAdd(&segsum[i], ex);
}

// ---------------- K7: per-query exact top-256 radix select + scatter-add ----
__global__ __launch_bounds__(256) void k7_topk(const float* __restrict__ exb,
                                               const int* __restrict__ node_i,
                                               const int* __restrict__ node_j,
                                               const float* __restrict__ segsum,
                                               const float* __restrict__ score,
                                               float* __restrict__ out) {
  __shared__ unsigned vals[2048];
  __shared__ unsigned hist[256];
  __shared__ unsigned sc[256];
  __shared__ unsigned tie_scan[256];
  __shared__ unsigned sel_info[2];
  int q = blockIdx.x, t = threadIdx.x;
  size_t base = (size_t)q * 2048;
#pragma unroll
  for (int l = 0; l < 8; ++l) {
    int el = t * 8 + l;
    int i = node_i[base + el];
    float tgt = exb[base + el] / segsum[i] * score[i];  // attn * src_score >= 0
    vals[el] = __float_as_uint(tgt);
  }
  __syncthreads();
  unsigned prefix = 0, need = KSEL;
  for (int pass = 3; pass >= 0; --pass) {
    hist[t] = 0;
    __syncthreads();
    int sh = pass * 8;
#pragma unroll
    for (int l = 0; l < 8; ++l) {
      unsigned v = vals[t * 8 + l];
      bool match = (pass == 3) || ((v >> (sh + 8)) == (prefix >> (sh + 8)));
      if (match) atomicAdd(&hist[(v >> sh) & 255u], 1u);
    }
    __syncthreads();
    sc[t] = hist[t];
    __syncthreads();
    for (int off = 1; off < 256; off <<= 1) {  // suffix-inclusive sum
      unsigned add = (t + off < 256) ? sc[t + off] : 0u;
      __syncthreads();
      sc[t] += add;
      __syncthreads();
    }
    unsigned above = sc[t] - hist[t];
    if (above < need && need <= sc[t]) {
      sel_info[0] = (unsigned)t;
      sel_info[1] = need - above;
    }
    __syncthreads();
    prefix |= sel_info[0] << sh;
    need = sel_info[1];
    __syncthreads();
  }
  unsigned T = prefix, r = need;
  unsigned lc = 0;
#pragma unroll
  for (int l = 0; l < 8; ++l)
    if (vals[t * 8 + l] == T) lc++;
  tie_scan[t] = lc;
  __syncthreads();
  unsigned own = lc;
  for (int off = 1; off < 256; off <<= 1) {
    unsigned add = (t >= off) ? tie_scan[t - off] : 0u;
    __syncthreads();
    tie_scan[t] += add;
    __syncthreads();
  }
  unsigned excl = tie_scan[t] - own;
  unsigned cnt = 0;
#pragma unroll
  for (int l = 0; l < 8; ++l) {
    int el = t * 8 + l;
    unsigned v = vals[el];
    bool take = false;
    if (v > T) take = true;
    else if (v == T) { if (excl + cnt < r) take = true; cnt++; }
    if (take) {
      int j = node_j[base + el];
      atomicAdd(&out[j], __uint_as_float(v));
    }
  }
}

// ---------------- host ----------------
extern "C" void kernel_launch(void* const* d_in, const int* in_sizes, int n_in,
                              void* d_out, int out_size, void* d_ws, size_t ws_size,
                              hipStream_t stream) {
  const float* score = (const float*)d_in[0];
  const float* hv    = (const float*)d_in[1];
  const float* rel   = (const float*)d_in[2];
  const float* qsrc  = (const float*)d_in[3];
  const float* qrel  = (const float*)d_in[4];
  const float* Wq    = (const float*)d_in[5];
  const float* Wk    = (const float*)d_in[6];
  const int* node_i  = (const int*)d_in[8];
  const int* node_j  = (const int*)d_in[9];

  const int N = in_sizes[0];            // 50000
  const int B = in_sizes[3] / 128;      // 64
  const int E = in_sizes[2] / 128;      // 131072

  float* ws = (float*)d_ws;
  float* M  = ws;
  float* Mt = M + 262144;
  float* Tj = Mt + 262144;              // [N][256] = J0|J1 packed
  float* I1 = Tj + (size_t)N * 256;
  float* wv = I1 + (size_t)N * 128;
  float* uv = wv + (size_t)B * 128;
  float* yv = uv + (size_t)B * 128;
  float* cb = yv + (size_t)B * 128;
  float* ec = cb + B;
  float* exb = ec + E;
  unsigned* segkey = (unsigned*)(exb + E);
  float* segsum = (float*)(segkey + N);
  unsigned short* Mh  = (unsigned short*)(segsum + N);
  unsigned short* Ml  = Mh + 262144;
  unsigned short* Mth = Ml + 262144;
  unsigned short* Mtl = Mth + 262144;
  float* out = (float*)d_out;

  k1_gemmM<<<dim3(8, 8), 256, 0, stream>>>(Wq, Wk, M, Mt, Mh, Ml, Mth, Mtl,
                                           out, segsum, segkey, N);
  k2m_mfma<<<dim3(3, (N + 63) / 64), 256, 0, stream>>>(hv, Mh, Ml, Mth, Mtl,
                                                       Tj, I1, N);
  k3_query<<<B, 256, 0, stream>>>(qsrc, qrel, M, Mt, wv, uv, yv, cb);
  k4m_mfma<<<E / 64, 256, 0, stream>>>(rel, Mth, Mtl, yv, cb, ec);
  k5_logits<<<E / 32, 256, 0, stream>>>(rel, hv, Tj, I1, wv, uv, ec,
                                        node_i, node_j, exb, segkey, 0);
  k5_logits<<<E / 32, 256, 0, stream>>>(rel, hv, Tj, I1, wv, uv, ec,
                                        node_i, node_j, exb, segkey, E / 2);
  k6_exp<<<(E + 255) / 256, 256, 0, stream>>>(exb, node_i, segkey, segsum, E);
  k7_topk<<<B, 256, 0, stream>>>(exb, node_i, node_j, segsum, score, out);
}

// Round 17
// 214.161 us; speedup vs baseline: 1.5067x; 1.0013x over previous
//
#include <hip/hip_runtime.h>
#include <cstddef>

// Problem constants (fixed by the reference)
#define EPQ_SHIFT 11       // EPQ = 2048
#define KSEL 256

typedef __attribute__((ext_vector_type(8))) short short8v;   // 8 bf16
typedef __attribute__((ext_vector_type(4))) float float4v;   // MFMA acc

__device__ __forceinline__ unsigned enc_f(float f) {
  unsigned u = __float_as_uint(f);
  return (u & 0x80000000u) ? ~u : (u | 0x80000000u);
}
__device__ __forceinline__ float dec_f(unsigned k) {
  unsigned u = (k & 0x80000000u) ? (k ^ 0x80000000u) : ~k;
  return __uint_as_float(u);
}
__device__ __forceinline__ unsigned short f2bf(float x) {  // RNE f32->bf16
  unsigned u = __float_as_uint(x);
  return (unsigned short)((u + 0x7FFFu + ((u >> 16) & 1u)) >> 16);
}

// ---------------- K1: init buffers + M = Wq^T Wk + Mt + bf16 splits -------
__global__ __launch_bounds__(256) void k1_gemmM(
    const float* __restrict__ Wq, const float* __restrict__ Wk,
    float* __restrict__ M, float* __restrict__ Mt,
    unsigned short* __restrict__ Mh, unsigned short* __restrict__ Ml,
    unsigned short* __restrict__ Mth, unsigned short* __restrict__ Mtl,
    float* __restrict__ outz, float* __restrict__ segsum,
    unsigned* __restrict__ segkey, int N) {
  int tid = threadIdx.x;
  {  // folded k0: zero out/segsum/segkey
    int bid = blockIdx.y * gridDim.x + blockIdx.x;
    for (int idx = bid * 256 + tid; idx < N; idx += 16384) {
      outz[idx] = 0.f;
      segsum[idx] = 0.f;
      segkey[idx] = 0u;
    }
  }
  __shared__ float as[16][64];
  __shared__ float bs[16][64];
  int tx = tid & 15, ty = tid >> 4;
  int c1b = blockIdx.y * 64, c2b = blockIdx.x * 64;
  float acc[4][4] = {};
  for (int k0 = 0; k0 < 512; k0 += 16) {
#pragma unroll
    for (int l = 0; l < 4; ++l) {
      int lin = tid + l * 256;
      int kk = lin >> 6, c = lin & 63;
      as[kk][c] = Wq[(k0 + kk) * 512 + c1b + c];
      bs[kk][c] = Wk[(k0 + kk) * 512 + c2b + c];
    }
    __syncthreads();
#pragma unroll
    for (int kk = 0; kk < 16; ++kk) {
      float a[4], b[4];
#pragma unroll
      for (int m = 0; m < 4; ++m) a[m] = as[kk][ty * 4 + m];
#pragma unroll
      for (int n = 0; n < 4; ++n) b[n] = bs[kk][tx * 4 + n];
#pragma unroll
      for (int m = 0; m < 4; ++m)
#pragma unroll
        for (int n = 0; n < 4; ++n) acc[m][n] += a[m] * b[n];
    }
    __syncthreads();
  }
#pragma unroll
  for (int m = 0; m < 4; ++m)
#pragma unroll
    for (int n = 0; n < 4; ++n) {
      int c1 = c1b + ty * 4 + m, c2 = c2b + tx * 4 + n;
      float v = acc[m][n];
      M[c1 * 512 + c2] = v;
      Mt[c2 * 512 + c1] = v;
      unsigned short h = f2bf(v);
      unsigned short lo = f2bf(v - __uint_as_float((unsigned)h << 16));
      Mh[c1 * 512 + c2] = h;
      Ml[c1 * 512 + c2] = lo;
      Mth[c2 * 512 + c1] = h;
      Mtl[c2 * 512 + c1] = lo;
    }
}

// ===== shared MFMA macros =====
#define EP_WRITE(GRP)                                                        \
  if (wc2 == ((GRP) >> 1)) {                                                 \
    int ln = lane & 15, kq = lane >> 4;                                      \
    _Pragma("unroll") for (int cc = 0; cc < 2; ++cc) {                       \
      int c = ((GRP) & 1) * 2 + cc;                                          \
      _Pragma("unroll") for (int r = 0; r < 2; ++r)                          \
        _Pragma("unroll") for (int reg = 0; reg < 4; ++reg)                  \
          ep[wr2 * 32 + r * 16 + kq * 4 + reg][cc * 16 + ln] =               \
              acc[r][c][reg];                                                \
  }                                                                          \
  }

// ---------------- K2m3: ALL 3 projections, one pass, 64-node tile ---------
// A (hv) staged ONCE in LDS bf16 hi/lo (all 4 K-chunks, 32KB). B tiles
// register-prefetched across the flattened (p,ch) sequence. LDS 48KB.
// Outputs Tj=[J0|J1] packed, I1. Bit-identical to split-kernel version.
__global__ __launch_bounds__(256) void k2m3_mfma(
    const float* __restrict__ hv, const unsigned short* __restrict__ Mh,
    const unsigned short* __restrict__ Ml, const unsigned short* __restrict__ Mth,
    const unsigned short* __restrict__ Mtl, float* __restrict__ Tj,
    float* __restrict__ I1, int N) {
  __shared__ char pool[49152];
  unsigned short (*Ah4)[64][32] = (unsigned short(*)[64][32])pool;            // 16KB
  unsigned short (*Al4)[64][32] = (unsigned short(*)[64][32])(pool + 16384);  // 16KB
  unsigned short (*Bh)[32] = (unsigned short(*)[32])(pool + 32768);           // 8KB
  unsigned short (*Bl)[32] = (unsigned short(*)[32])(pool + 40960);           // 8KB
  float (*ep)[34] = (float(*)[34])(pool + 32768);  // overlays B region

  const int tid = threadIdx.x;
  const int lane = tid & 63;
  const int w = tid >> 6;
  const int wr2 = w >> 1, wc2 = w & 1;
  const int n0 = blockIdx.x * 64;

  // ---- stage A once: hv[n0..n0+64][0..128] -> bf16 hi/lo, 4 chunks ----
  {
    const int an = tid >> 2, aq = tid & 3;
    const int ag = aq ^ ((an >> 1) & 3);
    int gn = n0 + an;
    gn = gn < N ? gn : N - 1;
    const float* asrc = hv + (size_t)gn * 128 + aq * 8;
#pragma unroll
    for (int ch = 0; ch < 4; ++ch) {
      float4 v0 = *(const float4*)&asrc[ch * 32];
      float4 v1 = *(const float4*)&asrc[ch * 32 + 4];
      float vv[8] = {v0.x, v0.y, v0.z, v0.w, v1.x, v1.y, v1.z, v1.w};
      unsigned hw[4], lw[4];
#pragma unroll
      for (int j = 0; j < 4; ++j) {
        unsigned short h0 = f2bf(vv[2 * j]);
        unsigned short h1 = f2bf(vv[2 * j + 1]);
        unsigned short l0 = f2bf(vv[2 * j] - __uint_as_float((unsigned)h0 << 16));
        unsigned short l1 = f2bf(vv[2 * j + 1] - __uint_as_float((unsigned)h1 << 16));
        hw[j] = (unsigned)h0 | ((unsigned)h1 << 16);
        lw[j] = (unsigned)l0 | ((unsigned)l1 << 16);
      }
      *(uint4*)&Ah4[ch][an][ag * 8] = make_uint4(hw[0], hw[1], hw[2], hw[3]);
      *(uint4*)&Al4[ch][an][ag * 8] = make_uint4(lw[0], lw[1], lw[2], lw[3]);
    }
  }

  const int bd = tid >> 1, bhalf = tid & 1;
  const int bsw = (bd >> 1) & 3;
  const int bg0 = (bhalf * 2) ^ bsw, bg1 = (bhalf * 2 + 1) ^ bsw;
  const size_t bcol = (size_t)bd * 512 + bhalf * 16;
  const unsigned short* bh0 = Mh + bcol;                       // p=0
  const unsigned short* bh1 = Mh + (size_t)128 * 512 + bcol;   // p=1
  const unsigned short* bh2 = Mth + (size_t)128 * 512 + bcol;  // p=2
  const unsigned short* bl0 = Ml + bcol;
  const unsigned short* bl1 = Ml + (size_t)128 * 512 + bcol;
  const unsigned short* bl2 = Mtl + (size_t)128 * 512 + bcol;

  uint4 rbh0 = *(const uint4*)&bh0[0];
  uint4 rbh1 = *(const uint4*)&bh0[8];
  uint4 rbl0 = *(const uint4*)&bl0[0];
  uint4 rbl1 = *(const uint4*)&bl0[8];

#pragma unroll
  for (int p = 0; p < 3; ++p) {
    float* outp = (p == 0) ? Tj : (p == 1) ? (Tj + 128) : I1;
    const size_t ostride = (p == 2) ? 128 : 256;
    float4v acc[2][4];
#pragma unroll
    for (int r = 0; r < 2; ++r)
#pragma unroll
      for (int c = 0; c < 4; ++c) acc[r][c] = (float4v){0.f, 0.f, 0.f, 0.f};

#pragma unroll
    for (int ch = 0; ch < 4; ++ch) {
      __syncthreads();
      *(uint4*)&Bh[bd][bg0 * 8] = rbh0;
      *(uint4*)&Bh[bd][bg1 * 8] = rbh1;
      *(uint4*)&Bl[bd][bg0 * 8] = rbl0;
      *(uint4*)&Bl[bd][bg1 * 8] = rbl1;
      uint4 nh0, nh1, nl0, nl1;
      {
        const int s = p * 4 + ch + 1;
        if (s < 12) {
          const int np = s >> 2, nch = s & 3;
          const unsigned short* nbh = (np == 0) ? bh0 : (np == 1) ? bh1 : bh2;
          const unsigned short* nbl = (np == 0) ? bl0 : (np == 1) ? bl1 : bl2;
          nh0 = *(const uint4*)&nbh[nch * 32];
          nh1 = *(const uint4*)&nbh[nch * 32 + 8];
          nl0 = *(const uint4*)&nbl[nch * 32];
          nl1 = *(const uint4*)&nbl[nch * 32 + 8];
        }
      }
      __syncthreads();
      {
        int ln = lane & 15, kq = lane >> 4;
        short8v ah[2], al[2];
#pragma unroll
        for (int r = 0; r < 2; ++r) {
          int row = wr2 * 32 + r * 16 + ln;
          int gg = kq ^ ((row >> 1) & 3);
          ah[r] = *(const short8v*)&Ah4[ch][row][gg * 8];
          al[r] = *(const short8v*)&Al4[ch][row][gg * 8];
        }
#pragma unroll
        for (int c = 0; c < 4; ++c) {
          int col = wc2 * 64 + c * 16 + ln;
          int gg = kq ^ ((col >> 1) & 3);
          short8v bh = *(const short8v*)&Bh[col][gg * 8];
          short8v bl = *(const short8v*)&Bl[col][gg * 8];
#pragma unroll
          for (int r = 0; r < 2; ++r) {
            acc[r][c] = __builtin_amdgcn_mfma_f32_16x16x32_bf16(ah[r], bh,
                                                                acc[r][c], 0, 0, 0);
            acc[r][c] = __builtin_amdgcn_mfma_f32_16x16x32_bf16(ah[r], bl,
                                                                acc[r][c], 0, 0, 0);
            acc[r][c] = __builtin_amdgcn_mfma_f32_16x16x32_bf16(al[r], bh,
                                                                acc[r][c], 0, 0, 0);
          }
        }
      }
      rbh0 = nh0; rbh1 = nh1; rbl0 = nl0; rbl1 = nl1;
    }

    // epilogue p: transpose via ep (overlays B), coalesced store
#pragma unroll
    for (int g = 0; g < 4; ++g) {
      __syncthreads();
      EP_WRITE(g);
      __syncthreads();
      int row = tid >> 2, part = tid & 3;
      int on = n0 + row;
      if (on < N) {
        *(float4*)&outp[(size_t)on * ostride + g * 32 + part * 8] =
            *(const float4*)&ep[row][part * 8];
        *(float4*)&outp[(size_t)on * ostride + g * 32 + part * 8 + 4] =
            *(const float4*)&ep[row][part * 8 + 4];
      }
    }
  }
}

// ---------------- K3: per-query vectors w,u,y,c_b (256 thr, c-split) ------
__global__ __launch_bounds__(256) void k3_query(const float* __restrict__ qsrc,
                                                const float* __restrict__ qrel,
                                                const float* __restrict__ M,
                                                const float* __restrict__ Mt,
                                                float* __restrict__ wv,
                                                float* __restrict__ uv,
                                                float* __restrict__ yv,
                                                float* __restrict__ cb) {
  __shared__ float qcat[256];
  __shared__ float prt[5][256];
  __shared__ float red[128];
  int b = blockIdx.x, tid = threadIdx.x;
  int d = tid & 127, hc = tid >> 7;
  qcat[tid] = (tid < 128) ? qsrc[b * 128 + tid] : qrel[b * 128 + (tid - 128)];
  __syncthreads();
  float w = 0.f, u = 0.f, y = 0.f, t1 = 0.f, t2 = 0.f;
  for (int c = hc * 128; c < hc * 128 + 128; ++c) {
    float q = qcat[c];
    size_t row = (size_t)(256 + c) * 512;
    w += Mt[row + d] * q;
    u += M[row + d] * q;
    y += (Mt[row + 128 + d] + M[row + 128 + d]) * q;
    t1 += M[row + 256 + d] * q;
    t2 += M[row + 384 + d] * q;
  }
  prt[0][tid] = w; prt[1][tid] = u; prt[2][tid] = y;
  prt[3][tid] = t1; prt[4][tid] = t2;
  __syncthreads();
  if (tid < 128) {
    float wc_ = prt[0][d] + prt[0][128 + d];
    float uc = prt[1][d] + prt[1][128 + d];
    float yc = prt[2][d] + prt[2][128 + d];
    float t1c = prt[3][d] + prt[3][128 + d];
    float t2c = prt[4][d] + prt[4][128 + d];
    wv[b * 128 + d] = wc_;
    uv[b * 128 + d] = uc;
    yv[b * 128 + d] = yc;
    red[d] = qcat[d] * t1c + qcat[128 + d] * t2c;
  }
  __syncthreads();
  for (int s = 64; s > 0; s >>= 1) {
    if (tid < s) red[tid] += red[tid + s];
    __syncthreads();
  }
  if (tid == 0) cb[b] = red[0];
}

// ---------------- K4m: edge_const, 64-edge tile, reg-pipelined ------------
__global__ __launch_bounds__(256) void k4m_mfma(
    const float* __restrict__ rel, const unsigned short* __restrict__ Mth,
    const unsigned short* __restrict__ Mtl, const float* __restrict__ yv,
    const float* __restrict__ cbp, float* __restrict__ ec) {
  __shared__ char pool[24576];
  unsigned short (*Ah)[32] = (unsigned short(*)[32])pool;
  unsigned short (*Al)[32] = (unsigned short(*)[32])(pool + 4096);
  unsigned short (*Bh)[32] = (unsigned short(*)[32])(pool + 8192);
  unsigned short (*Bl)[32] = (unsigned short(*)[32])(pool + 16384);
  float (*ep)[34] = (float(*)[34])(pool + 8192);

  const int tid = threadIdx.x;
  const int lane = tid & 63;
  const int w = tid >> 6;
  const int wr2 = w >> 1, wc2 = w & 1;
  const int e0 = blockIdx.x * 64;
  const int b = e0 >> EPQ_SHIFT;

  float4v acc[2][4];
#pragma unroll
  for (int r = 0; r < 2; ++r)
#pragma unroll
    for (int c = 0; c < 4; ++c) acc[r][c] = (float4v){0.f, 0.f, 0.f, 0.f};

  const int an = tid >> 2, aq = tid & 3;
  const int ag = aq ^ ((an >> 1) & 3);
  const int bd = tid >> 1, bhalf = tid & 1;
  const int bsw = (bd >> 1) & 3;
  const int bg0 = (bhalf * 2) ^ bsw, bg1 = (bhalf * 2 + 1) ^ bsw;
  const float* asrc = rel + (size_t)(e0 + an) * 128 + aq * 8;
  const unsigned short* bhsrc = Mth + (size_t)(128 + bd) * 512 + 128 + bhalf * 16;
  const unsigned short* blsrc = Mtl + (size_t)(128 + bd) * 512 + 128 + bhalf * 16;

  float4 ra0 = *(const float4*)&asrc[0];
  float4 ra1 = *(const float4*)&asrc[4];
  uint4 rbh0 = *(const uint4*)&bhsrc[0];
  uint4 rbh1 = *(const uint4*)&bhsrc[8];
  uint4 rbl0 = *(const uint4*)&blsrc[0];
  uint4 rbl1 = *(const uint4*)&blsrc[8];

#pragma unroll
  for (int ch = 0; ch < 4; ++ch) {
    __syncthreads();
    {
      float vv[8] = {ra0.x, ra0.y, ra0.z, ra0.w, ra1.x, ra1.y, ra1.z, ra1.w};
      unsigned hw[4], lw[4];
#pragma unroll
      for (int j = 0; j < 4; ++j) {
        unsigned short h0 = f2bf(vv[2 * j]);
        unsigned short h1 = f2bf(vv[2 * j + 1]);
        unsigned short l0 = f2bf(vv[2 * j] - __uint_as_float((unsigned)h0 << 16));
        unsigned short l1 = f2bf(vv[2 * j + 1] - __uint_as_float((unsigned)h1 << 16));
        hw[j] = (unsigned)h0 | ((unsigned)h1 << 16);
        lw[j] = (unsigned)l0 | ((unsigned)l1 << 16);
      }
      *(uint4*)&Ah[an][ag * 8] = make_uint4(hw[0], hw[1], hw[2], hw[3]);
      *(uint4*)&Al[an][ag * 8] = make_uint4(lw[0], lw[1], lw[2], lw[3]);
      *(uint4*)&Bh[bd][bg0 * 8] = rbh0;
      *(uint4*)&Bh[bd][bg1 * 8] = rbh1;
      *(uint4*)&Bl[bd][bg0 * 8] = rbl0;
      *(uint4*)&Bl[bd][bg1 * 8] = rbl1;
    }
    float4 na0, na1;
    uint4 nbh0, nbh1, nbl0, nbl1;
    if (ch < 3) {
      na0 = *(const float4*)&asrc[(ch + 1) * 32];
      na1 = *(const float4*)&asrc[(ch + 1) * 32 + 4];
      nbh0 = *(const uint4*)&bhsrc[(ch + 1) * 32];
      nbh1 = *(const uint4*)&bhsrc[(ch + 1) * 32 + 8];
      nbl0 = *(const uint4*)&blsrc[(ch + 1) * 32];
      nbl1 = *(const uint4*)&blsrc[(ch + 1) * 32 + 8];
    }
    __syncthreads();
    {
      int ln = lane & 15, kq = lane >> 4;
      short8v ah[2], al[2];
#pragma unroll
      for (int r = 0; r < 2; ++r) {
        int row = wr2 * 32 + r * 16 + ln;
        int gg = kq ^ ((row >> 1) & 3);
        ah[r] = *(const short8v*)&Ah[row][gg * 8];
        al[r] = *(const short8v*)&Al[row][gg * 8];
      }
#pragma unroll
      for (int c = 0; c < 4; ++c) {
        int col = wc2 * 64 + c * 16 + ln;
        int gg = kq ^ ((col >> 1) & 3);
        short8v bh = *(const short8v*)&Bh[col][gg * 8];
        short8v bl = *(const short8v*)&Bl[col][gg * 8];
#pragma unroll
        for (int r = 0; r < 2; ++r) {
          acc[r][c] = __builtin_amdgcn_mfma_f32_16x16x32_bf16(ah[r], bh,
                                                              acc[r][c], 0, 0, 0);
          acc[r][c] = __builtin_amdgcn_mfma_f32_16x16x32_bf16(ah[r], bl,
                                                              acc[r][c], 0, 0, 0);
          acc[r][c] = __builtin_amdgcn_mfma_f32_16x16x32_bf16(al[r], bh,
                                                              acc[r][c], 0, 0, 0);
        }
      }
    }
    ra0 = na0; ra1 = na1;
    rbh0 = nbh0; rbh1 = nbh1; rbl0 = nbl0; rbl1 = nbl1;
  }

  float part = 0.f;
  const int e_loc = tid >> 2, quarter = tid & 3;
#pragma unroll
  for (int g = 0; g < 4; ++g) {
    __syncthreads();
    EP_WRITE(g);
    __syncthreads();
    const float* rsrc = rel + (size_t)(e0 + e_loc) * 128 + g * 32 + quarter * 8;
    const float* ysrc = yv + b * 128 + g * 32 + quarter * 8;
#pragma unroll
    for (int j = 0; j < 2; ++j) {
      float4 qv = *(const float4*)&ep[e_loc][quarter * 8 + 4 * j];
      float4 rr = *(const float4*)&rsrc[4 * j];
      float4 yy = *(const float4*)&ysrc[4 * j];
      part += (qv.x + yy.x) * rr.x + (qv.y + yy.y) * rr.y +
              (qv.z + yy.z) * rr.z + (qv.w + yy.w) * rr.w;
    }
  }
  part += __shfl_xor(part, 1, 64);
  part += __shfl_xor(part, 2, 64);
  if ((tid & 3) == 0) ec[e0 + e_loc] = part + cbp[b];
}

// ---------------- K5: per-edge logits + segment max (16 edges/block) ------
__global__ __launch_bounds__(256) void k5_logits(const float* __restrict__ rel,
                                                 const float* __restrict__ hv,
                                                 const float* __restrict__ Tj,
                                                 const float* __restrict__ I1,
                                                 const float* __restrict__ wv,
                                                 const float* __restrict__ uv,
                                                 const float* __restrict__ ec,
                                                 const int* __restrict__ node_i,
                                                 const int* __restrict__ node_j,
                                                 float* __restrict__ logits,
                                                 unsigned* __restrict__ segkey) {
  __shared__ float wl[128];
  __shared__ float ul[128];
  int tid = threadIdx.x;
  int e0 = blockIdx.x * 16;
  int b = e0 >> EPQ_SHIFT;
  if (tid < 128) wl[tid] = wv[b * 128 + tid];
  else ul[tid - 128] = uv[b * 128 + (tid - 128)];
  __syncthreads();
  int lane = tid & 15, eg = tid >> 4;
  int e = e0 + eg;
  int i = node_i[e], j = node_j[e];
  int c0 = lane * 8;

  float rr[8], hi[8], hj[8], a0[8], a1[8], ii[8];
  *(float4*)&rr[0] = *(const float4*)&rel[(size_t)e * 128 + c0];
  *(float4*)&rr[4] = *(const float4*)&rel[(size_t)e * 128 + c0 + 4];
  *(float4*)&hi[0] = *(const float4*)&hv[(size_t)i * 128 + c0];
  *(float4*)&hi[4] = *(const float4*)&hv[(size_t)i * 128 + c0 + 4];
  *(float4*)&hj[0] = *(const float4*)&hv[(size_t)j * 128 + c0];
  *(float4*)&hj[4] = *(const float4*)&hv[(size_t)j * 128 + c0 + 4];
  *(float4*)&a0[0] = *(const float4*)&Tj[(size_t)j * 256 + c0];
  *(float4*)&a0[4] = *(const float4*)&Tj[(size_t)j * 256 + c0 + 4];
  *(float4*)&a1[0] = *(const float4*)&Tj[(size_t)j * 256 + 128 + c0];
  *(float4*)&a1[4] = *(const float4*)&Tj[(size_t)j * 256 + 128 + c0 + 4];
  *(float4*)&ii[0] = *(const float4*)&I1[(size_t)i * 128 + c0];
  *(float4*)&ii[4] = *(const float4*)&I1[(size_t)i * 128 + c0 + 4];

  float p = 0.f;
#pragma unroll
  for (int k = 0; k < 8; ++k) {
    p += hi[k] * a0[k];               // hvi . J0[j]
    p += rr[k] * (a1[k] + ii[k]);     // rel . (J1[j] + I1[i])
    p += hi[k] * wl[c0 + k];          // hvi . w_b
    p += hj[k] * ul[c0 + k];          // hvj . u_b
  }
#pragma unroll
  for (int m = 8; m >= 1; m >>= 1) p += __shfl_xor(p, m, 64);
  if (lane == 0) {
    float lg = p + ec[e];
    logits[e] = lg;
    atomicMax(&segkey[i], enc_f(lg));
  }
}

// ---------------- K6: ex = exp(logit - segmax), segment sum ----------------
__global__ void k6_exp(float* __restrict__ exb, const int* __restrict__ node_i,
                       const unsigned* __restrict__ segkey,
                       float* __restrict__ segsum, int E) {
  int e = blockIdx.x * 256 + threadIdx.x;
  if (e >= E) return;
  int i = node_i[e];
  float m = dec_f(segkey[i]);
  float ex = expf(exb[e] - m);
  exb[e] = ex;
  atomicAdd(&segsum[i], ex);
}

// ---------------- K7: top-256 radix select, shfl-scan version -------------
__global__ __launch_bounds__(256) void k7_topk(const float* __restrict__ exb,
                                               const int* __restrict__ node_i,
                                               const int* __restrict__ node_j,
                                               const float* __restrict__ segsum,
                                               const float* __restrict__ score,
                                               float* __restrict__ out) {
  __shared__ unsigned vals[2048];
  __shared__ unsigned hist[256];
  __shared__ unsigned wtot[4];
  __shared__ unsigned sel_info[2];
  int q = blockIdx.x, t = threadIdx.x;
  int lane = t & 63, w = t >> 6;
  size_t base = (size_t)q * 2048;
#pragma unroll
  for (int l = 0; l < 8; ++l) {
    int el = t * 8 + l;
    int i = node_i[base + el];
    float tgt = exb[base + el] / segsum[i] * score[i];  // attn * src_score >= 0
    vals[el] = __float_as_uint(tgt);
  }
  __syncthreads();
  unsigned prefix = 0, need = KSEL;
  for (int pass = 3; pass >= 0; --pass) {
    hist[t] = 0;
    __syncthreads();
    int sh = pass * 8;
#pragma unroll
    for (int l = 0; l < 8; ++l) {
      unsigned v = vals[t * 8 + l];
      bool match = (pass == 3) || ((v >> (sh + 8)) == (prefix >> (sh + 8)));
      if (match) atomicAdd(&hist[(v >> sh) & 255u], 1u);
    }
    __syncthreads();
    unsigned myh = hist[t];
    unsigned v = myh;
    // wave-local inclusive SUFFIX scan (Hillis-Steele via shfl_down)
#pragma unroll
    for (int off = 1; off < 64; off <<= 1) {
      unsigned o = __shfl_down(v, off, 64);
      if (lane + off < 64) v += o;
    }
    if (lane == 0) wtot[w] = v;  // total of this wave's 64 bins
    __syncthreads();
    unsigned sct = v;
    for (int ww = w + 1; ww < 4; ++ww) sct += wtot[ww];
    unsigned above = sct - myh;
    if (above < need && need <= sct) {
      sel_info[0] = (unsigned)t;
      sel_info[1] = need - above;
    }
    __syncthreads();
    prefix |= sel_info[0] << sh;
    need = sel_info[1];
    __syncthreads();
  }
  unsigned T = prefix, r = need;
  unsigned lc = 0;
#pragma unroll
  for (int l = 0; l < 8; ++l)
    if (vals[t * 8 + l] == T) lc++;
  // forward inclusive PREFIX scan of lc (shfl_up + wave combine)
  unsigned v = lc;
#pragma unroll
  for (int off = 1; off < 64; off <<= 1) {
    unsigned o = __shfl_up(v, off, 64);
    if (lane >= off) v += o;
  }
  if (lane == 63) wtot[w] = v;
  __syncthreads();
  unsigned pre = 0;
  for (int ww = 0; ww < w; ++ww) pre += wtot[ww];
  unsigned excl = v + pre - lc;
  unsigned cnt = 0;
#pragma unroll
  for (int l = 0; l < 8; ++l) {
    int el = t * 8 + l;
    unsigned vv = vals[el];
    bool take = false;
    if (vv > T) take = true;
    else if (vv == T) { if (excl + cnt < r) take = true; cnt++; }
    if (take) {
      int j = node_j[base + el];
      atomicAdd(&out[j], __uint_as_float(vv));
    }
  }
}

// ---------------- host ----------------
extern "C" void kernel_launch(void* const* d_in, const int* in_sizes, int n_in,
                              void* d_out, int out_size, void* d_ws, size_t ws_size,
                              hipStream_t stream) {
  const float* score = (const float*)d_in[0];
  const float* hv    = (const float*)d_in[1];
  const float* rel   = (const float*)d_in[2];
  const float* qsrc  = (const float*)d_in[3];
  const float* qrel  = (const float*)d_in[4];
  const float* Wq    = (const float*)d_in[5];
  const float* Wk    = (const float*)d_in[6];
  const int* node_i  = (const int*)d_in[8];
  const int* node_j  = (const int*)d_in[9];

  const int N = in_sizes[0];            // 50000
  const int B = in_sizes[3] / 128;      // 64
  const int E = in_sizes[2] / 128;      // 131072

  float* ws = (float*)d_ws;
  float* M  = ws;
  float* Mt = M + 262144;
  float* Tj = Mt + 262144;              // [N][256] = J0|J1 packed
  float* I1 = Tj + (size_t)N * 256;
  float* wv = I1 + (size_t)N * 128;
  float* uv = wv + (size_t)B * 128;
  float* yv = uv + (size_t)B * 128;
  float* cb = yv + (size_t)B * 128;
  float* ec = cb + B;
  float* exb = ec + E;
  unsigned* segkey = (unsigned*)(exb + E);
  float* segsum = (float*)(segkey + N);
  unsigned short* Mh  = (unsigned short*)(segsum + N);
  unsigned short* Ml  = Mh + 262144;
  unsigned short* Mth = Ml + 262144;
  unsigned short* Mtl = Mth + 262144;
  float* out = (float*)d_out;

  k1_gemmM<<<dim3(8, 8), 256, 0, stream>>>(Wq, Wk, M, Mt, Mh, Ml, Mth, Mtl,
                                           out, segsum, segkey, N);
  k2m3_mfma<<<(N + 63) / 64, 256, 0, stream>>>(hv, Mh, Ml, Mth, Mtl, Tj, I1, N);
  k3_query<<<B, 256, 0, stream>>>(qsrc, qrel, M, Mt, wv, uv, yv, cb);
  k4m_mfma<<<E / 64, 256, 0, stream>>>(rel, Mth, Mtl, yv, cb, ec);
  k5_logits<<<E / 16, 256, 0, stream>>>(rel, hv, Tj, I1, wv, uv, ec,
                                        node_i, node_j, exb, segkey);
  k6_exp<<<(E + 255) / 256, 256, 0, stream>>>(exb, node_i, segkey, segsum, E);
  k7_topk<<<B, 256, 0, stream>>>(exb, node_i, node_j, segsum, score, out);
}

// Round 18
// 211.204 us; speedup vs baseline: 1.5278x; 1.0140x over previous
//
#include <hip/hip_runtime.h>
#include <cstddef>

// Problem constants (fixed by the reference)
#define EPQ_SHIFT 11       // EPQ = 2048
#define KSEL 256

typedef __attribute__((ext_vector_type(8))) short short8v;   // 8 bf16
typedef __attribute__((ext_vector_type(4))) float float4v;   // MFMA acc

__device__ __forceinline__ unsigned enc_f(float f) {
  unsigned u = __float_as_uint(f);
  return (u & 0x80000000u) ? ~u : (u | 0x80000000u);
}
__device__ __forceinline__ float dec_f(unsigned k) {
  unsigned u = (k & 0x80000000u) ? (k ^ 0x80000000u) : ~k;
  return __uint_as_float(u);
}
__device__ __forceinline__ unsigned short f2bf(float x) {  // RNE f32->bf16
  unsigned u = __float_as_uint(x);
  return (unsigned short)((u + 0x7FFFu + ((u >> 16) & 1u)) >> 16);
}

// ---------------- K1: init buffers + M = Wq^T Wk + Mt + bf16 splits -------
__global__ __launch_bounds__(256) void k1_gemmM(
    const float* __restrict__ Wq, const float* __restrict__ Wk,
    float* __restrict__ M, float* __restrict__ Mt,
    unsigned short* __restrict__ Mh, unsigned short* __restrict__ Ml,
    unsigned short* __restrict__ Mth, unsigned short* __restrict__ Mtl,
    float* __restrict__ outz, float* __restrict__ segsum,
    unsigned* __restrict__ segkey, int N) {
  int tid = threadIdx.x;
  {  // folded k0: zero out/segsum/segkey
    int bid = blockIdx.y * gridDim.x + blockIdx.x;
    for (int idx = bid * 256 + tid; idx < N; idx += 16384) {
      outz[idx] = 0.f;
      segsum[idx] = 0.f;
      segkey[idx] = 0u;
    }
  }
  __shared__ float as[16][64];
  __shared__ float bs[16][64];
  int tx = tid & 15, ty = tid >> 4;
  int c1b = blockIdx.y * 64, c2b = blockIdx.x * 64;
  float acc[4][4] = {};
  for (int k0 = 0; k0 < 512; k0 += 16) {
#pragma unroll
    for (int l = 0; l < 4; ++l) {
      int lin = tid + l * 256;
      int kk = lin >> 6, c = lin & 63;
      as[kk][c] = Wq[(k0 + kk) * 512 + c1b + c];
      bs[kk][c] = Wk[(k0 + kk) * 512 + c2b + c];
    }
    __syncthreads();
#pragma unroll
    for (int kk = 0; kk < 16; ++kk) {
      float a[4], b[4];
#pragma unroll
      for (int m = 0; m < 4; ++m) a[m] = as[kk][ty * 4 + m];
#pragma unroll
      for (int n = 0; n < 4; ++n) b[n] = bs[kk][tx * 4 + n];
#pragma unroll
      for (int m = 0; m < 4; ++m)
#pragma unroll
        for (int n = 0; n < 4; ++n) acc[m][n] += a[m] * b[n];
    }
    __syncthreads();
  }
#pragma unroll
  for (int m = 0; m < 4; ++m)
#pragma unroll
    for (int n = 0; n < 4; ++n) {
      int c1 = c1b + ty * 4 + m, c2 = c2b + tx * 4 + n;
      float v = acc[m][n];
      M[c1 * 512 + c2] = v;
      Mt[c2 * 512 + c1] = v;
      unsigned short h = f2bf(v);
      unsigned short lo = f2bf(v - __uint_as_float((unsigned)h << 16));
      Mh[c1 * 512 + c2] = h;
      Ml[c1 * 512 + c2] = lo;
      Mth[c2 * 512 + c1] = h;
      Mtl[c2 * 512 + c1] = lo;
    }
}

// ===== shared MFMA macros =====
#define EP_WRITE(GRP)                                                        \
  if (wc2 == ((GRP) >> 1)) {                                                 \
    int ln = lane & 15, kq = lane >> 4;                                      \
    _Pragma("unroll") for (int cc = 0; cc < 2; ++cc) {                       \
      int c = ((GRP) & 1) * 2 + cc;                                          \
      _Pragma("unroll") for (int r = 0; r < 2; ++r)                          \
        _Pragma("unroll") for (int reg = 0; reg < 4; ++reg)                  \
          ep[wr2 * 32 + r * 16 + kq * 4 + reg][cc * 16 + ln] =               \
              acc[r][c][reg];                                                \
  }                                                                          \
  }

// ---------------- K2m3: ALL 3 projections, operand-swapped MFMA ----------
// A = M-table rows (d, 128), B = hv (64 nodes). D-frag: col=node(lane&15),
// row=d (kq*4+reg contiguous) -> accumulators store DIRECTLY as float4 to
// out[node][d0..d0+3]; no epilogue transpose, no epilogue barriers.
// hv staged ONCE (bf16 hi/lo, 4 chunks, 32KB); M tiles reg-prefetched
// across the flattened (p,ch) sequence. Product order (Mh*hvh, Ml*hvh,
// Mh*hvl) == old (hvh*Mh, hvh*Ml, hvl*Mh) -> bit-identical outputs.
__global__ __launch_bounds__(256) void k2m3_mfma(
    const float* __restrict__ hv, const unsigned short* __restrict__ Mh,
    const unsigned short* __restrict__ Ml, const unsigned short* __restrict__ Mth,
    const unsigned short* __restrict__ Mtl, float* __restrict__ Tj,
    float* __restrict__ I1, int N) {
  __shared__ char pool[49152];
  unsigned short (*Hh4)[64][32] = (unsigned short(*)[64][32])pool;            // 16KB
  unsigned short (*Hl4)[64][32] = (unsigned short(*)[64][32])(pool + 16384);  // 16KB
  unsigned short (*Bh)[32] = (unsigned short(*)[32])(pool + 32768);           // 8KB
  unsigned short (*Bl)[32] = (unsigned short(*)[32])(pool + 40960);           // 8KB

  const int tid = threadIdx.x;
  const int lane = tid & 63;
  const int w = tid >> 6;
  const int wr2 = w >> 1, wc2 = w & 1;  // wr2: 64-d half, wc2: 32-node half
  const int n0 = blockIdx.x * 64;

  // ---- stage hv once: [64 nodes][128] -> bf16 hi/lo, 4 K-chunks ----
  {
    const int an = tid >> 2, aq = tid & 3;
    const int ag = aq ^ ((an >> 1) & 3);
    int gn = n0 + an;
    gn = gn < N ? gn : N - 1;
    const float* asrc = hv + (size_t)gn * 128 + aq * 8;
#pragma unroll
    for (int ch = 0; ch < 4; ++ch) {
      float4 v0 = *(const float4*)&asrc[ch * 32];
      float4 v1 = *(const float4*)&asrc[ch * 32 + 4];
      float vv[8] = {v0.x, v0.y, v0.z, v0.w, v1.x, v1.y, v1.z, v1.w};
      unsigned hw[4], lw[4];
#pragma unroll
      for (int j = 0; j < 4; ++j) {
        unsigned short h0 = f2bf(vv[2 * j]);
        unsigned short h1 = f2bf(vv[2 * j + 1]);
        unsigned short l0 = f2bf(vv[2 * j] - __uint_as_float((unsigned)h0 << 16));
        unsigned short l1 = f2bf(vv[2 * j + 1] - __uint_as_float((unsigned)h1 << 16));
        hw[j] = (unsigned)h0 | ((unsigned)h1 << 16);
        lw[j] = (unsigned)l0 | ((unsigned)l1 << 16);
      }
      *(uint4*)&Hh4[ch][an][ag * 8] = make_uint4(hw[0], hw[1], hw[2], hw[3]);
      *(uint4*)&Hl4[ch][an][ag * 8] = make_uint4(lw[0], lw[1], lw[2], lw[3]);
    }
  }

  const int bd = tid >> 1, bhalf = tid & 1;
  const int bsw = (bd >> 1) & 3;
  const int bg0 = (bhalf * 2) ^ bsw, bg1 = (bhalf * 2 + 1) ^ bsw;
  const size_t bcol = (size_t)bd * 512 + bhalf * 16;
  const unsigned short* bh0 = Mh + bcol;                       // p=0
  const unsigned short* bh1 = Mh + (size_t)128 * 512 + bcol;   // p=1
  const unsigned short* bh2 = Mth + (size_t)128 * 512 + bcol;  // p=2
  const unsigned short* bl0 = Ml + bcol;
  const unsigned short* bl1 = Ml + (size_t)128 * 512 + bcol;
  const unsigned short* bl2 = Mtl + (size_t)128 * 512 + bcol;

  uint4 rbh0 = *(const uint4*)&bh0[0];
  uint4 rbh1 = *(const uint4*)&bh0[8];
  uint4 rbl0 = *(const uint4*)&bl0[0];
  uint4 rbl1 = *(const uint4*)&bl0[8];

#pragma unroll
  for (int p = 0; p < 3; ++p) {
    float* outp = (p == 0) ? Tj : (p == 1) ? (Tj + 128) : I1;
    const size_t ostride = (p == 2) ? 128 : 256;
    float4v acc[4][2];  // [d-frag r][node-frag c]
#pragma unroll
    for (int r = 0; r < 4; ++r)
#pragma unroll
      for (int c = 0; c < 2; ++c) acc[r][c] = (float4v){0.f, 0.f, 0.f, 0.f};

#pragma unroll
    for (int ch = 0; ch < 4; ++ch) {
      __syncthreads();
      *(uint4*)&Bh[bd][bg0 * 8] = rbh0;
      *(uint4*)&Bh[bd][bg1 * 8] = rbh1;
      *(uint4*)&Bl[bd][bg0 * 8] = rbl0;
      *(uint4*)&Bl[bd][bg1 * 8] = rbl1;
      uint4 nh0, nh1, nl0, nl1;
      {
        const int s = p * 4 + ch + 1;
        if (s < 12) {
          const int np = s >> 2, nch = s & 3;
          const unsigned short* nbh = (np == 0) ? bh0 : (np == 1) ? bh1 : bh2;
          const unsigned short* nbl = (np == 0) ? bl0 : (np == 1) ? bl1 : bl2;
          nh0 = *(const uint4*)&nbh[nch * 32];
          nh1 = *(const uint4*)&nbh[nch * 32 + 8];
          nl0 = *(const uint4*)&nbl[nch * 32];
          nl1 = *(const uint4*)&nbl[nch * 32 + 8];
        }
      }
      __syncthreads();
      {
        int ln = lane & 15, kq = lane >> 4;
        short8v mhf[4], mlf[4];
#pragma unroll
        for (int r = 0; r < 4; ++r) {
          int row = wr2 * 64 + r * 16 + ln;  // d index
          int gg = kq ^ ((row >> 1) & 3);
          mhf[r] = *(const short8v*)&Bh[row][gg * 8];
          mlf[r] = *(const short8v*)&Bl[row][gg * 8];
        }
#pragma unroll
        for (int c = 0; c < 2; ++c) {
          int col = wc2 * 32 + c * 16 + ln;  // node index
          int gg = kq ^ ((col >> 1) & 3);
          short8v hh = *(const short8v*)&Hh4[ch][col][gg * 8];
          short8v hl = *(const short8v*)&Hl4[ch][col][gg * 8];
#pragma unroll
          for (int r = 0; r < 4; ++r) {
            acc[r][c] = __builtin_amdgcn_mfma_f32_16x16x32_bf16(mhf[r], hh,
                                                                acc[r][c], 0, 0, 0);
            acc[r][c] = __builtin_amdgcn_mfma_f32_16x16x32_bf16(mlf[r], hh,
                                                                acc[r][c], 0, 0, 0);
            acc[r][c] = __builtin_amdgcn_mfma_f32_16x16x32_bf16(mhf[r], hl,
                                                                acc[r][c], 0, 0, 0);
          }
        }
      }
      rbh0 = nh0; rbh1 = nh1; rbl0 = nl0; rbl1 = nl1;
    }

    // epilogue p: direct fragment stores (no barriers, no LDS)
    {
      int ln = lane & 15, kq = lane >> 4;
#pragma unroll
      for (int c = 0; c < 2; ++c) {
        int nl = wc2 * 32 + c * 16 + ln;
        int gn = n0 + nl;
        if (gn < N) {
#pragma unroll
          for (int r = 0; r < 4; ++r) {
            int d0 = wr2 * 64 + r * 16 + kq * 4;
            float4 o = {acc[r][c][0], acc[r][c][1], acc[r][c][2], acc[r][c][3]};
            *(float4*)&outp[(size_t)gn * ostride + d0] = o;
          }
        }
      }
    }
  }
}

// ---------------- K3: per-query vectors w,u,y,c_b (256 thr, c-split) ------
__global__ __launch_bounds__(256) void k3_query(const float* __restrict__ qsrc,
                                                const float* __restrict__ qrel,
                                                const float* __restrict__ M,
                                                const float* __restrict__ Mt,
                                                float* __restrict__ wv,
                                                float* __restrict__ uv,
                                                float* __restrict__ yv,
                                                float* __restrict__ cb) {
  __shared__ float qcat[256];
  __shared__ float prt[5][256];
  __shared__ float red[128];
  int b = blockIdx.x, tid = threadIdx.x;
  int d = tid & 127, hc = tid >> 7;
  qcat[tid] = (tid < 128) ? qsrc[b * 128 + tid] : qrel[b * 128 + (tid - 128)];
  __syncthreads();
  float w = 0.f, u = 0.f, y = 0.f, t1 = 0.f, t2 = 0.f;
  for (int c = hc * 128; c < hc * 128 + 128; ++c) {
    float q = qcat[c];
    size_t row = (size_t)(256 + c) * 512;
    w += Mt[row + d] * q;
    u += M[row + d] * q;
    y += (Mt[row + 128 + d] + M[row + 128 + d]) * q;
    t1 += M[row + 256 + d] * q;
    t2 += M[row + 384 + d] * q;
  }
  prt[0][tid] = w; prt[1][tid] = u; prt[2][tid] = y;
  prt[3][tid] = t1; prt[4][tid] = t2;
  __syncthreads();
  if (tid < 128) {
    float wc_ = prt[0][d] + prt[0][128 + d];
    float uc = prt[1][d] + prt[1][128 + d];
    float yc = prt[2][d] + prt[2][128 + d];
    float t1c = prt[3][d] + prt[3][128 + d];
    float t2c = prt[4][d] + prt[4][128 + d];
    wv[b * 128 + d] = wc_;
    uv[b * 128 + d] = uc;
    yv[b * 128 + d] = yc;
    red[d] = qcat[d] * t1c + qcat[128 + d] * t2c;
  }
  __syncthreads();
  for (int s = 64; s > 0; s >>= 1) {
    if (tid < s) red[tid] += red[tid + s];
    __syncthreads();
  }
  if (tid == 0) cb[b] = red[0];
}

// ---------------- K4m: edge_const, 64-edge tile, reg-pipelined ------------
__global__ __launch_bounds__(256) void k4m_mfma(
    const float* __restrict__ rel, const unsigned short* __restrict__ Mth,
    const unsigned short* __restrict__ Mtl, const float* __restrict__ yv,
    const float* __restrict__ cbp, float* __restrict__ ec) {
  __shared__ char pool[24576];
  unsigned short (*Ah)[32] = (unsigned short(*)[32])pool;
  unsigned short (*Al)[32] = (unsigned short(*)[32])(pool + 4096);
  unsigned short (*Bh)[32] = (unsigned short(*)[32])(pool + 8192);
  unsigned short (*Bl)[32] = (unsigned short(*)[32])(pool + 16384);
  float (*ep)[34] = (float(*)[34])(pool + 8192);

  const int tid = threadIdx.x;
  const int lane = tid & 63;
  const int w = tid >> 6;
  const int wr2 = w >> 1, wc2 = w & 1;
  const int e0 = blockIdx.x * 64;
  const int b = e0 >> EPQ_SHIFT;

  float4v acc[2][4];
#pragma unroll
  for (int r = 0; r < 2; ++r)
#pragma unroll
    for (int c = 0; c < 4; ++c) acc[r][c] = (float4v){0.f, 0.f, 0.f, 0.f};

  const int an = tid >> 2, aq = tid & 3;
  const int ag = aq ^ ((an >> 1) & 3);
  const int bd = tid >> 1, bhalf = tid & 1;
  const int bsw = (bd >> 1) & 3;
  const int bg0 = (bhalf * 2) ^ bsw, bg1 = (bhalf * 2 + 1) ^ bsw;
  const float* asrc = rel + (size_t)(e0 + an) * 128 + aq * 8;
  const unsigned short* bhsrc = Mth + (size_t)(128 + bd) * 512 + 128 + bhalf * 16;
  const unsigned short* blsrc = Mtl + (size_t)(128 + bd) * 512 + 128 + bhalf * 16;

  float4 ra0 = *(const float4*)&asrc[0];
  float4 ra1 = *(const float4*)&asrc[4];
  uint4 rbh0 = *(const uint4*)&bhsrc[0];
  uint4 rbh1 = *(const uint4*)&bhsrc[8];
  uint4 rbl0 = *(const uint4*)&blsrc[0];
  uint4 rbl1 = *(const uint4*)&blsrc[8];

#pragma unroll
  for (int ch = 0; ch < 4; ++ch) {
    __syncthreads();
    {
      float vv[8] = {ra0.x, ra0.y, ra0.z, ra0.w, ra1.x, ra1.y, ra1.z, ra1.w};
      unsigned hw[4], lw[4];
#pragma unroll
      for (int j = 0; j < 4; ++j) {
        unsigned short h0 = f2bf(vv[2 * j]);
        unsigned short h1 = f2bf(vv[2 * j + 1]);
        unsigned short l0 = f2bf(vv[2 * j] - __uint_as_float((unsigned)h0 << 16));
        unsigned short l1 = f2bf(vv[2 * j + 1] - __uint_as_float((unsigned)h1 << 16));
        hw[j] = (unsigned)h0 | ((unsigned)h1 << 16);
        lw[j] = (unsigned)l0 | ((unsigned)l1 << 16);
      }
      *(uint4*)&Ah[an][ag * 8] = make_uint4(hw[0], hw[1], hw[2], hw[3]);
      *(uint4*)&Al[an][ag * 8] = make_uint4(lw[0], lw[1], lw[2], lw[3]);
      *(uint4*)&Bh[bd][bg0 * 8] = rbh0;
      *(uint4*)&Bh[bd][bg1 * 8] = rbh1;
      *(uint4*)&Bl[bd][bg0 * 8] = rbl0;
      *(uint4*)&Bl[bd][bg1 * 8] = rbl1;
    }
    float4 na0, na1;
    uint4 nbh0, nbh1, nbl0, nbl1;
    if (ch < 3) {
      na0 = *(const float4*)&asrc[(ch + 1) * 32];
      na1 = *(const float4*)&asrc[(ch + 1) * 32 + 4];
      nbh0 = *(const uint4*)&bhsrc[(ch + 1) * 32];
      nbh1 = *(const uint4*)&bhsrc[(ch + 1) * 32 + 8];
      nbl0 = *(const uint4*)&blsrc[(ch + 1) * 32];
      nbl1 = *(const uint4*)&blsrc[(ch + 1) * 32 + 8];
    }
    __syncthreads();
    {
      int ln = lane & 15, kq = lane >> 4;
      short8v ah[2], al[2];
#pragma unroll
      for (int r = 0; r < 2; ++r) {
        int row = wr2 * 32 + r * 16 + ln;
        int gg = kq ^ ((row >> 1) & 3);
        ah[r] = *(const short8v*)&Ah[row][gg * 8];
        al[r] = *(const short8v*)&Al[row][gg * 8];
      }
#pragma unroll
      for (int c = 0; c < 4; ++c) {
        int col = wc2 * 64 + c * 16 + ln;
        int gg = kq ^ ((col >> 1) & 3);
        short8v bh = *(const short8v*)&Bh[col][gg * 8];
        short8v bl = *(const short8v*)&Bl[col][gg * 8];
#pragma unroll
        for (int r = 0; r < 2; ++r) {
          acc[r][c] = __builtin_amdgcn_mfma_f32_16x16x32_bf16(ah[r], bh,
                                                              acc[r][c], 0, 0, 0);
          acc[r][c] = __builtin_amdgcn_mfma_f32_16x16x32_bf16(ah[r], bl,
                                                              acc[r][c], 0, 0, 0);
          acc[r][c] = __builtin_amdgcn_mfma_f32_16x16x32_bf16(al[r], bh,
                                                              acc[r][c], 0, 0, 0);
        }
      }
    }
    ra0 = na0; ra1 = na1;
    rbh0 = nbh0; rbh1 = nbh1; rbl0 = nbl0; rbl1 = nbl1;
  }

  float part = 0.f;
  const int e_loc = tid >> 2, quarter = tid & 3;
#pragma unroll
  for (int g = 0; g < 4; ++g) {
    __syncthreads();
    EP_WRITE(g);
    __syncthreads();
    const float* rsrc = rel + (size_t)(e0 + e_loc) * 128 + g * 32 + quarter * 8;
    const float* ysrc = yv + b * 128 + g * 32 + quarter * 8;
#pragma unroll
    for (int j = 0; j < 2; ++j) {
      float4 qv = *(const float4*)&ep[e_loc][quarter * 8 + 4 * j];
      float4 rr = *(const float4*)&rsrc[4 * j];
      float4 yy = *(const float4*)&ysrc[4 * j];
      part += (qv.x + yy.x) * rr.x + (qv.y + yy.y) * rr.y +
              (qv.z + yy.z) * rr.z + (qv.w + yy.w) * rr.w;
    }
  }
  part += __shfl_xor(part, 1, 64);
  part += __shfl_xor(part, 2, 64);
  if ((tid & 3) == 0) ec[e0 + e_loc] = part + cbp[b];
}

// ---------------- K5: per-edge logits + segment max (16 edges/block) ------
__global__ __launch_bounds__(256) void k5_logits(const float* __restrict__ rel,
                                                 const float* __restrict__ hv,
                                                 const float* __restrict__ Tj,
                                                 const float* __restrict__ I1,
                                                 const float* __restrict__ wv,
                                                 const float* __restrict__ uv,
                                                 const float* __restrict__ ec,
                                                 const int* __restrict__ node_i,
                                                 const int* __restrict__ node_j,
                                                 float* __restrict__ logits,
                                                 unsigned* __restrict__ segkey) {
  __shared__ float wl[128];
  __shared__ float ul[128];
  int tid = threadIdx.x;
  int e0 = blockIdx.x * 16;
  int b = e0 >> EPQ_SHIFT;
  if (tid < 128) wl[tid] = wv[b * 128 + tid];
  else ul[tid - 128] = uv[b * 128 + (tid - 128)];
  __syncthreads();
  int lane = tid & 15, eg = tid >> 4;
  int e = e0 + eg;
  int i = node_i[e], j = node_j[e];
  int c0 = lane * 8;

  float rr[8], hi[8], hj[8], a0[8], a1[8], ii[8];
  *(float4*)&rr[0] = *(const float4*)&rel[(size_t)e * 128 + c0];
  *(float4*)&rr[4] = *(const float4*)&rel[(size_t)e * 128 + c0 + 4];
  *(float4*)&hi[0] = *(const float4*)&hv[(size_t)i * 128 + c0];
  *(float4*)&hi[4] = *(const float4*)&hv[(size_t)i * 128 + c0 + 4];
  *(float4*)&hj[0] = *(const float4*)&hv[(size_t)j * 128 + c0];
  *(float4*)&hj[4] = *(const float4*)&hv[(size_t)j * 128 + c0 + 4];
  *(float4*)&a0[0] = *(const float4*)&Tj[(size_t)j * 256 + c0];
  *(float4*)&a0[4] = *(const float4*)&Tj[(size_t)j * 256 + c0 + 4];
  *(float4*)&a1[0] = *(const float4*)&Tj[(size_t)j * 256 + 128 + c0];
  *(float4*)&a1[4] = *(const float4*)&Tj[(size_t)j * 256 + 128 + c0 + 4];
  *(float4*)&ii[0] = *(const float4*)&I1[(size_t)i * 128 + c0];
  *(float4*)&ii[4] = *(const float4*)&I1[(size_t)i * 128 + c0 + 4];

  float p = 0.f;
#pragma unroll
  for (int k = 0; k < 8; ++k) {
    p += hi[k] * a0[k];               // hvi . J0[j]
    p += rr[k] * (a1[k] + ii[k]);     // rel . (J1[j] + I1[i])
    p += hi[k] * wl[c0 + k];          // hvi . w_b
    p += hj[k] * ul[c0 + k];          // hvj . u_b
  }
#pragma unroll
  for (int m = 8; m >= 1; m >>= 1) p += __shfl_xor(p, m, 64);
  if (lane == 0) {
    float lg = p + ec[e];
    logits[e] = lg;
    atomicMax(&segkey[i], enc_f(lg));
  }
}

// ---------------- K6: ex = exp(logit - segmax), segment sum ----------------
__global__ void k6_exp(float* __restrict__ exb, const int* __restrict__ node_i,
                       const unsigned* __restrict__ segkey,
                       float* __restrict__ segsum, int E) {
  int e = blockIdx.x * 256 + threadIdx.x;
  if (e >= E) return;
  int i = node_i[e];
  float m = dec_f(segkey[i]);
  float ex = expf(exb[e] - m);
  exb[e] = ex;
  atomicAdd(&segsum[i], ex);
}

// ---------------- K7: top-256 radix select, shfl-scan version -------------
__global__ __launch_bounds__(256) void k7_topk(const float* __restrict__ exb,
                                               const int* __restrict__ node_i,
                                               const int* __restrict__ node_j,
                                               const float* __restrict__ segsum,
                                               const float* __restrict__ score,
                                               float* __restrict__ out) {
  __shared__ unsigned vals[2048];
  __shared__ unsigned hist[256];
  __shared__ unsigned wtot[4];
  __shared__ unsigned sel_info[2];
  int q = blockIdx.x, t = threadIdx.x;
  int lane = t & 63, w = t >> 6;
  size_t base = (size_t)q * 2048;
#pragma unroll
  for (int l = 0; l < 8; ++l) {
    int el = t * 8 + l;
    int i = node_i[base + el];
    float tgt = exb[base + el] / segsum[i] * score[i];  // attn * src_score >= 0
    vals[el] = __float_as_uint(tgt);
  }
  __syncthreads();
  unsigned prefix = 0, need = KSEL;
  for (int pass = 3; pass >= 0; --pass) {
    hist[t] = 0;
    __syncthreads();
    int sh = pass * 8;
#pragma unroll
    for (int l = 0; l < 8; ++l) {
      unsigned v = vals[t * 8 + l];
      bool match = (pass == 3) || ((v >> (sh + 8)) == (prefix >> (sh + 8)));
      if (match) atomicAdd(&hist[(v >> sh) & 255u], 1u);
    }
    __syncthreads();
    unsigned myh = hist[t];
    unsigned v = myh;
    // wave-local inclusive SUFFIX scan (Hillis-Steele via shfl_down)
#pragma unroll
    for (int off = 1; off < 64; off <<= 1) {
      unsigned o = __shfl_down(v, off, 64);
      if (lane + off < 64) v += o;
    }
    if (lane == 0) wtot[w] = v;  // total of this wave's 64 bins
    __syncthreads();
    unsigned sct = v;
    for (int ww = w + 1; ww < 4; ++ww) sct += wtot[ww];
    unsigned above = sct - myh;
    if (above < need && need <= sct) {
      sel_info[0] = (unsigned)t;
      sel_info[1] = need - above;
    }
    __syncthreads();
    prefix |= sel_info[0] << sh;
    need = sel_info[1];
    __syncthreads();
  }
  unsigned T = prefix, r = need;
  unsigned lc = 0;
#pragma unroll
  for (int l = 0; l < 8; ++l)
    if (vals[t * 8 + l] == T) lc++;
  // forward inclusive PREFIX scan of lc (shfl_up + wave combine)
  unsigned v = lc;
#pragma unroll
  for (int off = 1; off < 64; off <<= 1) {
    unsigned o = __shfl_up(v, off, 64);
    if (lane >= off) v += o;
  }
  if (lane == 63) wtot[w] = v;
  __syncthreads();
  unsigned pre = 0;
  for (int ww = 0; ww < w; ++ww) pre += wtot[ww];
  unsigned excl = v + pre - lc;
  unsigned cnt = 0;
#pragma unroll
  for (int l = 0; l < 8; ++l) {
    int el = t * 8 + l;
    unsigned vv = vals[el];
    bool take = false;
    if (vv > T) take = true;
    else if (vv == T) { if (excl + cnt < r) take = true; cnt++; }
    if (take) {
      int j = node_j[base + el];
      atomicAdd(&out[j], __uint_as_float(vv));
    }
  }
}

// ---------------- host ----------------
extern "C" void kernel_launch(void* const* d_in, const int* in_sizes, int n_in,
                              void* d_out, int out_size, void* d_ws, size_t ws_size,
                              hipStream_t stream) {
  const float* score = (const float*)d_in[0];
  const float* hv    = (const float*)d_in[1];
  const float* rel   = (const float*)d_in[2];
  const float* qsrc  = (const float*)d_in[3];
  const float* qrel  = (const float*)d_in[4];
  const float* Wq    = (const float*)d_in[5];
  const float* Wk    = (const float*)d_in[6];
  const int* node_i  = (const int*)d_in[8];
  const int* node_j  = (const int*)d_in[9];

  const int N = in_sizes[0];            // 50000
  const int B = in_sizes[3] / 128;      // 64
  const int E = in_sizes[2] / 128;      // 131072

  float* ws = (float*)d_ws;
  float* M  = ws;
  float* Mt = M + 262144;
  float* Tj = Mt + 262144;              // [N][256] = J0|J1 packed
  float* I1 = Tj + (size_t)N * 256;
  float* wv = I1 + (size_t)N * 128;
  float* uv = wv + (size_t)B * 128;
  float* yv = uv + (size_t)B * 128;
  float* cb = yv + (size_t)B * 128;
  float* ec = cb + B;
  float* exb = ec + E;
  unsigned* segkey = (unsigned*)(exb + E);
  float* segsum = (float*)(segkey + N);
  unsigned short* Mh  = (unsigned short*)(segsum + N);
  unsigned short* Ml  = Mh + 262144;
  unsigned short* Mth = Ml + 262144;
  unsigned short* Mtl = Mth + 262144;
  float* out = (float*)d_out;

  k1_gemmM<<<dim3(8, 8), 256, 0, stream>>>(Wq, Wk, M, Mt, Mh, Ml, Mth, Mtl,
                                           out, segsum, segkey, N);
  k2m3_mfma<<<(N + 63) / 64, 256, 0, stream>>>(hv, Mh, Ml, Mth, Mtl, Tj, I1, N);
  k3_query<<<B, 256, 0, stream>>>(qsrc, qrel, M, Mt, wv, uv, yv, cb);
  k4m_mfma<<<E / 64, 256, 0, stream>>>(rel, Mth, Mtl, yv, cb, ec);
  k5_logits<<<E / 16, 256, 0, stream>>>(rel, hv, Tj, I1, wv, uv, ec,
                                        node_i, node_j, exb, segkey);
  k6_exp<<<(E + 255) / 256, 256, 0, stream>>>(exb, node_i, segkey, segsum, E);
  k7_topk<<<B, 256, 0, stream>>>(exb, node_i, node_j, segsum, score, out);
}

// Round 19
// 208.004 us; speedup vs baseline: 1.5513x; 1.0154x over previous
//
#include <hip/hip_runtime.h>
#include <cstddef>

// Problem constants (fixed by the reference)
#define EPQ_SHIFT 11       // EPQ = 2048
#define KSEL 256

typedef __attribute__((ext_vector_type(8))) short short8v;   // 8 bf16
typedef __attribute__((ext_vector_type(4))) float float4v;   // MFMA acc

__device__ __forceinline__ unsigned enc_f(float f) {
  unsigned u = __float_as_uint(f);
  return (u & 0x80000000u) ? ~u : (u | 0x80000000u);
}
__device__ __forceinline__ float dec_f(unsigned k) {
  unsigned u = (k & 0x80000000u) ? (k ^ 0x80000000u) : ~k;
  return __uint_as_float(u);
}
__device__ __forceinline__ unsigned short f2bf(float x) {  // RNE f32->bf16
  unsigned u = __float_as_uint(x);
  return (unsigned short)((u + 0x7FFFu + ((u >> 16) & 1u)) >> 16);
}

// ---------------- K1: init buffers + M = Wq^T Wk + Mt + bf16 splits -------
__global__ __launch_bounds__(256) void k1_gemmM(
    const float* __restrict__ Wq, const float* __restrict__ Wk,
    float* __restrict__ M, float* __restrict__ Mt,
    unsigned short* __restrict__ Mh, unsigned short* __restrict__ Ml,
    unsigned short* __restrict__ Mth, unsigned short* __restrict__ Mtl,
    float* __restrict__ outz, float* __restrict__ segsum,
    unsigned* __restrict__ segkey, int N) {
  int tid = threadIdx.x;
  {  // folded k0: zero out/segsum/segkey
    int bid = blockIdx.y * gridDim.x + blockIdx.x;
    for (int idx = bid * 256 + tid; idx < N; idx += 16384) {
      outz[idx] = 0.f;
      segsum[idx] = 0.f;
      segkey[idx] = 0u;
    }
  }
  __shared__ float as[16][64];
  __shared__ float bs[16][64];
  int tx = tid & 15, ty = tid >> 4;
  int c1b = blockIdx.y * 64, c2b = blockIdx.x * 64;
  float acc[4][4] = {};
  for (int k0 = 0; k0 < 512; k0 += 16) {
#pragma unroll
    for (int l = 0; l < 4; ++l) {
      int lin = tid + l * 256;
      int kk = lin >> 6, c = lin & 63;
      as[kk][c] = Wq[(k0 + kk) * 512 + c1b + c];
      bs[kk][c] = Wk[(k0 + kk) * 512 + c2b + c];
    }
    __syncthreads();
#pragma unroll
    for (int kk = 0; kk < 16; ++kk) {
      float a[4], b[4];
#pragma unroll
      for (int m = 0; m < 4; ++m) a[m] = as[kk][ty * 4 + m];
#pragma unroll
      for (int n = 0; n < 4; ++n) b[n] = bs[kk][tx * 4 + n];
#pragma unroll
      for (int m = 0; m < 4; ++m)
#pragma unroll
        for (int n = 0; n < 4; ++n) acc[m][n] += a[m] * b[n];
    }
    __syncthreads();
  }
#pragma unroll
  for (int m = 0; m < 4; ++m)
#pragma unroll
    for (int n = 0; n < 4; ++n) {
      int c1 = c1b + ty * 4 + m, c2 = c2b + tx * 4 + n;
      float v = acc[m][n];
      M[c1 * 512 + c2] = v;
      Mt[c2 * 512 + c1] = v;
      unsigned short h = f2bf(v);
      unsigned short lo = f2bf(v - __uint_as_float((unsigned)h << 16));
      Mh[c1 * 512 + c2] = h;
      Ml[c1 * 512 + c2] = lo;
      Mth[c2 * 512 + c1] = h;
      Mtl[c2 * 512 + c1] = lo;
    }
}

// ---------------- K2m3: ALL 3 projections, operand-swapped MFMA ----------
// A = M-table rows (d, 128), B = hv (64 nodes). D-frag: col=node(lane&15),
// row=d (kq*4+reg contiguous) -> accumulators store DIRECTLY as float4.
__global__ __launch_bounds__(256) void k2m3_mfma(
    const float* __restrict__ hv, const unsigned short* __restrict__ Mh,
    const unsigned short* __restrict__ Ml, const unsigned short* __restrict__ Mth,
    const unsigned short* __restrict__ Mtl, float* __restrict__ Tj,
    float* __restrict__ I1, int N) {
  __shared__ char pool[49152];
  unsigned short (*Hh4)[64][32] = (unsigned short(*)[64][32])pool;            // 16KB
  unsigned short (*Hl4)[64][32] = (unsigned short(*)[64][32])(pool + 16384);  // 16KB
  unsigned short (*Bh)[32] = (unsigned short(*)[32])(pool + 32768);           // 8KB
  unsigned short (*Bl)[32] = (unsigned short(*)[32])(pool + 40960);           // 8KB

  const int tid = threadIdx.x;
  const int lane = tid & 63;
  const int w = tid >> 6;
  const int wr2 = w >> 1, wc2 = w & 1;  // wr2: 64-d half, wc2: 32-node half
  const int n0 = blockIdx.x * 64;

  // ---- stage hv once: [64 nodes][128] -> bf16 hi/lo, 4 K-chunks ----
  {
    const int an = tid >> 2, aq = tid & 3;
    const int ag = aq ^ ((an >> 1) & 3);
    int gn = n0 + an;
    gn = gn < N ? gn : N - 1;
    const float* asrc = hv + (size_t)gn * 128 + aq * 8;
#pragma unroll
    for (int ch = 0; ch < 4; ++ch) {
      float4 v0 = *(const float4*)&asrc[ch * 32];
      float4 v1 = *(const float4*)&asrc[ch * 32 + 4];
      float vv[8] = {v0.x, v0.y, v0.z, v0.w, v1.x, v1.y, v1.z, v1.w};
      unsigned hw[4], lw[4];
#pragma unroll
      for (int j = 0; j < 4; ++j) {
        unsigned short h0 = f2bf(vv[2 * j]);
        unsigned short h1 = f2bf(vv[2 * j + 1]);
        unsigned short l0 = f2bf(vv[2 * j] - __uint_as_float((unsigned)h0 << 16));
        unsigned short l1 = f2bf(vv[2 * j + 1] - __uint_as_float((unsigned)h1 << 16));
        hw[j] = (unsigned)h0 | ((unsigned)h1 << 16);
        lw[j] = (unsigned)l0 | ((unsigned)l1 << 16);
      }
      *(uint4*)&Hh4[ch][an][ag * 8] = make_uint4(hw[0], hw[1], hw[2], hw[3]);
      *(uint4*)&Hl4[ch][an][ag * 8] = make_uint4(lw[0], lw[1], lw[2], lw[3]);
    }
  }

  const int bd = tid >> 1, bhalf = tid & 1;
  const int bsw = (bd >> 1) & 3;
  const int bg0 = (bhalf * 2) ^ bsw, bg1 = (bhalf * 2 + 1) ^ bsw;
  const size_t bcol = (size_t)bd * 512 + bhalf * 16;
  const unsigned short* bh0 = Mh + bcol;                       // p=0
  const unsigned short* bh1 = Mh + (size_t)128 * 512 + bcol;   // p=1
  const unsigned short* bh2 = Mth + (size_t)128 * 512 + bcol;  // p=2
  const unsigned short* bl0 = Ml + bcol;
  const unsigned short* bl1 = Ml + (size_t)128 * 512 + bcol;
  const unsigned short* bl2 = Mtl + (size_t)128 * 512 + bcol;

  uint4 rbh0 = *(const uint4*)&bh0[0];
  uint4 rbh1 = *(const uint4*)&bh0[8];
  uint4 rbl0 = *(const uint4*)&bl0[0];
  uint4 rbl1 = *(const uint4*)&bl0[8];

#pragma unroll
  for (int p = 0; p < 3; ++p) {
    float* outp = (p == 0) ? Tj : (p == 1) ? (Tj + 128) : I1;
    const size_t ostride = (p == 2) ? 128 : 256;
    float4v acc[4][2];  // [d-frag r][node-frag c]
#pragma unroll
    for (int r = 0; r < 4; ++r)
#pragma unroll
      for (int c = 0; c < 2; ++c) acc[r][c] = (float4v){0.f, 0.f, 0.f, 0.f};

#pragma unroll
    for (int ch = 0; ch < 4; ++ch) {
      __syncthreads();
      *(uint4*)&Bh[bd][bg0 * 8] = rbh0;
      *(uint4*)&Bh[bd][bg1 * 8] = rbh1;
      *(uint4*)&Bl[bd][bg0 * 8] = rbl0;
      *(uint4*)&Bl[bd][bg1 * 8] = rbl1;
      uint4 nh0, nh1, nl0, nl1;
      {
        const int s = p * 4 + ch + 1;
        if (s < 12) {
          const int np = s >> 2, nch = s & 3;
          const unsigned short* nbh = (np == 0) ? bh0 : (np == 1) ? bh1 : bh2;
          const unsigned short* nbl = (np == 0) ? bl0 : (np == 1) ? bl1 : bl2;
          nh0 = *(const uint4*)&nbh[nch * 32];
          nh1 = *(const uint4*)&nbh[nch * 32 + 8];
          nl0 = *(const uint4*)&nbl[nch * 32];
          nl1 = *(const uint4*)&nbl[nch * 32 + 8];
        }
      }
      __syncthreads();
      {
        int ln = lane & 15, kq = lane >> 4;
        short8v mhf[4], mlf[4];
#pragma unroll
        for (int r = 0; r < 4; ++r) {
          int row = wr2 * 64 + r * 16 + ln;  // d index
          int gg = kq ^ ((row >> 1) & 3);
          mhf[r] = *(const short8v*)&Bh[row][gg * 8];
          mlf[r] = *(const short8v*)&Bl[row][gg * 8];
        }
#pragma unroll
        for (int c = 0; c < 2; ++c) {
          int col = wc2 * 32 + c * 16 + ln;  // node index
          int gg = kq ^ ((col >> 1) & 3);
          short8v hh = *(const short8v*)&Hh4[ch][col][gg * 8];
          short8v hl = *(const short8v*)&Hl4[ch][col][gg * 8];
#pragma unroll
          for (int r = 0; r < 4; ++r) {
            acc[r][c] = __builtin_amdgcn_mfma_f32_16x16x32_bf16(mhf[r], hh,
                                                                acc[r][c], 0, 0, 0);
            acc[r][c] = __builtin_amdgcn_mfma_f32_16x16x32_bf16(mlf[r], hh,
                                                                acc[r][c], 0, 0, 0);
            acc[r][c] = __builtin_amdgcn_mfma_f32_16x16x32_bf16(mhf[r], hl,
                                                                acc[r][c], 0, 0, 0);
          }
        }
      }
      rbh0 = nh0; rbh1 = nh1; rbl0 = nl0; rbl1 = nl1;
    }

    // epilogue p: direct fragment stores (no barriers, no LDS)
    {
      int ln = lane & 15, kq = lane >> 4;
#pragma unroll
      for (int c = 0; c < 2; ++c) {
        int nl = wc2 * 32 + c * 16 + ln;
        int gn = n0 + nl;
        if (gn < N) {
#pragma unroll
          for (int r = 0; r < 4; ++r) {
            int d0 = wr2 * 64 + r * 16 + kq * 4;
            float4 o = {acc[r][c][0], acc[r][c][1], acc[r][c][2], acc[r][c][3]};
            *(float4*)&outp[(size_t)gn * ostride + d0] = o;
          }
        }
      }
    }
  }
}

// ---------------- K3: per-query vectors w,u,y,c_b (256 thr, c-split) ------
__global__ __launch_bounds__(256) void k3_query(const float* __restrict__ qsrc,
                                                const float* __restrict__ qrel,
                                                const float* __restrict__ M,
                                                const float* __restrict__ Mt,
                                                float* __restrict__ wv,
                                                float* __restrict__ uv,
                                                float* __restrict__ yv,
                                                float* __restrict__ cb) {
  __shared__ float qcat[256];
  __shared__ float prt[5][256];
  __shared__ float red[128];
  int b = blockIdx.x, tid = threadIdx.x;
  int d = tid & 127, hc = tid >> 7;
  qcat[tid] = (tid < 128) ? qsrc[b * 128 + tid] : qrel[b * 128 + (tid - 128)];
  __syncthreads();
  float w = 0.f, u = 0.f, y = 0.f, t1 = 0.f, t2 = 0.f;
  for (int c = hc * 128; c < hc * 128 + 128; ++c) {
    float q = qcat[c];
    size_t row = (size_t)(256 + c) * 512;
    w += Mt[row + d] * q;
    u += M[row + d] * q;
    y += (Mt[row + 128 + d] + M[row + 128 + d]) * q;
    t1 += M[row + 256 + d] * q;
    t2 += M[row + 384 + d] * q;
  }
  prt[0][tid] = w; prt[1][tid] = u; prt[2][tid] = y;
  prt[3][tid] = t1; prt[4][tid] = t2;
  __syncthreads();
  if (tid < 128) {
    float wc_ = prt[0][d] + prt[0][128 + d];
    float uc = prt[1][d] + prt[1][128 + d];
    float yc = prt[2][d] + prt[2][128 + d];
    float t1c = prt[3][d] + prt[3][128 + d];
    float t2c = prt[4][d] + prt[4][128 + d];
    wv[b * 128 + d] = wc_;
    uv[b * 128 + d] = uc;
    yv[b * 128 + d] = yc;
    red[d] = qcat[d] * t1c + qcat[128 + d] * t2c;
  }
  __syncthreads();
  for (int s = 64; s > 0; s >>= 1) {
    if (tid < s) red[tid] += red[tid + s];
    __syncthreads();
  }
  if (tid == 0) cb[b] = red[0];
}

// ---------------- K4m: edge_const, operand-swapped, direct reduce ---------
// A = Mt11 rows (d), B = rel (64 edges). D-frag: col=edge(lane&15),
// row=d (kq*4+reg contiguous). Epilogue: per-lane dot with rel/y in
// registers, shfl_xor(16/32) across kq, tiny red[2][64] cross-wave combine.
// 1 epilogue barrier (was 8), no ep LDS round-trip. Bit-identical ec.
__global__ __launch_bounds__(256) void k4m_mfma(
    const float* __restrict__ rel, const unsigned short* __restrict__ Mth,
    const unsigned short* __restrict__ Mtl, const float* __restrict__ yv,
    const float* __restrict__ cbp, float* __restrict__ ec) {
  __shared__ char pool[24576];
  unsigned short (*Rh)[32] = (unsigned short(*)[32])pool;            // rel hi [64][32]
  unsigned short (*Rl)[32] = (unsigned short(*)[32])(pool + 4096);   // rel lo
  unsigned short (*Qh)[32] = (unsigned short(*)[32])(pool + 8192);   // M  hi [128][32]
  unsigned short (*Ql)[32] = (unsigned short(*)[32])(pool + 16384);  // M  lo
  __shared__ float red[2][64];

  const int tid = threadIdx.x;
  const int lane = tid & 63;
  const int w = tid >> 6;
  const int wr2 = w >> 1, wc2 = w & 1;  // wr2: 64-d half, wc2: 32-edge half
  const int e0 = blockIdx.x * 64;
  const int b = e0 >> EPQ_SHIFT;

  float4v acc[4][2];  // [d-frag r][edge-frag c]
#pragma unroll
  for (int r = 0; r < 4; ++r)
#pragma unroll
    for (int c = 0; c < 2; ++c) acc[r][c] = (float4v){0.f, 0.f, 0.f, 0.f};

  const int an = tid >> 2, aq = tid & 3;
  const int ag = aq ^ ((an >> 1) & 3);
  const int bd = tid >> 1, bhalf = tid & 1;
  const int bsw = (bd >> 1) & 3;
  const int bg0 = (bhalf * 2) ^ bsw, bg1 = (bhalf * 2 + 1) ^ bsw;
  const float* asrc = rel + (size_t)(e0 + an) * 128 + aq * 8;
  const unsigned short* bhsrc = Mth + (size_t)(128 + bd) * 512 + 128 + bhalf * 16;
  const unsigned short* blsrc = Mtl + (size_t)(128 + bd) * 512 + 128 + bhalf * 16;

  float4 ra0 = *(const float4*)&asrc[0];
  float4 ra1 = *(const float4*)&asrc[4];
  uint4 rbh0 = *(const uint4*)&bhsrc[0];
  uint4 rbh1 = *(const uint4*)&bhsrc[8];
  uint4 rbl0 = *(const uint4*)&blsrc[0];
  uint4 rbl1 = *(const uint4*)&blsrc[8];

#pragma unroll
  for (int ch = 0; ch < 4; ++ch) {
    __syncthreads();
    {
      float vv[8] = {ra0.x, ra0.y, ra0.z, ra0.w, ra1.x, ra1.y, ra1.z, ra1.w};
      unsigned hw[4], lw[4];
#pragma unroll
      for (int j = 0; j < 4; ++j) {
        unsigned short h0 = f2bf(vv[2 * j]);
        unsigned short h1 = f2bf(vv[2 * j + 1]);
        unsigned short l0 = f2bf(vv[2 * j] - __uint_as_float((unsigned)h0 << 16));
        unsigned short l1 = f2bf(vv[2 * j + 1] - __uint_as_float((unsigned)h1 << 16));
        hw[j] = (unsigned)h0 | ((unsigned)h1 << 16);
        lw[j] = (unsigned)l0 | ((unsigned)l1 << 16);
      }
      *(uint4*)&Rh[an][ag * 8] = make_uint4(hw[0], hw[1], hw[2], hw[3]);
      *(uint4*)&Rl[an][ag * 8] = make_uint4(lw[0], lw[1], lw[2], lw[3]);
      *(uint4*)&Qh[bd][bg0 * 8] = rbh0;
      *(uint4*)&Qh[bd][bg1 * 8] = rbh1;
      *(uint4*)&Ql[bd][bg0 * 8] = rbl0;
      *(uint4*)&Ql[bd][bg1 * 8] = rbl1;
    }
    float4 na0, na1;
    uint4 nbh0, nbh1, nbl0, nbl1;
    if (ch < 3) {
      na0 = *(const float4*)&asrc[(ch + 1) * 32];
      na1 = *(const float4*)&asrc[(ch + 1) * 32 + 4];
      nbh0 = *(const uint4*)&bhsrc[(ch + 1) * 32];
      nbh1 = *(const uint4*)&bhsrc[(ch + 1) * 32 + 8];
      nbl0 = *(const uint4*)&blsrc[(ch + 1) * 32];
      nbl1 = *(const uint4*)&blsrc[(ch + 1) * 32 + 8];
    }
    __syncthreads();
    {
      int ln = lane & 15, kq = lane >> 4;
      short8v mhf[4], mlf[4];
#pragma unroll
      for (int r = 0; r < 4; ++r) {
        int row = wr2 * 64 + r * 16 + ln;  // d index
        int gg = kq ^ ((row >> 1) & 3);
        mhf[r] = *(const short8v*)&Qh[row][gg * 8];
        mlf[r] = *(const short8v*)&Ql[row][gg * 8];
      }
#pragma unroll
      for (int c = 0; c < 2; ++c) {
        int col = wc2 * 32 + c * 16 + ln;  // edge index
        int gg = kq ^ ((col >> 1) & 3);
        short8v rh = *(const short8v*)&Rh[col][gg * 8];
        short8v rl = *(const short8v*)&Rl[col][gg * 8];
#pragma unroll
        for (int r = 0; r < 4; ++r) {
          acc[r][c] = __builtin_amdgcn_mfma_f32_16x16x32_bf16(mhf[r], rh,
                                                              acc[r][c], 0, 0, 0);
          acc[r][c] = __builtin_amdgcn_mfma_f32_16x16x32_bf16(mlf[r], rh,
                                                              acc[r][c], 0, 0, 0);
          acc[r][c] = __builtin_amdgcn_mfma_f32_16x16x32_bf16(mhf[r], rl,
                                                              acc[r][c], 0, 0, 0);
        }
      }
    }
    ra0 = na0; ra1 = na1;
    rbh0 = nbh0; rbh1 = nbh1; rbl0 = nbl0; rbl1 = nbl1;
  }

  // epilogue: ec[e] = sum_d (q[e][d] + y_b[d]) * rel[e][d] + c_b
  {
    int ln = lane & 15, kq = lane >> 4;
    float4 y4[4];
#pragma unroll
    for (int r = 0; r < 4; ++r)
      y4[r] = *(const float4*)&yv[b * 128 + wr2 * 64 + r * 16 + kq * 4];
#pragma unroll
    for (int c = 0; c < 2; ++c) {
      int el = wc2 * 32 + c * 16 + ln;
      int e = e0 + el;
      float part = 0.f;
#pragma unroll
      for (int r = 0; r < 4; ++r) {
        int d0 = wr2 * 64 + r * 16 + kq * 4;
        float4 rr = *(const float4*)&rel[(size_t)e * 128 + d0];
        part += (acc[r][c][0] + y4[r].x) * rr.x +
                (acc[r][c][1] + y4[r].y) * rr.y +
                (acc[r][c][2] + y4[r].z) * rr.z +
                (acc[r][c][3] + y4[r].w) * rr.w;
      }
      part += __shfl_xor(part, 16, 64);
      part += __shfl_xor(part, 32, 64);
      if (kq == 0) red[wr2][el] = part;
    }
  }
  __syncthreads();
  if (tid < 64) ec[e0 + tid] = red[0][tid] + red[1][tid] + cbp[b];
}

// ---------------- K5: per-edge logits + segment max (16 edges/block) ------
__global__ __launch_bounds__(256) void k5_logits(const float* __restrict__ rel,
                                                 const float* __restrict__ hv,
                                                 const float* __restrict__ Tj,
                                                 const float* __restrict__ I1,
                                                 const float* __restrict__ wv,
                                                 const float* __restrict__ uv,
                                                 const float* __restrict__ ec,
                                                 const int* __restrict__ node_i,
                                                 const int* __restrict__ node_j,
                                                 float* __restrict__ logits,
                                                 unsigned* __restrict__ segkey) {
  __shared__ float wl[128];
  __shared__ float ul[128];
  int tid = threadIdx.x;
  int e0 = blockIdx.x * 16;
  int b = e0 >> EPQ_SHIFT;
  if (tid < 128) wl[tid] = wv[b * 128 + tid];
  else ul[tid - 128] = uv[b * 128 + (tid - 128)];
  __syncthreads();
  int lane = tid & 15, eg = tid >> 4;
  int e = e0 + eg;
  int i = node_i[e], j = node_j[e];
  int c0 = lane * 8;

  float rr[8], hi[8], hj[8], a0[8], a1[8], ii[8];
  *(float4*)&rr[0] = *(const float4*)&rel[(size_t)e * 128 + c0];
  *(float4*)&rr[4] = *(const float4*)&rel[(size_t)e * 128 + c0 + 4];
  *(float4*)&hi[0] = *(const float4*)&hv[(size_t)i * 128 + c0];
  *(float4*)&hi[4] = *(const float4*)&hv[(size_t)i * 128 + c0 + 4];
  *(float4*)&hj[0] = *(const float4*)&hv[(size_t)j * 128 + c0];
  *(float4*)&hj[4] = *(const float4*)&hv[(size_t)j * 128 + c0 + 4];
  *(float4*)&a0[0] = *(const float4*)&Tj[(size_t)j * 256 + c0];
  *(float4*)&a0[4] = *(const float4*)&Tj[(size_t)j * 256 + c0 + 4];
  *(float4*)&a1[0] = *(const float4*)&Tj[(size_t)j * 256 + 128 + c0];
  *(float4*)&a1[4] = *(const float4*)&Tj[(size_t)j * 256 + 128 + c0 + 4];
  *(float4*)&ii[0] = *(const float4*)&I1[(size_t)i * 128 + c0];
  *(float4*)&ii[4] = *(const float4*)&I1[(size_t)i * 128 + c0 + 4];

  float p = 0.f;
#pragma unroll
  for (int k = 0; k < 8; ++k) {
    p += hi[k] * a0[k];               // hvi . J0[j]
    p += rr[k] * (a1[k] + ii[k]);     // rel . (J1[j] + I1[i])
    p += hi[k] * wl[c0 + k];          // hvi . w_b
    p += hj[k] * ul[c0 + k];          // hvj . u_b
  }
#pragma unroll
  for (int m = 8; m >= 1; m >>= 1) p += __shfl_xor(p, m, 64);
  if (lane == 0) {
    float lg = p + ec[e];
    logits[e] = lg;
    atomicMax(&segkey[i], enc_f(lg));
  }
}

// ---------------- K6: ex = exp(logit - segmax), segment sum ----------------
__global__ void k6_exp(float* __restrict__ exb, const int* __restrict__ node_i,
                       const unsigned* __restrict__ segkey,
                       float* __restrict__ segsum, int E) {
  int e = blockIdx.x * 256 + threadIdx.x;
  if (e >= E) return;
  int i = node_i[e];
  float m = dec_f(segkey[i]);
  float ex = expf(exb[e] - m);
  exb[e] = ex;
  atomicAdd(&segsum[i], ex);
}

// ---------------- K7: top-256 radix select, shfl-scan version -------------
__global__ __launch_bounds__(256) void k7_topk(const float* __restrict__ exb,
                                               const int* __restrict__ node_i,
                                               const int* __restrict__ node_j,
                                               const float* __restrict__ segsum,
                                               const float* __restrict__ score,
                                               float* __restrict__ out) {
  __shared__ unsigned vals[2048];
  __shared__ unsigned hist[256];
  __shared__ unsigned wtot[4];
  __shared__ unsigned sel_info[2];
  int q = blockIdx.x, t = threadIdx.x;
  int lane = t & 63, w = t >> 6;
  size_t base = (size_t)q * 2048;
#pragma unroll
  for (int l = 0; l < 8; ++l) {
    int el = t * 8 + l;
    int i = node_i[base + el];
    float tgt = exb[base + el] / segsum[i] * score[i];  // attn * src_score >= 0
    vals[el] = __float_as_uint(tgt);
  }
  __syncthreads();
  unsigned prefix = 0, need = KSEL;
  for (int pass = 3; pass >= 0; --pass) {
    hist[t] = 0;
    __syncthreads();
    int sh = pass * 8;
#pragma unroll
    for (int l = 0; l < 8; ++l) {
      unsigned v = vals[t * 8 + l];
      bool match = (pass == 3) || ((v >> (sh + 8)) == (prefix >> (sh + 8)));
      if (match) atomicAdd(&hist[(v >> sh) & 255u], 1u);
    }
    __syncthreads();
    unsigned myh = hist[t];
    unsigned v = myh;
#pragma unroll
    for (int off = 1; off < 64; off <<= 1) {
      unsigned o = __shfl_down(v, off, 64);
      if (lane + off < 64) v += o;
    }
    if (lane == 0) wtot[w] = v;
    __syncthreads();
    unsigned sct = v;
    for (int ww = w + 1; ww < 4; ++ww) sct += wtot[ww];
    unsigned above = sct - myh;
    if (above < need && need <= sct) {
      sel_info[0] = (unsigned)t;
      sel_info[1] = need - above;
    }
    __syncthreads();
    prefix |= sel_info[0] << sh;
    need = sel_info[1];
    __syncthreads();
  }
  unsigned T = prefix, r = need;
  unsigned lc = 0;
#pragma unroll
  for (int l = 0; l < 8; ++l)
    if (vals[t * 8 + l] == T) lc++;
  unsigned v = lc;
#pragma unroll
  for (int off = 1; off < 64; off <<= 1) {
    unsigned o = __shfl_up(v, off, 64);
    if (lane >= off) v += o;
  }
  if (lane == 63) wtot[w] = v;
  __syncthreads();
  unsigned pre = 0;
  for (int ww = 0; ww < w; ++ww) pre += wtot[ww];
  unsigned excl = v + pre - lc;
  unsigned cnt = 0;
#pragma unroll
  for (int l = 0; l < 8; ++l) {
    int el = t * 8 + l;
    unsigned vv = vals[el];
    bool take = false;
    if (vv > T) take = true;
    else if (vv == T) { if (excl + cnt < r) take = true; cnt++; }
    if (take) {
      int j = node_j[base + el];
      atomicAdd(&out[j], __uint_as_float(vv));
    }
  }
}

// ---------------- host ----------------
extern "C" void kernel_launch(void* const* d_in, const int* in_sizes, int n_in,
                              void* d_out, int out_size, void* d_ws, size_t ws_size,
                              hipStream_t stream) {
  const float* score = (const float*)d_in[0];
  const float* hv    = (const float*)d_in[1];
  const float* rel   = (const float*)d_in[2];
  const float* qsrc  = (const float*)d_in[3];
  const float* qrel  = (const float*)d_in[4];
  const float* Wq    = (const float*)d_in[5];
  const float* Wk    = (const float*)d_in[6];
  const int* node_i  = (const int*)d_in[8];
  const int* node_j  = (const int*)d_in[9];

  const int N = in_sizes[0];            // 50000
  const int B = in_sizes[3] / 128;      // 64
  const int E = in_sizes[2] / 128;      // 131072

  float* ws = (float*)d_ws;
  float* M  = ws;
  float* Mt = M + 262144;
  float* Tj = Mt + 262144;              // [N][256] = J0|J1 packed
  float* I1 = Tj + (size_t)N * 256;
  float* wv = I1 + (size_t)N * 128;
  float* uv = wv + (size_t)B * 128;
  float* yv = uv + (size_t)B * 128;
  float* cb = yv + (size_t)B * 128;
  float* ec = cb + B;
  float* exb = ec + E;
  unsigned* segkey = (unsigned*)(exb + E);
  float* segsum = (float*)(segkey + N);
  unsigned short* Mh  = (unsigned short*)(segsum + N);
  unsigned short* Ml  = Mh + 262144;
  unsigned short* Mth = Ml + 262144;
  unsigned short* Mtl = Mth + 262144;
  float* out = (float*)d_out;

  k1_gemmM<<<dim3(8, 8), 256, 0, stream>>>(Wq, Wk, M, Mt, Mh, Ml, Mth, Mtl,
                                           out, segsum, segkey, N);
  k2m3_mfma<<<(N + 63) / 64, 256, 0, stream>>>(hv, Mh, Ml, Mth, Mtl, Tj, I1, N);
  k3_query<<<B, 256, 0, stream>>>(qsrc, qrel, M, Mt, wv, uv, yv, cb);
  k4m_mfma<<<E / 64, 256, 0, stream>>>(rel, Mth, Mtl, yv, cb, ec);
  k5_logits<<<E / 16, 256, 0, stream>>>(rel, hv, Tj, I1, wv, uv, ec,
                                        node_i, node_j, exb, segkey);
  k6_exp<<<(E + 255) / 256, 256, 0, stream>>>(exb, node_i, segkey, segsum, E);
  k7_topk<<<B, 256, 0, stream>>>(exb, node_i, node_j, segsum, score, out);
}

// Round 20
// 197.147 us; speedup vs baseline: 1.6367x; 1.0551x over previous
//
#include <hip/hip_runtime.h>
#include <cstddef>

// Problem constants (fixed by the reference)
#define EPQ_SHIFT 11       // EPQ = 2048
#define KSEL 256

typedef __attribute__((ext_vector_type(8))) short short8v;   // 8 bf16
typedef __attribute__((ext_vector_type(4))) float float4v;   // MFMA acc

__device__ __forceinline__ unsigned enc_f(float f) {
  unsigned u = __float_as_uint(f);
  return (u & 0x80000000u) ? ~u : (u | 0x80000000u);
}
__device__ __forceinline__ float dec_f(unsigned k) {
  unsigned u = (k & 0x80000000u) ? (k ^ 0x80000000u) : ~k;
  return __uint_as_float(u);
}
__device__ __forceinline__ unsigned short f2bf(float x) {  // RNE f32->bf16
  unsigned u = __float_as_uint(x);
  return (unsigned short)((u + 0x7FFFu + ((u >> 16) & 1u)) >> 16);
}

// ---------------- K1: init buffers + M = Wq^T Wk + Mt + bf16 splits -------
// 32x32 tiles -> 256 blocks (one per CU). Same per-element k-order as the
// 64x64 version -> bit-identical M/Mt/Mh/Ml/Mth/Mtl.
__global__ __launch_bounds__(256) void k1_gemmM(
    const float* __restrict__ Wq, const float* __restrict__ Wk,
    float* __restrict__ M, float* __restrict__ Mt,
    unsigned short* __restrict__ Mh, unsigned short* __restrict__ Ml,
    unsigned short* __restrict__ Mth, unsigned short* __restrict__ Mtl,
    float* __restrict__ outz, float* __restrict__ segsum,
    unsigned* __restrict__ segkey, int N) {
  int tid = threadIdx.x;
  {  // folded k0: zero out/segsum/segkey (grid-stride over 256x256 threads)
    int bid = blockIdx.y * gridDim.x + blockIdx.x;
    for (int idx = bid * 256 + tid; idx < N; idx += 65536) {
      outz[idx] = 0.f;
      segsum[idx] = 0.f;
      segkey[idx] = 0u;
    }
  }
  __shared__ float as[16][32];
  __shared__ float bs[16][32];
  int tx = tid & 15, ty = tid >> 4;
  int c1b = blockIdx.y * 32, c2b = blockIdx.x * 32;
  float acc[2][2] = {};
  for (int k0 = 0; k0 < 512; k0 += 16) {
    {
      int kk = tid >> 4, c = (tid & 15) * 2;
      *(float2*)&as[kk][c] = *(const float2*)&Wq[(k0 + kk) * 512 + c1b + c];
      *(float2*)&bs[kk][c] = *(const float2*)&Wk[(k0 + kk) * 512 + c2b + c];
    }
    __syncthreads();
#pragma unroll
    for (int kk = 0; kk < 16; ++kk) {
      float a[2], b[2];
#pragma unroll
      for (int m = 0; m < 2; ++m) a[m] = as[kk][ty * 2 + m];
#pragma unroll
      for (int n = 0; n < 2; ++n) b[n] = bs[kk][tx * 2 + n];
#pragma unroll
      for (int m = 0; m < 2; ++m)
#pragma unroll
        for (int n = 0; n < 2; ++n) acc[m][n] += a[m] * b[n];
    }
    __syncthreads();
  }
#pragma unroll
  for (int m = 0; m < 2; ++m)
#pragma unroll
    for (int n = 0; n < 2; ++n) {
      int c1 = c1b + ty * 2 + m, c2 = c2b + tx * 2 + n;
      float v = acc[m][n];
      M[c1 * 512 + c2] = v;
      Mt[c2 * 512 + c1] = v;
      unsigned short h = f2bf(v);
      unsigned short lo = f2bf(v - __uint_as_float((unsigned)h << 16));
      Mh[c1 * 512 + c2] = h;
      Ml[c1 * 512 + c2] = lo;
      Mth[c2 * 512 + c1] = h;
      Mtl[c2 * 512 + c1] = lo;
    }
}

// ---------------- K2m3: ALL 3 projections, operand-swapped MFMA ----------
// A = M-table rows (d, 128), B = hv (64 nodes). D-frag: col=node(lane&15),
// row=d (kq*4+reg contiguous) -> accumulators store DIRECTLY as float4.
__global__ __launch_bounds__(256) void k2m3_mfma(
    const float* __restrict__ hv, const unsigned short* __restrict__ Mh,
    const unsigned short* __restrict__ Ml, const unsigned short* __restrict__ Mth,
    const unsigned short* __restrict__ Mtl, float* __restrict__ Tj,
    float* __restrict__ I1, int N) {
  __shared__ char pool[49152];
  unsigned short (*Hh4)[64][32] = (unsigned short(*)[64][32])pool;            // 16KB
  unsigned short (*Hl4)[64][32] = (unsigned short(*)[64][32])(pool + 16384);  // 16KB
  unsigned short (*Bh)[32] = (unsigned short(*)[32])(pool + 32768);           // 8KB
  unsigned short (*Bl)[32] = (unsigned short(*)[32])(pool + 40960);           // 8KB

  const int tid = threadIdx.x;
  const int lane = tid & 63;
  const int w = tid >> 6;
  const int wr2 = w >> 1, wc2 = w & 1;  // wr2: 64-d half, wc2: 32-node half
  const int n0 = blockIdx.x * 64;

  // ---- stage hv once: [64 nodes][128] -> bf16 hi/lo, 4 K-chunks ----
  {
    const int an = tid >> 2, aq = tid & 3;
    const int ag = aq ^ ((an >> 1) & 3);
    int gn = n0 + an;
    gn = gn < N ? gn : N - 1;
    const float* asrc = hv + (size_t)gn * 128 + aq * 8;
#pragma unroll
    for (int ch = 0; ch < 4; ++ch) {
      float4 v0 = *(const float4*)&asrc[ch * 32];
      float4 v1 = *(const float4*)&asrc[ch * 32 + 4];
      float vv[8] = {v0.x, v0.y, v0.z, v0.w, v1.x, v1.y, v1.z, v1.w};
      unsigned hw[4], lw[4];
#pragma unroll
      for (int j = 0; j < 4; ++j) {
        unsigned short h0 = f2bf(vv[2 * j]);
        unsigned short h1 = f2bf(vv[2 * j + 1]);
        unsigned short l0 = f2bf(vv[2 * j] - __uint_as_float((unsigned)h0 << 16));
        unsigned short l1 = f2bf(vv[2 * j + 1] - __uint_as_float((unsigned)h1 << 16));
        hw[j] = (unsigned)h0 | ((unsigned)h1 << 16);
        lw[j] = (unsigned)l0 | ((unsigned)l1 << 16);
      }
      *(uint4*)&Hh4[ch][an][ag * 8] = make_uint4(hw[0], hw[1], hw[2], hw[3]);
      *(uint4*)&Hl4[ch][an][ag * 8] = make_uint4(lw[0], lw[1], lw[2], lw[3]);
    }
  }

  const int bd = tid >> 1, bhalf = tid & 1;
  const int bsw = (bd >> 1) & 3;
  const int bg0 = (bhalf * 2) ^ bsw, bg1 = (bhalf * 2 + 1) ^ bsw;
  const size_t bcol = (size_t)bd * 512 + bhalf * 16;
  const unsigned short* bh0 = Mh + bcol;                       // p=0
  const unsigned short* bh1 = Mh + (size_t)128 * 512 + bcol;   // p=1
  const unsigned short* bh2 = Mth + (size_t)128 * 512 + bcol;  // p=2
  const unsigned short* bl0 = Ml + bcol;
  const unsigned short* bl1 = Ml + (size_t)128 * 512 + bcol;
  const unsigned short* bl2 = Mtl + (size_t)128 * 512 + bcol;

  uint4 rbh0 = *(const uint4*)&bh0[0];
  uint4 rbh1 = *(const uint4*)&bh0[8];
  uint4 rbl0 = *(const uint4*)&bl0[0];
  uint4 rbl1 = *(const uint4*)&bl0[8];

#pragma unroll
  for (int p = 0; p < 3; ++p) {
    float* outp = (p == 0) ? Tj : (p == 1) ? (Tj + 128) : I1;
    const size_t ostride = (p == 2) ? 128 : 256;
    float4v acc[4][2];  // [d-frag r][node-frag c]
#pragma unroll
    for (int r = 0; r < 4; ++r)
#pragma unroll
      for (int c = 0; c < 2; ++c) acc[r][c] = (float4v){0.f, 0.f, 0.f, 0.f};

#pragma unroll
    for (int ch = 0; ch < 4; ++ch) {
      __syncthreads();
      *(uint4*)&Bh[bd][bg0 * 8] = rbh0;
      *(uint4*)&Bh[bd][bg1 * 8] = rbh1;
      *(uint4*)&Bl[bd][bg0 * 8] = rbl0;
      *(uint4*)&Bl[bd][bg1 * 8] = rbl1;
      uint4 nh0, nh1, nl0, nl1;
      {
        const int s = p * 4 + ch + 1;
        if (s < 12) {
          const int np = s >> 2, nch = s & 3;
          const unsigned short* nbh = (np == 0) ? bh0 : (np == 1) ? bh1 : bh2;
          const unsigned short* nbl = (np == 0) ? bl0 : (np == 1) ? bl1 : bl2;
          nh0 = *(const uint4*)&nbh[nch * 32];
          nh1 = *(const uint4*)&nbh[nch * 32 + 8];
          nl0 = *(const uint4*)&nbl[nch * 32];
          nl1 = *(const uint4*)&nbl[nch * 32 + 8];
        }
      }
      __syncthreads();
      {
        int ln = lane & 15, kq = lane >> 4;
        short8v mhf[4], mlf[4];
#pragma unroll
        for (int r = 0; r < 4; ++r) {
          int row = wr2 * 64 + r * 16 + ln;  // d index
          int gg = kq ^ ((row >> 1) & 3);
          mhf[r] = *(const short8v*)&Bh[row][gg * 8];
          mlf[r] = *(const short8v*)&Bl[row][gg * 8];
        }
#pragma unroll
        for (int c = 0; c < 2; ++c) {
          int col = wc2 * 32 + c * 16 + ln;  // node index
          int gg = kq ^ ((col >> 1) & 3);
          short8v hh = *(const short8v*)&Hh4[ch][col][gg * 8];
          short8v hl = *(const short8v*)&Hl4[ch][col][gg * 8];
#pragma unroll
          for (int r = 0; r < 4; ++r) {
            acc[r][c] = __builtin_amdgcn_mfma_f32_16x16x32_bf16(mhf[r], hh,
                                                                acc[r][c], 0, 0, 0);
            acc[r][c] = __builtin_amdgcn_mfma_f32_16x16x32_bf16(mlf[r], hh,
                                                                acc[r][c], 0, 0, 0);
            acc[r][c] = __builtin_amdgcn_mfma_f32_16x16x32_bf16(mhf[r], hl,
                                                                acc[r][c], 0, 0, 0);
          }
        }
      }
      rbh0 = nh0; rbh1 = nh1; rbl0 = nl0; rbl1 = nl1;
    }

    // epilogue p: direct fragment stores (no barriers, no LDS)
    {
      int ln = lane & 15, kq = lane >> 4;
#pragma unroll
      for (int c = 0; c < 2; ++c) {
        int nl = wc2 * 32 + c * 16 + ln;
        int gn = n0 + nl;
        if (gn < N) {
#pragma unroll
          for (int r = 0; r < 4; ++r) {
            int d0 = wr2 * 64 + r * 16 + kq * 4;
            float4 o = {acc[r][c][0], acc[r][c][1], acc[r][c][2], acc[r][c][3]};
            *(float4*)&outp[(size_t)gn * ostride + d0] = o;
          }
        }
      }
    }
  }
}

// ---------------- K3: per-query vectors w,u,y,c_b (256 thr, c-split) ------
__global__ __launch_bounds__(256) void k3_query(const float* __restrict__ qsrc,
                                                const float* __restrict__ qrel,
                                                const float* __restrict__ M,
                                                const float* __restrict__ Mt,
                                                float* __restrict__ wv,
                                                float* __restrict__ uv,
                                                float* __restrict__ yv,
                                                float* __restrict__ cb) {
  __shared__ float qcat[256];
  __shared__ float prt[5][256];
  __shared__ float red[128];
  int b = blockIdx.x, tid = threadIdx.x;
  int d = tid & 127, hc = tid >> 7;
  qcat[tid] = (tid < 128) ? qsrc[b * 128 + tid] : qrel[b * 128 + (tid - 128)];
  __syncthreads();
  float w = 0.f, u = 0.f, y = 0.f, t1 = 0.f, t2 = 0.f;
  for (int c = hc * 128; c < hc * 128 + 128; ++c) {
    float q = qcat[c];
    size_t row = (size_t)(256 + c) * 512;
    w += Mt[row + d] * q;
    u += M[row + d] * q;
    y += (Mt[row + 128 + d] + M[row + 128 + d]) * q;
    t1 += M[row + 256 + d] * q;
    t2 += M[row + 384 + d] * q;
  }
  prt[0][tid] = w; prt[1][tid] = u; prt[2][tid] = y;
  prt[3][tid] = t1; prt[4][tid] = t2;
  __syncthreads();
  if (tid < 128) {
    float wc_ = prt[0][d] + prt[0][128 + d];
    float uc = prt[1][d] + prt[1][128 + d];
    float yc = prt[2][d] + prt[2][128 + d];
    float t1c = prt[3][d] + prt[3][128 + d];
    float t2c = prt[4][d] + prt[4][128 + d];
    wv[b * 128 + d] = wc_;
    uv[b * 128 + d] = uc;
    yv[b * 128 + d] = yc;
    red[d] = qcat[d] * t1c + qcat[128 + d] * t2c;
  }
  __syncthreads();
  for (int s = 64; s > 0; s >>= 1) {
    if (tid < s) red[tid] += red[tid + s];
    __syncthreads();
  }
  if (tid == 0) cb[b] = red[0];
}

// ---------------- K4m: edge_const, operand-swapped, direct reduce ---------
__global__ __launch_bounds__(256) void k4m_mfma(
    const float* __restrict__ rel, const unsigned short* __restrict__ Mth,
    const unsigned short* __restrict__ Mtl, const float* __restrict__ yv,
    const float* __restrict__ cbp, float* __restrict__ ec) {
  __shared__ char pool[24576];
  unsigned short (*Rh)[32] = (unsigned short(*)[32])pool;            // rel hi [64][32]
  unsigned short (*Rl)[32] = (unsigned short(*)[32])(pool + 4096);   // rel lo
  unsigned short (*Qh)[32] = (unsigned short(*)[32])(pool + 8192);   // M  hi [128][32]
  unsigned short (*Ql)[32] = (unsigned short(*)[32])(pool + 16384);  // M  lo
  __shared__ float red[2][64];

  const int tid = threadIdx.x;
  const int lane = tid & 63;
  const int w = tid >> 6;
  const int wr2 = w >> 1, wc2 = w & 1;  // wr2: 64-d half, wc2: 32-edge half
  const int e0 = blockIdx.x * 64;
  const int b = e0 >> EPQ_SHIFT;

  float4v acc[4][2];  // [d-frag r][edge-frag c]
#pragma unroll
  for (int r = 0; r < 4; ++r)
#pragma unroll
    for (int c = 0; c < 2; ++c) acc[r][c] = (float4v){0.f, 0.f, 0.f, 0.f};

  const int an = tid >> 2, aq = tid & 3;
  const int ag = aq ^ ((an >> 1) & 3);
  const int bd = tid >> 1, bhalf = tid & 1;
  const int bsw = (bd >> 1) & 3;
  const int bg0 = (bhalf * 2) ^ bsw, bg1 = (bhalf * 2 + 1) ^ bsw;
  const float* asrc = rel + (size_t)(e0 + an) * 128 + aq * 8;
  const unsigned short* bhsrc = Mth + (size_t)(128 + bd) * 512 + 128 + bhalf * 16;
  const unsigned short* blsrc = Mtl + (size_t)(128 + bd) * 512 + 128 + bhalf * 16;

  float4 ra0 = *(const float4*)&asrc[0];
  float4 ra1 = *(const float4*)&asrc[4];
  uint4 rbh0 = *(const uint4*)&bhsrc[0];
  uint4 rbh1 = *(const uint4*)&bhsrc[8];
  uint4 rbl0 = *(const uint4*)&blsrc[0];
  uint4 rbl1 = *(const uint4*)&blsrc[8];

#pragma unroll
  for (int ch = 0; ch < 4; ++ch) {
    __syncthreads();
    {
      float vv[8] = {ra0.x, ra0.y, ra0.z, ra0.w, ra1.x, ra1.y, ra1.z, ra1.w};
      unsigned hw[4], lw[4];
#pragma unroll
      for (int j = 0; j < 4; ++j) {
        unsigned short h0 = f2bf(vv[2 * j]);
        unsigned short h1 = f2bf(vv[2 * j + 1]);
        unsigned short l0 = f2bf(vv[2 * j] - __uint_as_float((unsigned)h0 << 16));
        unsigned short l1 = f2bf(vv[2 * j + 1] - __uint_as_float((unsigned)h1 << 16));
        hw[j] = (unsigned)h0 | ((unsigned)h1 << 16);
        lw[j] = (unsigned)l0 | ((unsigned)l1 << 16);
      }
      *(uint4*)&Rh[an][ag * 8] = make_uint4(hw[0], hw[1], hw[2], hw[3]);
      *(uint4*)&Rl[an][ag * 8] = make_uint4(lw[0], lw[1], lw[2], lw[3]);
      *(uint4*)&Qh[bd][bg0 * 8] = rbh0;
      *(uint4*)&Qh[bd][bg1 * 8] = rbh1;
      *(uint4*)&Ql[bd][bg0 * 8] = rbl0;
      *(uint4*)&Ql[bd][bg1 * 8] = rbl1;
    }
    float4 na0, na1;
    uint4 nbh0, nbh1, nbl0, nbl1;
    if (ch < 3) {
      na0 = *(const float4*)&asrc[(ch + 1) * 32];
      na1 = *(const float4*)&asrc[(ch + 1) * 32 + 4];
      nbh0 = *(const uint4*)&bhsrc[(ch + 1) * 32];
      nbh1 = *(const uint4*)&bhsrc[(ch + 1) * 32 + 8];
      nbl0 = *(const uint4*)&blsrc[(ch + 1) * 32];
      nbl1 = *(const uint4*)&blsrc[(ch + 1) * 32 + 8];
    }
    __syncthreads();
    {
      int ln = lane & 15, kq = lane >> 4;
      short8v mhf[4], mlf[4];
#pragma unroll
      for (int r = 0; r < 4; ++r) {
        int row = wr2 * 64 + r * 16 + ln;  // d index
        int gg = kq ^ ((row >> 1) & 3);
        mhf[r] = *(const short8v*)&Qh[row][gg * 8];
        mlf[r] = *(const short8v*)&Ql[row][gg * 8];
      }
#pragma unroll
      for (int c = 0; c < 2; ++c) {
        int col = wc2 * 32 + c * 16 + ln;  // edge index
        int gg = kq ^ ((col >> 1) & 3);
        short8v rh = *(const short8v*)&Rh[col][gg * 8];
        short8v rl = *(const short8v*)&Rl[col][gg * 8];
#pragma unroll
        for (int r = 0; r < 4; ++r) {
          acc[r][c] = __builtin_amdgcn_mfma_f32_16x16x32_bf16(mhf[r], rh,
                                                              acc[r][c], 0, 0, 0);
          acc[r][c] = __builtin_amdgcn_mfma_f32_16x16x32_bf16(mlf[r], rh,
                                                              acc[r][c], 0, 0, 0);
          acc[r][c] = __builtin_amdgcn_mfma_f32_16x16x32_bf16(mhf[r], rl,
                                                              acc[r][c], 0, 0, 0);
        }
      }
    }
    ra0 = na0; ra1 = na1;
    rbh0 = nbh0; rbh1 = nbh1; rbl0 = nbl0; rbl1 = nbl1;
  }

  // epilogue: ec[e] = sum_d (q[e][d] + y_b[d]) * rel[e][d] + c_b
  {
    int ln = lane & 15, kq = lane >> 4;
    float4 y4[4];
#pragma unroll
    for (int r = 0; r < 4; ++r)
      y4[r] = *(const float4*)&yv[b * 128 + wr2 * 64 + r * 16 + kq * 4];
#pragma unroll
    for (int c = 0; c < 2; ++c) {
      int el = wc2 * 32 + c * 16 + ln;
      int e = e0 + el;
      float part = 0.f;
#pragma unroll
      for (int r = 0; r < 4; ++r) {
        int d0 = wr2 * 64 + r * 16 + kq * 4;
        float4 rr = *(const float4*)&rel[(size_t)e * 128 + d0];
        part += (acc[r][c][0] + y4[r].x) * rr.x +
                (acc[r][c][1] + y4[r].y) * rr.y +
                (acc[r][c][2] + y4[r].z) * rr.z +
                (acc[r][c][3] + y4[r].w) * rr.w;
      }
      part += __shfl_xor(part, 16, 64);
      part += __shfl_xor(part, 32, 64);
      if (kq == 0) red[wr2][el] = part;
    }
  }
  __syncthreads();
  if (tid < 64) ec[e0 + tid] = red[0][tid] + red[1][tid] + cbp[b];
}

// ---------------- K5: per-edge logits + segment max (16 edges/block) ------
__global__ __launch_bounds__(256) void k5_logits(const float* __restrict__ rel,
                                                 const float* __restrict__ hv,
                                                 const float* __restrict__ Tj,
                                                 const float* __restrict__ I1,
                                                 const float* __restrict__ wv,
                                                 const float* __restrict__ uv,
                                                 const float* __restrict__ ec,
                                                 const int* __restrict__ node_i,
                                                 const int* __restrict__ node_j,
                                                 float* __restrict__ logits,
                                                 unsigned* __restrict__ segkey) {
  __shared__ float wl[128];
  __shared__ float ul[128];
  int tid = threadIdx.x;
  int e0 = blockIdx.x * 16;
  int b = e0 >> EPQ_SHIFT;
  if (tid < 128) wl[tid] = wv[b * 128 + tid];
  else ul[tid - 128] = uv[b * 128 + (tid - 128)];
  __syncthreads();
  int lane = tid & 15, eg = tid >> 4;
  int e = e0 + eg;
  int i = node_i[e], j = node_j[e];
  int c0 = lane * 8;

  float rr[8], hi[8], hj[8], a0[8], a1[8], ii[8];
  *(float4*)&rr[0] = *(const float4*)&rel[(size_t)e * 128 + c0];
  *(float4*)&rr[4] = *(const float4*)&rel[(size_t)e * 128 + c0 + 4];
  *(float4*)&hi[0] = *(const float4*)&hv[(size_t)i * 128 + c0];
  *(float4*)&hi[4] = *(const float4*)&hv[(size_t)i * 128 + c0 + 4];
  *(float4*)&hj[0] = *(const float4*)&hv[(size_t)j * 128 + c0];
  *(float4*)&hj[4] = *(const float4*)&hv[(size_t)j * 128 + c0 + 4];
  *(float4*)&a0[0] = *(const float4*)&Tj[(size_t)j * 256 + c0];
  *(float4*)&a0[4] = *(const float4*)&Tj[(size_t)j * 256 + c0 + 4];
  *(float4*)&a1[0] = *(const float4*)&Tj[(size_t)j * 256 + 128 + c0];
  *(float4*)&a1[4] = *(const float4*)&Tj[(size_t)j * 256 + 128 + c0 + 4];
  *(float4*)&ii[0] = *(const float4*)&I1[(size_t)i * 128 + c0];
  *(float4*)&ii[4] = *(const float4*)&I1[(size_t)i * 128 + c0 + 4];

  float p = 0.f;
#pragma unroll
  for (int k = 0; k < 8; ++k) {
    p += hi[k] * a0[k];               // hvi . J0[j]
    p += rr[k] * (a1[k] + ii[k]);     // rel . (J1[j] + I1[i])
    p += hi[k] * wl[c0 + k];          // hvi . w_b
    p += hj[k] * ul[c0 + k];          // hvj . u_b
  }
#pragma unroll
  for (int m = 8; m >= 1; m >>= 1) p += __shfl_xor(p, m, 64);
  if (lane == 0) {
    float lg = p + ec[e];
    logits[e] = lg;
    atomicMax(&segkey[i], enc_f(lg));
  }
}

// ---------------- K6: ex = exp(logit - segmax), segment sum ----------------
__global__ void k6_exp(float* __restrict__ exb, const int* __restrict__ node_i,
                       const unsigned* __restrict__ segkey,
                       float* __restrict__ segsum, int E) {
  int e = blockIdx.x * 256 + threadIdx.x;
  if (e >= E) return;
  int i = node_i[e];
  float m = dec_f(segkey[i]);
  float ex = expf(exb[e] - m);
  exb[e] = ex;
  atomicAdd(&segsum[i], ex);
}

// ---------------- K7: top-256 radix select, shfl-scan version -------------
__global__ __launch_bounds__(256) void k7_topk(const float* __restrict__ exb,
                                               const int* __restrict__ node_i,
                                               const int* __restrict__ node_j,
                                               const float* __restrict__ segsum,
                                               const float* __restrict__ score,
                                               float* __restrict__ out) {
  __shared__ unsigned vals[2048];
  __shared__ unsigned hist[256];
  __shared__ unsigned wtot[4];
  __shared__ unsigned sel_info[2];
  int q = blockIdx.x, t = threadIdx.x;
  int lane = t & 63, w = t >> 6;
  size_t base = (size_t)q * 2048;
#pragma unroll
  for (int l = 0; l < 8; ++l) {
    int el = t * 8 + l;
    int i = node_i[base + el];
    float tgt = exb[base + el] / segsum[i] * score[i];  // attn * src_score >= 0
    vals[el] = __float_as_uint(tgt);
  }
  __syncthreads();
  unsigned prefix = 0, need = KSEL;
  for (int pass = 3; pass >= 0; --pass) {
    hist[t] = 0;
    __syncthreads();
    int sh = pass * 8;
#pragma unroll
    for (int l = 0; l < 8; ++l) {
      unsigned v = vals[t * 8 + l];
      bool match = (pass == 3) || ((v >> (sh + 8)) == (prefix >> (sh + 8)));
      if (match) atomicAdd(&hist[(v >> sh) & 255u], 1u);
    }
    __syncthreads();
    unsigned myh = hist[t];
    unsigned v = myh;
#pragma unroll
    for (int off = 1; off < 64; off <<= 1) {
      unsigned o = __shfl_down(v, off, 64);
      if (lane + off < 64) v += o;
    }
    if (lane == 0) wtot[w] = v;
    __syncthreads();
    unsigned sct = v;
    for (int ww = w + 1; ww < 4; ++ww) sct += wtot[ww];
    unsigned above = sct - myh;
    if (above < need && need <= sct) {
      sel_info[0] = (unsigned)t;
      sel_info[1] = need - above;
    }
    __syncthreads();
    prefix |= sel_info[0] << sh;
    need = sel_info[1];
    __syncthreads();
  }
  unsigned T = prefix, r = need;
  unsigned lc = 0;
#pragma unroll
  for (int l = 0; l < 8; ++l)
    if (vals[t * 8 + l] == T) lc++;
  unsigned v = lc;
#pragma unroll
  for (int off = 1; off < 64; off <<= 1) {
    unsigned o = __shfl_up(v, off, 64);
    if (lane >= off) v += o;
  }
  if (lane == 63) wtot[w] = v;
  __syncthreads();
  unsigned pre = 0;
  for (int ww = 0; ww < w; ++ww) pre += wtot[ww];
  unsigned excl = v + pre - lc;
  unsigned cnt = 0;
#pragma unroll
  for (int l = 0; l < 8; ++l) {
    int el = t * 8 + l;
    unsigned vv = vals[el];
    bool take = false;
    if (vv > T) take = true;
    else if (vv == T) { if (excl + cnt < r) take = true; cnt++; }
    if (take) {
      int j = node_j[base + el];
      atomicAdd(&out[j], __uint_as_float(vv));
    }
  }
}

// ---------------- host ----------------
extern "C" void kernel_launch(void* const* d_in, const int* in_sizes, int n_in,
                              void* d_out, int out_size, void* d_ws, size_t ws_size,
                              hipStream_t stream) {
  const float* score = (const float*)d_in[0];
  const float* hv    = (const float*)d_in[1];
  const float* rel   = (const float*)d_in[2];
  const float* qsrc  = (const float*)d_in[3];
  const float* qrel  = (const float*)d_in[4];
  const float* Wq    = (const float*)d_in[5];
  const float* Wk    = (const float*)d_in[6];
  const int* node_i  = (const int*)d_in[8];
  const int* node_j  = (const int*)d_in[9];

  const int N = in_sizes[0];            // 50000
  const int B = in_sizes[3] / 128;      // 64
  const int E = in_sizes[2] / 128;      // 131072

  float* ws = (float*)d_ws;
  float* M  = ws;
  float* Mt = M + 262144;
  float* Tj = Mt + 262144;              // [N][256] = J0|J1 packed
  float* I1 = Tj + (size_t)N * 256;
  float* wv = I1 + (size_t)N * 128;
  float* uv = wv + (size_t)B * 128;
  float* yv = uv + (size_t)B * 128;
  float* cb = yv + (size_t)B * 128;
  float* ec = cb + B;
  float* exb = ec + E;
  unsigned* segkey = (unsigned*)(exb + E);
  float* segsum = (float*)(segkey + N);
  unsigned short* Mh  = (unsigned short*)(segsum + N);
  unsigned short* Ml  = Mh + 262144;
  unsigned short* Mth = Ml + 262144;
  unsigned short* Mtl = Mth + 262144;
  float* out = (float*)d_out;

  k1_gemmM<<<dim3(16, 16), 256, 0, stream>>>(Wq, Wk, M, Mt, Mh, Ml, Mth, Mtl,
                                             out, segsum, segkey, N);
  k2m3_mfma<<<(N + 63) / 64, 256, 0, stream>>>(hv, Mh, Ml, Mth, Mtl, Tj, I1, N);
  k3_query<<<B, 256, 0, stream>>>(qsrc, qrel, M, Mt, wv, uv, yv, cb);
  k4m_mfma<<<E / 64, 256, 0, stream>>>(rel, Mth, Mtl, yv, cb, ec);
  k5_logits<<<E / 16, 256, 0, stream>>>(rel, hv, Tj, I1, wv, uv, ec,
                                        node_i, node_j, exb, segkey);
  k6_exp<<<(E + 255) / 256, 256, 0, stream>>>(exb, node_i, segkey, segsum, E);
  k7_topk<<<B, 256, 0, stream>>>(exb, node_i, node_j, segsum, score, out);
}